// Round 10
// baseline (885.087 us; speedup 1.0000x reference)
//
#include <hip/hip_runtime.h>
#include <hip/hip_cooperative_groups.h>
#include <math.h>

namespace cg = cooperative_groups;

typedef __attribute__((ext_vector_type(8))) short s8;
typedef __attribute__((ext_vector_type(4))) float f4;
typedef unsigned short u16;

__device__ inline u16 f2bf(float f) {
    unsigned u = __float_as_uint(f);
    u += 0x7fffu + ((u >> 16) & 1u);
    return (u16)(u >> 16);
}
__device__ inline float bf2f(u16 x) {
    return __uint_as_float(((unsigned)x) << 16);
}
#define MFMA16(a, b, c) __builtin_amdgcn_mfma_f32_16x16x32_bf16(a, b, c, 0, 0, 0)

// ================= shared-memory union for the trunk kernels =================
struct SMemG64 { u16 As[2][64][136]; u16 Bs[2][64][136]; };    // 69,632 B
struct SMemG128 { u16 As[2][128][72]; u16 Bs[2][128][72]; };   // 73,728 B
struct SMemCA {
    u16 QHs[80][72]; u16 KHs[256][72];
    float rmax[80][4]; float rsum[80][4]; float Wj[256];
};                                                              // 51,968 B
struct SMemLN { float red[8]; };
union SMemU { SMemG64 g64; SMemG128 g128; SMemCA ca; SMemLN ln; };

// ============ fused axis means, no atomics ============
__global__ __launch_bounds__(256) void mean3_k(const float* __restrict__ img,
                                               float* __restrict__ axp,
                                               float* __restrict__ sag,
                                               float* __restrict__ cor) {
    __shared__ float sl[112*81];
    int blk = blockIdx.x;
    int dc = blk & 15, bc = blk >> 4;
    int d0 = dc * 7;
    int t = threadIdx.x;
    f4 axr[9];
    #pragma unroll
    for (int k = 0; k < 9; ++k) axr[k] = (f4){0.f,0.f,0.f,0.f};
    const float* base = img + (size_t)bc * 1003520 + (size_t)d0 * 8960;
    for (int sidx = 0; sidx < 7; ++sidx) {
        const f4* sp = reinterpret_cast<const f4*>(base + (size_t)sidx * 8960);
        #pragma unroll
        for (int k = 0; k < 9; ++k) {
            int q = t + k * 256;
            if (q < 2240) {
                f4 v = sp[q];
                axr[k] += v;
                int h = q / 20, w4 = q % 20;
                float* row = &sl[h * 81 + w4 * 4];
                row[0] = v[0]; row[1] = v[1]; row[2] = v[2]; row[3] = v[3];
            }
        }
        __syncthreads();
        if (t < 112) {
            float acc = 0.f;
            #pragma unroll 8
            for (int w = 0; w < 80; ++w) acc += sl[t * 81 + w];
            cor[((size_t)bc * 112 + d0 + sidx) * 112 + t] = acc * (1.f / 80.f);
        } else if (t < 192) {
            int w = t - 112;
            float acc = 0.f;
            #pragma unroll 8
            for (int h = 0; h < 112; ++h) acc += sl[h * 81 + w];
            sag[((size_t)bc * 112 + d0 + sidx) * 80 + w] = acc * (1.f / 112.f);
        }
        __syncthreads();
    }
    float* axo = axp + ((size_t)dc * 64 + bc) * 8960;
    #pragma unroll
    for (int k = 0; k < 9; ++k) {
        int q = t + k * 256;
        if (q < 2240) *reinterpret_cast<f4*>(axo + q * 4) = axr[k];
    }
}

// ============ batched transpose-convert: f32 [K][N] -> bf16 [N][K] ============
struct TT {
    const float* in[16];
    u16* out[16];
    int K[16];
    int N[16];
    int start[16];
};

__global__ __launch_bounds__(256) void transp_all(TT tab) {
    __shared__ float tl[32][33];
    int bid = blockIdx.x;
    int e = 0;
    #pragma unroll
    for (int i = 1; i < 16; ++i) if (bid >= tab.start[i]) e = i;
    const float* in = tab.in[e];
    u16* out = tab.out[e];
    int K = tab.K[e], N = tab.N[e];
    int tid = bid - tab.start[e];
    int nt = N >> 5;
    int k0 = (tid / nt) * 32, n0 = (tid % nt) * 32;
    int t = threadIdx.x;
    int r = t >> 5, c = t & 31;
    #pragma unroll
    for (int i = 0; i < 4; ++i) tl[r + i*8][c] = in[(long)(k0 + r + i*8)*N + n0 + c];
    __syncthreads();
    #pragma unroll
    for (int i = 0; i < 4; ++i) out[(long)(n0 + r + i*8)*K + k0 + c] = f2bf(tl[c][r + i*8]);
}

// ============ patchify, 3 branches; br0 sums ax partials ============
__global__ __launch_bounds__(256) void patchify3_k(const float* __restrict__ axp,
                                                   const float* __restrict__ m_sag,
                                                   const float* __restrict__ m_cor,
                                                   u16* __restrict__ P0, u16* __restrict__ P1,
                                                   u16* __restrict__ P2) {
    __shared__ float sl[32][113];
    int br = blockIdx.y;
    int X = blockIdx.x;
    int b = X / 112, rem = X % 112;
    int hh = rem / 7, pp1 = rem % 7;
    const float* src; u16* dst; int Wt, p2, PD;
    if (br == 0)      { src = nullptr; dst = P0; Wt = 80;  p2 = 5; PD = 1120; }
    else if (br == 1) { src = m_sag;   dst = P1; Wt = 80;  p2 = 5; PD = 1120; }
    else              { src = m_cor;   dst = P2; Wt = 112; p2 = 7; PD = 1568; }
    int t = threadIdx.x;
    int row = hh*7 + pp1;
    int wq = Wt >> 2;
    if (br == 0) {
        for (int i = t; i < 32*20; i += 256) {
            int c = i / 20, w4 = i % 20;
            f4 s = (f4){0.f,0.f,0.f,0.f};
            size_t base = ((size_t)(b*32 + c)*112 + row)*80 + w4*4;
            #pragma unroll
            for (int p = 0; p < 16; ++p)
                s += *reinterpret_cast<const f4*>(axp + (size_t)p*573440 + base);
            s *= (1.f/112.f);
            sl[c][w4*4+0] = s[0]; sl[c][w4*4+1] = s[1]; sl[c][w4*4+2] = s[2]; sl[c][w4*4+3] = s[3];
        }
    } else {
        for (int i = t; i < 32*wq; i += 256) {
            int c = i / wq, w4 = i % wq;
            float4 v = *reinterpret_cast<const float4*>(
                src + ((size_t)(b*32 + c)*112 + row)*Wt + w4*4);
            sl[c][w4*4+0] = v.x; sl[c][w4*4+1] = v.y; sl[c][w4*4+2] = v.z; sl[c][w4*4+3] = v.w;
        }
    }
    __syncthreads();
    int tot = 16 * p2 * 32;
    for (int o = t; o < tot; o += 256) {
        int ww = o / (p2*32), rest = o % (p2*32);
        int pp2 = rest >> 5, c = rest & 31;
        dst[((size_t)(b*256 + hh*16 + ww))*PD + (pp1*p2 + pp2)*32 + c]
            = f2bf(sl[c][ww*p2 + pp2]);
    }
}

// ============ GEMM building blocks ============
__device__ inline void load_tile(const u16* __restrict__ P, int ld, int nrows, int K,
                                 int r0, int k0, int t, s8 v[4]) {
    #pragma unroll
    for (int i = 0; i < 4; ++i) {
        int chunk = t + i*256;
        int row = chunk >> 4, c8 = (chunk & 15) * 8;
        s8 x;
        #pragma unroll
        for (int q = 0; q < 8; ++q) x[q] = 0;
        if (r0 + row < nrows && k0 + c8 < K)
            x = *reinterpret_cast<const s8*>(P + (long)(r0 + row)*ld + k0 + c8);
        v[i] = x;
    }
}
__device__ inline void load_tile_f32(const float* __restrict__ P, int ld, int nrows, int K,
                                     int r0, int k0, int t, s8 v[4]) {
    #pragma unroll
    for (int i = 0; i < 4; ++i) {
        int chunk = t + i*256;
        int row = chunk >> 4, c8 = (chunk & 15) * 8;
        s8 x;
        #pragma unroll
        for (int q = 0; q < 8; ++q) x[q] = 0;
        if (r0 + row < nrows && k0 + c8 < K) {
            const float* src = P + (long)(r0 + row)*ld + k0 + c8;
            #pragma unroll
            for (int q = 0; q < 8; ++q) x[q] = (short)f2bf(src[q]);
        }
        v[i] = x;
    }
}
__device__ inline void write_tile(u16 (*S)[136], int t, const s8 v[4]) {
    #pragma unroll
    for (int i = 0; i < 4; ++i) {
        int chunk = t + i*256;
        *reinterpret_cast<s8*>(&S[chunk >> 4][(chunk & 15)*8]) = v[i];
    }
}
__device__ inline void mfma_tile(const u16 (*As)[136], const u16 (*Bs)[136],
                                 int wr, int wc, int lane, f4 acc[2][2]) {
    int lrow = lane & 15;
    #pragma unroll
    for (int kh = 0; kh < 4; ++kh) {
        int lk = kh*32 + (lane >> 4) * 8;
        s8 af0 = *reinterpret_cast<const s8*>(&As[wr*32 + lrow][lk]);
        s8 af1 = *reinterpret_cast<const s8*>(&As[wr*32 + 16 + lrow][lk]);
        s8 bg0 = *reinterpret_cast<const s8*>(&Bs[wc*32 + lrow][lk]);
        s8 bg1 = *reinterpret_cast<const s8*>(&Bs[wc*32 + 16 + lrow][lk]);
        acc[0][0] = MFMA16(af0, bg0, acc[0][0]);
        acc[0][1] = MFMA16(af0, bg1, acc[0][1]);
        acc[1][0] = MFMA16(af1, bg0, acc[1][0]);
        acc[1][1] = MFMA16(af1, bg1, acc[1][1]);
    }
}

// one 64x64 tile: acc = A[m0:,k] @ Bt[n0:,k]^T (A optionally fp32)
__device__ void g64_core(SMemG64& S, const u16* A, const float* Af32,
                         const u16* Bt, int M, int N, int K,
                         int m0, int n0, int t, f4 acc[2][2]) {
    int wave = t >> 6, lane = t & 63;
    int wr = wave >> 1, wc = wave & 1;
    #pragma unroll
    for (int m = 0; m < 2; ++m)
        #pragma unroll
        for (int n = 0; n < 2; ++n)
            #pragma unroll
            for (int r = 0; r < 4; ++r) acc[m][n][r] = 0.f;
    int nk = (K + 127) >> 7;
    s8 pa[4], pbv[4];
    if (Af32) load_tile_f32(Af32, K, M, K, m0, 0, t, pa);
    else      load_tile(A, K, M, K, m0, 0, t, pa);
    load_tile(Bt, K, N, K, n0, 0, t, pbv);
    write_tile(S.As[0], t, pa);
    write_tile(S.Bs[0], t, pbv);
    __syncthreads();
    for (int kt = 0; kt < nk; ++kt) {
        int cur = kt & 1;
        if (kt + 1 < nk) {
            if (Af32) load_tile_f32(Af32, K, M, K, m0, (kt+1) << 7, t, pa);
            else      load_tile(A, K, M, K, m0, (kt+1) << 7, t, pa);
            load_tile(Bt, K, N, K, n0, (kt+1) << 7, t, pbv);
        }
        mfma_tile(S.As[cur], S.Bs[cur], wr, wc, lane, acc);
        if (kt + 1 < nk) {
            write_tile(S.As[cur^1], t, pa);
            write_tile(S.Bs[cur^1], t, pbv);
        }
        __syncthreads();
    }
}

__device__ void g64_epi_std(const f4 acc[2][2], int M, int N, int m0, int n0, int t,
                            float* Cf, u16* Cb, const float* bias,
                            const float* resid, int act) {
    int wave = t >> 6, lane = t & 63;
    int wr = wave >> 1, wc = wave & 1;
    #pragma unroll
    for (int m = 0; m < 2; ++m) {
        int rbase = m0 + wr*32 + m*16 + (lane >> 4) * 4;
        #pragma unroll
        for (int n = 0; n < 2; ++n) {
            int col = n0 + wc*32 + n*16 + (lane & 15);
            if (col >= N) continue;
            #pragma unroll
            for (int r = 0; r < 4; ++r) {
                int row = rbase + r;
                if (row >= M) continue;
                float v = acc[m][n][r];
                if (bias)  v += bias[col];
                if (resid) v += resid[(long)row * N + col];
                if (act == 1) v = 0.5f * v * (1.0f + erff(v * 0.70710678118654752f));
                long ci = (long)row * N + col;
                if (Cf) Cf[ci] = v;
                if (Cb) Cb[ci] = f2bf(v);
            }
        }
    }
}

// standard 64-tile GEMM phase (grid-stride)
__device__ void phase_g64(SMemU& sm, const u16* A, const u16* Bt,
                          float* Cf, u16* Cb, int M, int N, int K,
                          const float* bias, const float* resid, int act) {
    int ntx = (N + 63) >> 6, nty = (M + 63) >> 6;
    int ntiles = ntx * nty;
    for (int tile = blockIdx.x; tile < ntiles; tile += gridDim.x) {
        int m0 = (tile / ntx) * 64, n0 = (tile % ntx) * 64;
        f4 acc[2][2];
        g64_core(sm.g64, A, nullptr, Bt, M, N, K, m0, n0, threadIdx.x, acc);
        g64_epi_std(acc, M, N, m0, n0, threadIdx.x, Cf, Cb, bias, resid, act);
    }
}

// big-tile (128x128, BK=64) phase; optional vt scatter + split bias + act
__device__ void phase_g128(SMemU& sm, const u16* A, const u16* Bt,
                           u16* Cb, u16* vt, int Mt, int Nt, int N, int K,
                           const float* bias, const float* bias2, int act) {
    SMemG128& S = sm.g128;
    int t = threadIdx.x;
    int wave = t >> 6, lane = t & 63;
    int wr = wave >> 1, wc = wave & 1;
    int ntiles = Mt * Nt;
    for (int tile = blockIdx.x; tile < ntiles; tile += gridDim.x) {
        int m0 = (tile / Nt) * 128, n0 = (tile % Nt) * 128;
        f4 acc[4][4];
        #pragma unroll
        for (int m = 0; m < 4; ++m)
            #pragma unroll
            for (int n = 0; n < 4; ++n)
                #pragma unroll
                for (int r = 0; r < 4; ++r) acc[m][n][r] = 0.f;
        int nk = K >> 6;
        s8 pa[4], pbv[4];
        #pragma unroll
        for (int i = 0; i < 4; ++i) {
            int chunk = t + i*256;
            pa[i]  = *reinterpret_cast<const s8*>(A  + (long)(m0 + (chunk>>3))*K + (chunk&7)*8);
            pbv[i] = *reinterpret_cast<const s8*>(Bt + (long)(n0 + (chunk>>3))*K + (chunk&7)*8);
        }
        #pragma unroll
        for (int i = 0; i < 4; ++i) {
            int chunk = t + i*256;
            *reinterpret_cast<s8*>(&S.As[0][chunk>>3][(chunk&7)*8]) = pa[i];
            *reinterpret_cast<s8*>(&S.Bs[0][chunk>>3][(chunk&7)*8]) = pbv[i];
        }
        __syncthreads();
        for (int kt = 0; kt < nk; ++kt) {
            int cur = kt & 1;
            if (kt + 1 < nk) {
                int k0 = (kt+1) << 6;
                #pragma unroll
                for (int i = 0; i < 4; ++i) {
                    int chunk = t + i*256;
                    pa[i]  = *reinterpret_cast<const s8*>(A  + (long)(m0 + (chunk>>3))*K + k0 + (chunk&7)*8);
                    pbv[i] = *reinterpret_cast<const s8*>(Bt + (long)(n0 + (chunk>>3))*K + k0 + (chunk&7)*8);
                }
            }
            #pragma unroll
            for (int kh = 0; kh < 2; ++kh) {
                int lk = kh*32 + (lane >> 4) * 8;
                int lr = lane & 15;
                s8 af[4], bf[4];
                #pragma unroll
                for (int m = 0; m < 4; ++m)
                    af[m] = *reinterpret_cast<const s8*>(&S.As[cur][wr*64 + m*16 + lr][lk]);
                #pragma unroll
                for (int n = 0; n < 4; ++n)
                    bf[n] = *reinterpret_cast<const s8*>(&S.Bs[cur][wc*64 + n*16 + lr][lk]);
                #pragma unroll
                for (int m = 0; m < 4; ++m)
                    #pragma unroll
                    for (int n = 0; n < 4; ++n)
                        acc[m][n] = MFMA16(af[m], bf[n], acc[m][n]);
            }
            if (kt + 1 < nk) {
                #pragma unroll
                for (int i = 0; i < 4; ++i) {
                    int chunk = t + i*256;
                    *reinterpret_cast<s8*>(&S.As[cur^1][chunk>>3][(chunk&7)*8]) = pa[i];
                    *reinterpret_cast<s8*>(&S.Bs[cur^1][chunk>>3][(chunk&7)*8]) = pbv[i];
                }
            }
            __syncthreads();
        }
        #pragma unroll
        for (int m = 0; m < 4; ++m) {
            int rbase = m0 + wr*64 + m*16 + (lane >> 4) * 4;
            #pragma unroll
            for (int n = 0; n < 4; ++n) {
                int col = n0 + wc*64 + n*16 + (lane & 15);
                #pragma unroll
                for (int r = 0; r < 4; ++r) {
                    int row = rbase + r;
                    float v = acc[m][n][r];
                    if (bias) {
                        float bb = bias2 ? ((col < 768) ? bias[col] : bias2[col - 768]) : bias[col];
                        v += bb;
                    }
                    if (act == 1) v = 0.5f * v * (1.0f + erff(v * 0.70710678118654752f));
                    u16 b = f2bf(v);
                    Cb[(long)row * N + col] = b;
                    if (vt && col >= 1536) {
                        int z = (row >> 8) * 12 + ((col - 1536) >> 6);
                        vt[((long)z * 64 + (col & 63)) * 256 + (row & 255)] = b;
                    }
                }
            }
        }
    }
}

// LayerNorm phase: rows of 768, grid-stride
__device__ void ln_rows(SMemLN& S, const float* in, float* outf, u16* outb,
                        const float* g, const float* bta) {
    int t = threadIdx.x;
    int wid = t >> 6, lane = t & 63;
    for (int row = blockIdx.x; row < 1536; row += gridDim.x) {
        const float* x = in + (size_t)row * 768;
        float v0 = x[t], v1 = x[t+256], v2 = x[t+512];
        float s = v0+v1+v2, s2 = v0*v0+v1*v1+v2*v2;
        #pragma unroll
        for (int off = 32; off; off >>= 1) { s += __shfl_down(s, off); s2 += __shfl_down(s2, off); }
        if (lane == 0) { S.red[wid] = s; S.red[wid+4] = s2; }
        __syncthreads();
        float mean = (S.red[0]+S.red[1]+S.red[2]+S.red[3]) * (1.f/768.f);
        float var = (S.red[4]+S.red[5]+S.red[6]+S.red[7]) * (1.f/768.f) - mean*mean;
        float rstd = rsqrtf(var + 1e-5f);
        float y0 = (v0-mean)*rstd*g[t]     + bta[t];
        float y1 = (v1-mean)*rstd*g[t+256] + bta[t+256];
        float y2 = (v2-mean)*rstd*g[t+512] + bta[t+512];
        if (outf) {
            float* y = outf + (size_t)row * 768;
            y[t] = y0; y[t+256] = y1; y[t+512] = y2;
        }
        if (outb) {
            u16* y = outb + (size_t)row * 768;
            y[t] = f2bf(y0); y[t+256] = f2bf(y1); y[t+512] = f2bf(y2);
        }
        __syncthreads();
    }
}

// fused cross-attention phase (one block per bh < 72)
__device__ void ca_phase(SMemU& sm, const u16* QHb, const u16* KVHb, u16* O) {
    if (blockIdx.x >= 72) return;
    SMemCA& C = sm.ca;
    int bh = blockIdx.x;
    int rowblk = bh / 12, h = bh % 12;
    int bsel = rowblk & 1;
    int t = threadIdx.x;
    int wave = t >> 6, lane = t & 63;
    int lr = lane & 15, lg = lane >> 4;
    #pragma unroll
    for (int i = 0; i < 3; ++i) {
        int chunk = t + i*256;
        if (chunk < 640) {
            int row = chunk >> 3, c8 = (chunk & 7)*8;
            s8 v;
            #pragma unroll
            for (int q = 0; q < 8; ++q) v[q] = 0;
            if (row < 77)
                v = *reinterpret_cast<const s8*>(QHb + ((long)(bsel*77 + row))*768 + h*64 + c8);
            *reinterpret_cast<s8*>(&C.QHs[row][c8]) = v;
        }
    }
    #pragma unroll
    for (int i = 0; i < 8; ++i) {
        int chunk = t + i*256;
        int row = chunk >> 3, c8 = (chunk & 7)*8;
        *reinterpret_cast<s8*>(&C.KHs[row][c8]) =
            *reinterpret_cast<const s8*>(KVHb + ((long)rowblk*256 + row)*1536 + h*64 + c8);
    }
    __syncthreads();
    f4 acc[5][4];
    #pragma unroll
    for (int m = 0; m < 5; ++m)
        #pragma unroll
        for (int n = 0; n < 4; ++n)
            #pragma unroll
            for (int r = 0; r < 4; ++r) acc[m][n][r] = 0.f;
    #pragma unroll
    for (int kh = 0; kh < 2; ++kh) {
        s8 af[5], bf[4];
        #pragma unroll
        for (int m = 0; m < 5; ++m)
            af[m] = *reinterpret_cast<const s8*>(&C.QHs[m*16 + lr][kh*32 + lg*8]);
        #pragma unroll
        for (int n = 0; n < 4; ++n)
            bf[n] = *reinterpret_cast<const s8*>(&C.KHs[wave*64 + n*16 + lr][kh*32 + lg*8]);
        #pragma unroll
        for (int m = 0; m < 5; ++m)
            #pragma unroll
            for (int n = 0; n < 4; ++n)
                acc[m][n] = MFMA16(af[m], bf[n], acc[m][n]);
    }
    #pragma unroll
    for (int m = 0; m < 5; ++m)
        #pragma unroll
        for (int r = 0; r < 4; ++r) {
            float mx = -1e30f;
            #pragma unroll
            for (int n = 0; n < 4; ++n) mx = fmaxf(mx, acc[m][n][r]);
            #pragma unroll
            for (int o = 8; o; o >>= 1) mx = fmaxf(mx, __shfl_xor(mx, o));
            if (lr == 0) C.rmax[m*16 + lg*4 + r][wave] = mx;
        }
    __syncthreads();
    #pragma unroll
    for (int m = 0; m < 5; ++m)
        #pragma unroll
        for (int r = 0; r < 4; ++r) {
            int i = m*16 + lg*4 + r;
            float mi = fmaxf(fmaxf(C.rmax[i][0], C.rmax[i][1]), fmaxf(C.rmax[i][2], C.rmax[i][3]));
            float s = 0.f;
            #pragma unroll
            for (int n = 0; n < 4; ++n) s += __expf((acc[m][n][r] - mi) * 0.125f);
            #pragma unroll
            for (int o = 8; o; o >>= 1) s += __shfl_xor(s, o);
            if (lr == 0) C.rsum[i][wave] = s;
        }
    __syncthreads();
    float wn[4] = {0.f, 0.f, 0.f, 0.f};
    #pragma unroll
    for (int m = 0; m < 5; ++m)
        #pragma unroll
        for (int r = 0; r < 4; ++r) {
            int i = m*16 + lg*4 + r;
            if (i < 77) {
                float mi = fmaxf(fmaxf(C.rmax[i][0], C.rmax[i][1]), fmaxf(C.rmax[i][2], C.rmax[i][3]));
                float li = C.rsum[i][0] + C.rsum[i][1] + C.rsum[i][2] + C.rsum[i][3];
                float inv = 1.f / li;
                #pragma unroll
                for (int n = 0; n < 4; ++n)
                    wn[n] += __expf((acc[m][n][r] - mi) * 0.125f) * inv;
            }
        }
    #pragma unroll
    for (int n = 0; n < 4; ++n) {
        wn[n] += __shfl_xor(wn[n], 16);
        wn[n] += __shfl_xor(wn[n], 32);
    }
    if (lane < 16) {
        #pragma unroll
        for (int n = 0; n < 4; ++n) C.Wj[wave*64 + n*16 + lr] = wn[n];
    }
    __syncthreads();
    int d = t & 63;
    #pragma unroll 4
    for (int it = 0; it < 64; ++it) {
        int j = it*4 + (t >> 6);
        long row = (long)rowblk*256 + j;
        float vh = bf2f(KVHb[row*1536 + 768 + h*64 + d]);
        O[row*768 + h*64 + d] = f2bf(C.Wj[j] * vh);
    }
}

// ================= cooperative trunk kernels =================
struct T1Args {
    const u16* P[3];
    const u16* peT[3]; const u16* caqT;
    const float* peb[3]; const float* caqb;
    const float* pos[3];
    const float* txt;
    float* X0; u16* QHb;
    const float* g0; const float* b0;
    float* X1f; u16* X1b;
    const u16* qkvT; u16* QKVb; u16* Vt;
    int K[4];
};

__global__ __launch_bounds__(256, 2) void trunk1_k(T1Args a) {
    __shared__ SMemU sm;
    cg::grid_group grid = cg::this_grid();
    int t = threadIdx.x;
    // phase 1: patch-embed (z<3) + QH projection (z=3): 324 tiles
    for (int tile = blockIdx.x; tile < 324; tile += gridDim.x) {
        int z, ty, tx;
        if (tile < 288) { z = tile / 96; int r = tile % 96; ty = r / 12; tx = r % 12; }
        else            { z = 3; int r = tile - 288; ty = r / 12; tx = r % 12; }
        int M = (z < 3) ? 512 : 154;
        int K = a.K[z];
        f4 acc[2][2];
        g64_core(sm.g64, (z < 3) ? a.P[z] : nullptr, (z == 3) ? a.txt : nullptr,
                 (z < 3) ? a.peT[z] : a.caqT, M, 768, K, ty*64, tx*64, t, acc);
        int wave = t >> 6, lane = t & 63;
        int wr = wave >> 1, wc = wave & 1;
        const float* bias = (z < 3) ? a.peb[z] : a.caqb;
        #pragma unroll
        for (int m = 0; m < 2; ++m) {
            int rbase = ty*64 + wr*32 + m*16 + (lane >> 4) * 4;
            #pragma unroll
            for (int n = 0; n < 2; ++n) {
                int col = tx*64 + wc*32 + n*16 + (lane & 15);
                #pragma unroll
                for (int r = 0; r < 4; ++r) {
                    int row = rbase + r;
                    if (row >= M) continue;
                    float v = acc[m][n][r] + bias[col];
                    if (z < 3) {
                        v += a.pos[z][(long)(row & 255)*768 + col];
                        a.X0[((long)z*512 + row) * 768 + col] = v;
                    } else {
                        a.QHb[(long)row * 768 + col] = f2bf(v);
                    }
                }
            }
        }
    }
    grid.sync();
    // phase 2: LN1
    ln_rows(sm.ln, a.X0, a.X1f, a.X1b, a.g0, a.b0);
    grid.sync();
    // phase 3: QKV projection (big tile) + Vt scatter
    phase_g128(sm, a.X1b, a.qkvT, a.QKVb, a.Vt, 12, 18, 2304, 768, nullptr, nullptr, 0);
}

struct T2Args {
    const u16* Obf; const u16* pwT; const float* pb; const float* X1f; float* X2;
    const float* g1; const float* b1; float* X3f; u16* X3b;
    const u16* cakvT; const float* cakb; const float* cavb; u16* KVHb;
    const u16* QHb; u16* Oca;
    const u16* caoT; const float* caob; float* X4;
    const float* g2; const float* b2; u16* X5b;
    const u16* mlp1T; const float* mb1; u16* Hb;
    const u16* mlp2T; const float* mb2; u16* X6b;
    const u16* owT[3]; const float* ob[3];
    float* plane[3]; const float* vw;
};

__global__ __launch_bounds__(256, 2) void trunk2_k(T2Args a) {
    __shared__ SMemU sm;
    cg::grid_group grid = cg::this_grid();
    int t = threadIdx.x;
    // 1: X2 = Obf @ pwT + pb + X1f
    phase_g64(sm, a.Obf, a.pwT, a.X2, nullptr, 1536, 768, 768, a.pb, a.X1f, 0);
    grid.sync();
    // 2: LN2
    ln_rows(sm.ln, a.X2, a.X3f, a.X3b, a.g1, a.b1);
    grid.sync();
    // 3: KVHb = X3b @ cakvT + [cakb|cavb]
    phase_g128(sm, a.X3b, a.cakvT, a.KVHb, nullptr, 12, 12, 1536, 768, a.cakb, a.cavb, 0);
    grid.sync();
    // 4: cross-attention
    ca_phase(sm, a.QHb, a.KVHb, a.Oca);
    grid.sync();
    // 5: X4 = Oca @ caoT + caob + X3f
    phase_g64(sm, a.Oca, a.caoT, a.X4, nullptr, 1536, 768, 768, a.caob, a.X3f, 0);
    grid.sync();
    // 6: LN3
    ln_rows(sm.ln, a.X4, nullptr, a.X5b, a.g2, a.b2);
    grid.sync();
    // 7: Hb = gelu(X5b @ mlp1T + mb1)
    phase_g128(sm, a.X5b, a.mlp1T, a.Hb, nullptr, 12, 24, 3072, 768, a.mb1, nullptr, 1);
    grid.sync();
    // 8: X6b = Hb @ mlp2T + mb2 + X4
    phase_g64(sm, a.Hb, a.mlp2T, nullptr, a.X6b, 1536, 768, 3072, a.mb2, a.X4, 0);
    grid.sync();
    // 9: output projections + fused unpatchify: 488 tiles
    {
        const int Nz[3] = {1120, 1120, 1568};
        const int ntxz[3] = {18, 18, 25};
        const int p2z[3] = {5, 5, 7};
        const int Wdz[3] = {80, 80, 112};
        for (int tile = blockIdx.x; tile < 488; tile += gridDim.x) {
            int z, ty, tx;
            if (tile < 144)      { z = 0; ty = tile / 18; tx = tile % 18; }
            else if (tile < 288) { z = 1; int r = tile - 144; ty = r / 18; tx = r % 18; }
            else                 { z = 2; int r = tile - 288; ty = r / 25; tx = r % 25; }
            int N = Nz[z];
            f4 acc[2][2];
            g64_core(sm.g64, a.X6b + (long)z*512*768, nullptr, a.owT[z],
                     512, N, 768, ty*64, tx*64, t, acc);
            int wave = t >> 6, lane = t & 63;
            int wr = wave >> 1, wc = wave & 1;
            float* plane = a.plane[z];
            const float* bias = a.ob[z];
            int p2 = p2z[z], Wd = Wdz[z];
            float wt = a.vw[z];
            #pragma unroll
            for (int m = 0; m < 2; ++m) {
                int rbase = ty*64 + wr*32 + m*16 + (lane >> 4) * 4;
                #pragma unroll
                for (int n = 0; n < 2; ++n) {
                    int col = tx*64 + wc*32 + n*16 + (lane & 15);
                    if (col >= N) continue;
                    int pp = col >> 5, c = col & 31;
                    int pp1 = pp / p2, pp2 = pp % p2;
                    float bv = bias[col];
                    #pragma unroll
                    for (int r = 0; r < 4; ++r) {
                        int row = rbase + r;
                        int b = row >> 8, nn = row & 255;
                        int hh = nn >> 4, ww = nn & 15;
                        plane[((long)(b*32 + c)*112 + hh*7 + pp1)*Wd + ww*p2 + pp2]
                            = wt * (acc[m][n][r] + bv);
                    }
                }
            }
        }
    }
}

// ============ fully fused self-attention (standalone: 138 KB LDS) ============
__global__ __launch_bounds__(256) void attn_k(const u16* __restrict__ QKV,
                                              const u16* __restrict__ Vt,
                                              u16* __restrict__ O) {
    __shared__ u16 Ks[256][72];
    __shared__ u16 Ps[128][264];
    __shared__ u16 Vs[64][264];
    int zz = blockIdx.x;
    int bh = zz >> 1, half = zz & 1;
    int bb = bh / 12, h = bh % 12;
    long qrow0 = (long)bb*256 + half*128;
    int hcol = h*64;
    int t = threadIdx.x;
    int wave = t >> 6, lane = t & 63;
    int lr = lane & 15, lg = lane >> 4;
    #pragma unroll
    for (int i = 0; i < 8; ++i) {
        int chunk = t + i*256;
        int row = chunk >> 3, c8 = (chunk & 7)*8;
        *reinterpret_cast<s8*>(&Ks[row][c8]) =
            *reinterpret_cast<const s8*>(QKV + ((long)bb*256 + row)*2304 + 768 + hcol + c8);
    }
    #pragma unroll
    for (int i = 0; i < 8; ++i) {
        int chunk = t + i*256;
        int d = chunk >> 5, j8 = (chunk & 31)*8;
        *reinterpret_cast<s8*>(&Vs[d][j8]) =
            *reinterpret_cast<const s8*>(Vt + (long)bh*16384 + (long)d*256 + j8);
    }
    __syncthreads();
    f4 acc[2][16];
    #pragma unroll
    for (int m = 0; m < 2; ++m)
        #pragma unroll
        for (int n = 0; n < 16; ++n)
            #pragma unroll
            for (int r = 0; r < 4; ++r) acc[m][n][r] = 0.f;
    #pragma unroll
    for (int kh = 0; kh < 2; ++kh) {
        s8 af0 = *reinterpret_cast<const s8*>(QKV + (qrow0 + wave*32 + lr)*2304 + hcol + kh*32 + lg*8);
        s8 af1 = *reinterpret_cast<const s8*>(QKV + (qrow0 + wave*32 + 16 + lr)*2304 + hcol + kh*32 + lg*8);
        #pragma unroll
        for (int n = 0; n < 16; ++n) {
            s8 bf = *reinterpret_cast<const s8*>(&Ks[n*16 + lr][kh*32 + lg*8]);
            acc[0][n] = MFMA16(af0, bf, acc[0][n]);
            acc[1][n] = MFMA16(af1, bf, acc[1][n]);
        }
    }
    #pragma unroll
    for (int m = 0; m < 2; ++m)
        #pragma unroll
        for (int r = 0; r < 4; ++r) {
            float mx = -1e30f;
            #pragma unroll
            for (int n = 0; n < 16; ++n) mx = fmaxf(mx, acc[m][n][r]);
            #pragma unroll
            for (int o = 8; o; o >>= 1) mx = fmaxf(mx, __shfl_xor(mx, o));
            float l = 0.f;
            float p[16];
            #pragma unroll
            for (int n = 0; n < 16; ++n) {
                p[n] = __expf((acc[m][n][r] - mx) * 0.125f);
                l += p[n];
            }
            #pragma unroll
            for (int o = 8; o; o >>= 1) l += __shfl_xor(l, o);
            float inv = 1.f / l;
            int prow = wave*32 + m*16 + lg*4 + r;
            #pragma unroll
            for (int n = 0; n < 16; ++n)
                Ps[prow][n*16 + lr] = f2bf(p[n] * inv);
        }
    __syncthreads();
    f4 o2[2][4];
    #pragma unroll
    for (int m = 0; m < 2; ++m)
        #pragma unroll
        for (int n = 0; n < 4; ++n)
            #pragma unroll
            for (int r = 0; r < 4; ++r) o2[m][n][r] = 0.f;
    #pragma unroll
    for (int kh = 0; kh < 8; ++kh) {
        s8 pf0 = *reinterpret_cast<const s8*>(&Ps[wave*32 + lr][kh*32 + lg*8]);
        s8 pf1 = *reinterpret_cast<const s8*>(&Ps[wave*32 + 16 + lr][kh*32 + lg*8]);
        #pragma unroll
        for (int n = 0; n < 4; ++n) {
            s8 vf = *reinterpret_cast<const s8*>(&Vs[n*16 + lr][kh*32 + lg*8]);
            o2[0][n] = MFMA16(pf0, vf, o2[0][n]);
            o2[1][n] = MFMA16(pf1, vf, o2[1][n]);
        }
    }
    #pragma unroll
    for (int m = 0; m < 2; ++m)
        #pragma unroll
        for (int n = 0; n < 4; ++n)
            #pragma unroll
            for (int r = 0; r < 4; ++r)
                O[(qrow0 + wave*32 + m*16 + lg*4 + r)*768 + hcol + n*16 + lr] = f2bf(o2[m][n][r]);
}

// ============ streaming final combine ============
__global__ __launch_bounds__(256) void final_k(const float* __restrict__ img,
                                               const float* __restrict__ Aax,
                                               const float* __restrict__ Asag,
                                               const float* __restrict__ Acor,
                                               float* __restrict__ out) {
    int blk = blockIdx.x;
    int bc = blk / 112;
    const float4* ip = reinterpret_cast<const float4*>(img + (size_t)blk * 8960);
    const float4* ap = reinterpret_cast<const float4*>(Aax + (size_t)bc * 8960);
    const float4* sp = reinterpret_cast<const float4*>(Asag + (size_t)blk * 80);
    const float*  cp = Acor + (size_t)blk * 112;
    float4* op = reinterpret_cast<float4*>(out + (size_t)blk * 8960);
    int t = threadIdx.x;
    for (int q = t; q < 2240; q += 256) {
        int h = q / 20, w4 = q % 20;
        float4 iv = ip[q], av = ap[q], sv = sp[w4];
        float cv = cp[h];
        float4 o;
        o.x = iv.x + av.x + sv.x + cv;
        o.y = iv.y + av.y + sv.y + cv;
        o.z = iv.z + av.z + sv.z + cv;
        o.w = iv.w + av.w + sv.w + cv;
        op[q] = o;
    }
}

extern "C" void kernel_launch(void* const* d_in, const int* in_sizes, int n_in,
                              void* d_out, int out_size, void* d_ws, size_t ws_size,
                              hipStream_t stream) {
    (void)in_sizes; (void)n_in; (void)out_size; (void)ws_size;
    const float* img    = (const float*)d_in[0];
    const float* txt    = (const float*)d_in[1];
    const float* pe_w[3] = {(const float*)d_in[2], (const float*)d_in[4], (const float*)d_in[6]};
    const float* pe_b[3] = {(const float*)d_in[3], (const float*)d_in[5], (const float*)d_in[7]};
    const float* pos[3]  = {(const float*)d_in[8], (const float*)d_in[9], (const float*)d_in[10]};
    const float* qw = (const float*)d_in[11];
    const float* kw = (const float*)d_in[12];
    const float* vw_attn = (const float*)d_in[13];
    const float* pw = (const float*)d_in[14];
    const float* pb = (const float*)d_in[15];
    const float* caq_w = (const float*)d_in[16];
    const float* caq_b = (const float*)d_in[17];
    const float* cak_w = (const float*)d_in[18];
    const float* cak_b = (const float*)d_in[19];
    const float* cav_w = (const float*)d_in[20];
    const float* cav_b = (const float*)d_in[21];
    const float* cao_w = (const float*)d_in[22];
    const float* cao_b = (const float*)d_in[23];
    const float* mlp_w1 = (const float*)d_in[24];
    const float* mlp_b1 = (const float*)d_in[25];
    const float* mlp_w2 = (const float*)d_in[26];
    const float* mlp_b2 = (const float*)d_in[27];
    const float* ow[3] = {(const float*)d_in[28], (const float*)d_in[30], (const float*)d_in[32]};
    const float* ob[3] = {(const float*)d_in[29], (const float*)d_in[31], (const float*)d_in[33]};
    const float* view_w = (const float*)d_in[34];
    const float* n_g[3] = {(const float*)d_in[35], (const float*)d_in[36], (const float*)d_in[37]};
    const float* n_b[3] = {(const float*)d_in[38], (const float*)d_in[39], (const float*)d_in[40]};

    typedef unsigned short u16t;
    unsigned char* sb = (unsigned char*)d_out;
    size_t off = 0;
    auto B = [&](size_t bytes) -> void* {
        void* p = sb + off; off += (bytes + 511) & ~(size_t)511; return p;
    };
    u16t* qkvT  = (u16t*)B((size_t)2304*768*2);
    u16t* pwT   = (u16t*)B(768*768*2);
    u16t* caqT  = (u16t*)B(768*768*2);
    u16t* cakvT = (u16t*)B((size_t)1536*768*2);
    u16t* caoT  = (u16t*)B(768*768*2);
    u16t* mlp1T = (u16t*)B((size_t)3072*768*2);
    u16t* mlp2T = (u16t*)B((size_t)768*3072*2);
    u16t* peT[3]; peT[0] = (u16t*)B((size_t)768*1120*2); peT[1] = (u16t*)B((size_t)768*1120*2); peT[2] = (u16t*)B((size_t)768*1568*2);
    u16t* owT[3]; owT[0] = (u16t*)B((size_t)1120*768*2); owT[1] = (u16t*)B((size_t)1120*768*2); owT[2] = (u16t*)B((size_t)1568*768*2);
    float* axp   = (float*)B((size_t)16*573440*4);
    float* m_sag = (float*)B(573440*4);
    float* m_cor = (float*)B(802816*4);
    u16t* P0 = (u16t*)B((size_t)512*1120*2);
    u16t* P1 = (u16t*)B((size_t)512*1120*2);
    u16t* P2 = (u16t*)B((size_t)512*1568*2);
    float* X0  = (float*)B((size_t)1536*768*4);
    float* X1f = (float*)B((size_t)1536*768*4);
    float* X2  = (float*)B((size_t)1536*768*4);
    float* X3f = (float*)B((size_t)1536*768*4);
    float* X4  = (float*)B((size_t)1536*768*4);
    u16t* X1b = (u16t*)B((size_t)1536*768*2);
    u16t* X3b = (u16t*)B((size_t)1536*768*2);
    u16t* X5b = (u16t*)B((size_t)1536*768*2);
    u16t* X6b = (u16t*)B((size_t)1536*768*2);
    u16t* QKVb = (u16t*)B((size_t)1536*2304*2);
    u16t* Obf = (u16t*)B((size_t)1536*768*2);
    u16t* Vt  = (u16t*)B((size_t)72*64*256*2);
    u16t* Hb  = (u16t*)B((size_t)1536*3072*2);
    u16t* KVHb = (u16t*)B((size_t)1536*1536*2);
    u16t* QHb  = (u16t*)B((size_t)154*768*2);

    float* ws = (float*)d_ws;
    float* Aax  = ws;
    float* Asag = ws + 573440;
    float* Acor = ws + 1146880;

    // ---- batched weight transposes (1 launch) ----
    TT tab;
    {
        const float* ins[16] = {qw, kw, vw_attn, pw, caq_w, cak_w, cav_w, cao_w,
                                mlp_w1, mlp_w2, pe_w[0], pe_w[1], pe_w[2], ow[0], ow[1], ow[2]};
        u16t* outs[16] = {qkvT, qkvT + 768*768, qkvT + 2*768*768, pwT, caqT, cakvT,
                          cakvT + 768*768, caoT, mlp1T, mlp2T, peT[0], peT[1], peT[2],
                          owT[0], owT[1], owT[2]};
        int Ks[16] = {768,768,768,768,768,768,768,768, 768,3072, 1120,1120,1568, 768,768,768};
        int Ns[16] = {768,768,768,768,768,768,768,768, 3072,768, 768,768,768, 1120,1120,1568};
        int st = 0;
        for (int i = 0; i < 16; ++i) {
            tab.in[i] = ins[i]; tab.out[i] = outs[i]; tab.K[i] = Ks[i]; tab.N[i] = Ns[i];
            tab.start[i] = st;
            st += (Ks[i] >> 5) * (Ns[i] >> 5);
        }
        transp_all<<<st, 256, 0, stream>>>(tab);
    }

    mean3_k<<<1024, 256, 0, stream>>>(img, axp, m_sag, m_cor);
    patchify3_k<<<dim3(224,3), 256, 0, stream>>>(axp, m_sag, m_cor, P0, P1, P2);

    // ---- cooperative trunk 1 ----
    {
        int occ = 0;
        hipOccupancyMaxActiveBlocksPerMultiprocessor(&occ, trunk1_k, 256, 0);
        if (occ < 1) occ = 1;
        int g1 = occ * 256; if (g1 > 512) g1 = 512;
        T1Args a;
        a.P[0] = P0; a.P[1] = P1; a.P[2] = P2;
        a.peT[0] = peT[0]; a.peT[1] = peT[1]; a.peT[2] = peT[2]; a.caqT = caqT;
        a.peb[0] = pe_b[0]; a.peb[1] = pe_b[1]; a.peb[2] = pe_b[2]; a.caqb = caq_b;
        a.pos[0] = pos[0]; a.pos[1] = pos[1]; a.pos[2] = pos[2];
        a.txt = txt; a.X0 = X0; a.QHb = QHb;
        a.g0 = n_g[0]; a.b0 = n_b[0]; a.X1f = X1f; a.X1b = X1b;
        a.qkvT = qkvT; a.QKVb = QKVb; a.Vt = Vt;
        a.K[0] = 1120; a.K[1] = 1120; a.K[2] = 1568; a.K[3] = 768;
        void* args[] = { (void*)&a };
        hipLaunchCooperativeKernel(reinterpret_cast<void*>(trunk1_k),
                                   dim3(g1), dim3(256), args, 0, stream);
    }

    attn_k<<<144, 256, 0, stream>>>(QKVb, Vt, Obf);

    // ---- cooperative trunk 2 ----
    {
        int occ = 0;
        hipOccupancyMaxActiveBlocksPerMultiprocessor(&occ, trunk2_k, 256, 0);
        if (occ < 1) occ = 1;
        int g2 = occ * 256; if (g2 > 512) g2 = 512;
        T2Args a;
        a.Obf = Obf; a.pwT = pwT; a.pb = pb; a.X1f = X1f; a.X2 = X2;
        a.g1 = n_g[1]; a.b1 = n_b[1]; a.X3f = X3f; a.X3b = X3b;
        a.cakvT = cakvT; a.cakb = cak_b; a.cavb = cav_b; a.KVHb = KVHb;
        a.QHb = QHb; a.Oca = Obf;
        a.caoT = caoT; a.caob = cao_b; a.X4 = X4;
        a.g2 = n_g[2]; a.b2 = n_b[2]; a.X5b = X5b;
        a.mlp1T = mlp1T; a.mb1 = mlp_b1; a.Hb = Hb;
        a.mlp2T = mlp2T; a.mb2 = mlp_b2; a.X6b = X6b;
        a.owT[0] = owT[0]; a.owT[1] = owT[1]; a.owT[2] = owT[2];
        a.ob[0] = ob[0]; a.ob[1] = ob[1]; a.ob[2] = ob[2];
        a.plane[0] = Aax; a.plane[1] = Asag; a.plane[2] = Acor;
        a.vw = view_w;
        void* args[] = { (void*)&a };
        hipLaunchCooperativeKernel(reinterpret_cast<void*>(trunk2_k),
                                   dim3(g2), dim3(256), args, 0, stream);
    }

    final_k<<<7168, 256, 0, stream>>>(img, Aax, Asag, Acor, (float*)d_out);
}

// Round 11
// 484.995 us; speedup vs baseline: 1.8249x; 1.8249x over previous
//
#include <hip/hip_runtime.h>
#include <math.h>

typedef __attribute__((ext_vector_type(8))) short s8;
typedef __attribute__((ext_vector_type(4))) float f4;
typedef unsigned short u16;

__device__ inline u16 f2bf(float f) {
    unsigned u = __float_as_uint(f);
    u += 0x7fffu + ((u >> 16) & 1u);
    return (u16)(u >> 16);
}
__device__ inline float bf2f(u16 x) {
    return __uint_as_float(((unsigned)x) << 16);
}
#define MFMA16(a, b, c) __builtin_amdgcn_mfma_f32_16x16x32_bf16(a, b, c, 0, 0, 0)

// ============ prep: weight transposes + axis means + stats zero (1 launch) ============
struct TT {
    const float* in[16];
    u16* out[16];
    int K[16];
    int N[16];
    int start[16];
    int total;          // total transpose tiles
};

__global__ __launch_bounds__(256) void prep_k(TT tab, const float* __restrict__ img,
                                              float* __restrict__ axp,
                                              float* __restrict__ sag,
                                              float* __restrict__ cor,
                                              float* __restrict__ stats) {
    __shared__ float sl[112*81];
    int bid = blockIdx.x;
    int t = threadIdx.x;
    if (bid < 1024) {
        // ---- mean3 ----
        int dc = bid & 15, bc = bid >> 4;
        int d0 = dc * 7;
        f4 axr[9];
        #pragma unroll
        for (int k = 0; k < 9; ++k) axr[k] = (f4){0.f,0.f,0.f,0.f};
        const float* base = img + (size_t)bc * 1003520 + (size_t)d0 * 8960;
        for (int sidx = 0; sidx < 7; ++sidx) {
            const f4* sp = reinterpret_cast<const f4*>(base + (size_t)sidx * 8960);
            #pragma unroll
            for (int k = 0; k < 9; ++k) {
                int q = t + k * 256;
                if (q < 2240) {
                    f4 v = sp[q];
                    axr[k] += v;
                    int h = q / 20, w4 = q % 20;
                    float* row = &sl[h * 81 + w4 * 4];
                    row[0] = v[0]; row[1] = v[1]; row[2] = v[2]; row[3] = v[3];
                }
            }
            __syncthreads();
            if (t < 112) {
                float acc = 0.f;
                #pragma unroll 8
                for (int w = 0; w < 80; ++w) acc += sl[t * 81 + w];
                cor[((size_t)bc * 112 + d0 + sidx) * 112 + t] = acc * (1.f / 80.f);
            } else if (t < 192) {
                int w = t - 112;
                float acc = 0.f;
                #pragma unroll 8
                for (int h = 0; h < 112; ++h) acc += sl[h * 81 + w];
                sag[((size_t)bc * 112 + d0 + sidx) * 80 + w] = acc * (1.f / 112.f);
            }
            __syncthreads();
        }
        float* axo = axp + ((size_t)dc * 64 + bc) * 8960;
        #pragma unroll
        for (int k = 0; k < 9; ++k) {
            int q = t + k * 256;
            if (q < 2240) *reinterpret_cast<f4*>(axo + q * 4) = axr[k];
        }
        return;
    }
    int tb = bid - 1024;
    if (tb < tab.total) {
        // ---- transpose tile ----
        float (*tl)[33] = reinterpret_cast<float(*)[33]>(sl);
        int e = 0;
        #pragma unroll
        for (int i = 1; i < 16; ++i) if (tb >= tab.start[i]) e = i;
        const float* in = tab.in[e];
        u16* out = tab.out[e];
        int K = tab.K[e], N = tab.N[e];
        int tid = tb - tab.start[e];
        int nt = N >> 5;
        int k0 = (tid / nt) * 32, n0 = (tid % nt) * 32;
        int r = t >> 5, c = t & 31;
        #pragma unroll
        for (int i = 0; i < 4; ++i) tl[r + i*8][c] = in[(long)(k0 + r + i*8)*N + n0 + c];
        __syncthreads();
        #pragma unroll
        for (int i = 0; i < 4; ++i) out[(long)(n0 + r + i*8)*K + k0 + c] = f2bf(tl[c][r + i*8]);
        return;
    }
    // ---- zero the 3 stats buffers: 3*1536*2 floats ----
    for (int i = t; i < 9216; i += 256) stats[i] = 0.f;
}

// ============ patchify, 3 branches; br0 sums ax partials ============
__global__ __launch_bounds__(256) void patchify3_k(const float* __restrict__ axp,
                                                   const float* __restrict__ m_sag,
                                                   const float* __restrict__ m_cor,
                                                   u16* __restrict__ P0, u16* __restrict__ P1,
                                                   u16* __restrict__ P2) {
    __shared__ float sl[32][113];
    int br = blockIdx.y;
    int X = blockIdx.x;
    int b = X / 112, rem = X % 112;
    int hh = rem / 7, pp1 = rem % 7;
    const float* src; u16* dst; int Wt, p2, PD;
    if (br == 0)      { src = nullptr; dst = P0; Wt = 80;  p2 = 5; PD = 1120; }
    else if (br == 1) { src = m_sag;   dst = P1; Wt = 80;  p2 = 5; PD = 1120; }
    else              { src = m_cor;   dst = P2; Wt = 112; p2 = 7; PD = 1568; }
    int t = threadIdx.x;
    int row = hh*7 + pp1;
    int wq = Wt >> 2;
    if (br == 0) {
        for (int i = t; i < 32*20; i += 256) {
            int c = i / 20, w4 = i % 20;
            f4 s = (f4){0.f,0.f,0.f,0.f};
            size_t base = ((size_t)(b*32 + c)*112 + row)*80 + w4*4;
            #pragma unroll
            for (int p = 0; p < 16; ++p)
                s += *reinterpret_cast<const f4*>(axp + (size_t)p*573440 + base);
            s *= (1.f/112.f);
            sl[c][w4*4+0] = s[0]; sl[c][w4*4+1] = s[1]; sl[c][w4*4+2] = s[2]; sl[c][w4*4+3] = s[3];
        }
    } else {
        for (int i = t; i < 32*wq; i += 256) {
            int c = i / wq, w4 = i % wq;
            float4 v = *reinterpret_cast<const float4*>(
                src + ((size_t)(b*32 + c)*112 + row)*Wt + w4*4);
            sl[c][w4*4+0] = v.x; sl[c][w4*4+1] = v.y; sl[c][w4*4+2] = v.z; sl[c][w4*4+3] = v.w;
        }
    }
    __syncthreads();
    int tot = 16 * p2 * 32;
    for (int o = t; o < tot; o += 256) {
        int ww = o / (p2*32), rest = o % (p2*32);
        int pp2 = rest >> 5, c = rest & 31;
        dst[((size_t)(b*256 + hh*16 + ww))*PD + (pp1*p2 + pp2)*32 + c]
            = f2bf(sl[c][ww*p2 + pp2]);
    }
}

// ============ GEMM building blocks ============
__device__ inline void load_tile(const u16* __restrict__ P, int ld, int nrows, int K,
                                 int r0, int k0, int t, s8 v[4]) {
    #pragma unroll
    for (int i = 0; i < 4; ++i) {
        int chunk = t + i*256;
        int row = chunk >> 4, c8 = (chunk & 15) * 8;
        s8 x;
        #pragma unroll
        for (int q = 0; q < 8; ++q) x[q] = 0;
        if (r0 + row < nrows && k0 + c8 < K)
            x = *reinterpret_cast<const s8*>(P + (long)(r0 + row)*ld + k0 + c8);
        v[i] = x;
    }
}
__device__ inline void load_tile_f32(const float* __restrict__ P, int ld, int nrows, int K,
                                     int r0, int k0, int t, s8 v[4]) {
    #pragma unroll
    for (int i = 0; i < 4; ++i) {
        int chunk = t + i*256;
        int row = chunk >> 4, c8 = (chunk & 15) * 8;
        s8 x;
        #pragma unroll
        for (int q = 0; q < 8; ++q) x[q] = 0;
        if (r0 + row < nrows && k0 + c8 < K) {
            const float* src = P + (long)(r0 + row)*ld + k0 + c8;
            #pragma unroll
            for (int q = 0; q < 8; ++q) x[q] = (short)f2bf(src[q]);
        }
        v[i] = x;
    }
}
__device__ inline void write_tile(u16 (*S)[136], int t, const s8 v[4]) {
    #pragma unroll
    for (int i = 0; i < 4; ++i) {
        int chunk = t + i*256;
        *reinterpret_cast<s8*>(&S[chunk >> 4][(chunk & 15)*8]) = v[i];
    }
}
__device__ inline void mfma_tile(const u16 (*As)[136], const u16 (*Bs)[136],
                                 int wr, int wc, int lane, f4 acc[2][2]) {
    int lrow = lane & 15;
    #pragma unroll
    for (int kh = 0; kh < 4; ++kh) {
        int lk = kh*32 + (lane >> 4) * 8;
        s8 af0 = *reinterpret_cast<const s8*>(&As[wr*32 + lrow][lk]);
        s8 af1 = *reinterpret_cast<const s8*>(&As[wr*32 + 16 + lrow][lk]);
        s8 bg0 = *reinterpret_cast<const s8*>(&Bs[wc*32 + lrow][lk]);
        s8 bg1 = *reinterpret_cast<const s8*>(&Bs[wc*32 + 16 + lrow][lk]);
        acc[0][0] = MFMA16(af0, bg0, acc[0][0]);
        acc[0][1] = MFMA16(af0, bg1, acc[0][1]);
        acc[1][0] = MFMA16(af1, bg0, acc[1][0]);
        acc[1][1] = MFMA16(af1, bg1, acc[1][1]);
    }
}
__device__ inline void ln_params(const float* stats, int row, float& mean, float& rstd) {
    float su = stats[row*2], sq = stats[row*2+1];
    mean = su * (1.f/768.f);
    rstd = rsqrtf(sq * (1.f/768.f) - mean*mean + 1e-5f);
}

// ============ bf16 MFMA GEMM (64-tile) with LN-resid + stats emission ============
__global__ __launch_bounds__(256) void gemm_bf(
    const u16* __restrict__ A, const u16* __restrict__ Bt,
    float* __restrict__ Cf, u16* __restrict__ Cb,
    int M, int N, int K,
    const float* __restrict__ bias,
    const float* __restrict__ resid,    // plain resid OR LN source (if rstats)
    const float* __restrict__ rstats, const float* __restrict__ rg,
    const float* __restrict__ rb,
    float* __restrict__ stats_out,
    int act)
{
    __shared__ u16 As[2][64][136];
    __shared__ u16 Bs[2][64][136];
    int t = threadIdx.x;
    int m0 = blockIdx.y * 64, n0 = blockIdx.x * 64;
    int wave = t >> 6, lane = t & 63;
    int wr = wave >> 1, wc = wave & 1;
    int lr = lane & 15;
    f4 acc[2][2];
    #pragma unroll
    for (int m = 0; m < 2; ++m)
        #pragma unroll
        for (int n = 0; n < 2; ++n)
            #pragma unroll
            for (int r = 0; r < 4; ++r) acc[m][n][r] = 0.f;
    int nk = (K + 127) >> 7;
    s8 pa[4], pbv[4];
    load_tile(A, K, M, K, m0, 0, t, pa);
    load_tile(Bt, K, N, K, n0, 0, t, pbv);
    write_tile(As[0], t, pa);
    write_tile(Bs[0], t, pbv);
    __syncthreads();
    for (int kt = 0; kt < nk; ++kt) {
        int cur = kt & 1;
        if (kt + 1 < nk) {
            load_tile(A, K, M, K, m0, (kt+1) << 7, t, pa);
            load_tile(Bt, K, N, K, n0, (kt+1) << 7, t, pbv);
        }
        mfma_tile(As[cur], Bs[cur], wr, wc, lane, acc);
        if (kt + 1 < nk) {
            write_tile(As[cur^1], t, pa);
            write_tile(Bs[cur^1], t, pbv);
        }
        __syncthreads();
    }
    float ps[2][4], psq[2][4];
    #pragma unroll
    for (int m = 0; m < 2; ++m)
        #pragma unroll
        for (int r = 0; r < 4; ++r) { ps[m][r] = 0.f; psq[m][r] = 0.f; }
    #pragma unroll
    for (int m = 0; m < 2; ++m) {
        int rbase = m0 + wr*32 + m*16 + (lane >> 4) * 4;
        #pragma unroll
        for (int n = 0; n < 2; ++n) {
            int col = n0 + wc*32 + n*16 + lr;
            if (col >= N) continue;
            #pragma unroll
            for (int r = 0; r < 4; ++r) {
                int row = rbase + r;
                if (row >= M) continue;
                float v = acc[m][n][r];
                if (bias)  v += bias[col];
                if (rstats) {
                    float mean, rstd;
                    ln_params(rstats, row, mean, rstd);
                    v += (resid[(long)row * N + col] - mean) * rstd * rg[col] + rb[col];
                } else if (resid) {
                    v += resid[(long)row * N + col];
                }
                if (act == 1) v = 0.5f * v * (1.0f + erff(v * 0.70710678118654752f));
                long ci = (long)row * N + col;
                if (Cf) Cf[ci] = v;
                if (Cb) Cb[ci] = f2bf(v);
                ps[m][r] += v; psq[m][r] += v*v;
            }
        }
    }
    if (stats_out) {
        #pragma unroll
        for (int m = 0; m < 2; ++m) {
            int rbase = m0 + wr*32 + m*16 + (lane >> 4) * 4;
            #pragma unroll
            for (int r = 0; r < 4; ++r) {
                float p = ps[m][r], q = psq[m][r];
                #pragma unroll
                for (int o = 1; o < 16; o <<= 1) {
                    p += __shfl_xor(p, o);
                    q += __shfl_xor(q, o);
                }
                if (lr == 0) {
                    int row = rbase + r;
                    if (row < M) {
                        atomicAdd(&stats_out[row*2],   p);
                        atomicAdd(&stats_out[row*2+1], q);
                    }
                }
            }
        }
    }
}

// ============ big-tile GEMM: BM=BN=128, BK=64; A = fp32 with inline LN ============
__global__ __launch_bounds__(256) void gemm_big(
    const float* __restrict__ A32, const float* __restrict__ astats,
    const float* __restrict__ ag, const float* __restrict__ ab,
    const u16* __restrict__ Bt, u16* __restrict__ Cb, u16* __restrict__ vt,
    int N, const float* __restrict__ bias, const float* __restrict__ bias2, int act)
{
    __shared__ u16 As[2][128][72];
    __shared__ u16 Bs[2][128][72];
    constexpr int K = 768;
    int t = threadIdx.x;
    int m0 = blockIdx.y * 128, n0 = blockIdx.x * 128;
    int wave = t >> 6, lane = t & 63;
    int wr = wave >> 1, wc = wave & 1;
    f4 acc[4][4];
    #pragma unroll
    for (int m = 0; m < 4; ++m)
        #pragma unroll
        for (int n = 0; n < 4; ++n)
            #pragma unroll
            for (int r = 0; r < 4; ++r) acc[m][n][r] = 0.f;
    s8 pa[4], pbv[4];
    auto loadA = [&](int k0, int i) -> s8 {
        int chunk = t + i*256;
        int row = m0 + (chunk>>3);
        int kk = k0 + (chunk&7)*8;
        float mean, rstd;
        ln_params(astats, row, mean, rstd);
        const float* src = A32 + (long)row*K + kk;
        s8 x;
        #pragma unroll
        for (int q = 0; q < 8; ++q)
            x[q] = (short)f2bf((src[q]-mean)*rstd*ag[kk+q] + ab[kk+q]);
        return x;
    };
    #pragma unroll
    for (int i = 0; i < 4; ++i) {
        int chunk = t + i*256;
        pa[i]  = loadA(0, i);
        pbv[i] = *reinterpret_cast<const s8*>(Bt + (long)(n0 + (chunk>>3))*K + (chunk&7)*8);
    }
    #pragma unroll
    for (int i = 0; i < 4; ++i) {
        int chunk = t + i*256;
        *reinterpret_cast<s8*>(&As[0][chunk>>3][(chunk&7)*8]) = pa[i];
        *reinterpret_cast<s8*>(&Bs[0][chunk>>3][(chunk&7)*8]) = pbv[i];
    }
    __syncthreads();
    for (int kt = 0; kt < 12; ++kt) {
        int cur = kt & 1;
        if (kt + 1 < 12) {
            int k0 = (kt+1) << 6;
            #pragma unroll
            for (int i = 0; i < 4; ++i) {
                int chunk = t + i*256;
                pa[i]  = loadA(k0, i);
                pbv[i] = *reinterpret_cast<const s8*>(Bt + (long)(n0 + (chunk>>3))*K + k0 + (chunk&7)*8);
            }
        }
        #pragma unroll
        for (int kh = 0; kh < 2; ++kh) {
            int lk = kh*32 + (lane >> 4) * 8;
            int lr = lane & 15;
            s8 af[4], bf[4];
            #pragma unroll
            for (int m = 0; m < 4; ++m)
                af[m] = *reinterpret_cast<const s8*>(&As[cur][wr*64 + m*16 + lr][lk]);
            #pragma unroll
            for (int n = 0; n < 4; ++n)
                bf[n] = *reinterpret_cast<const s8*>(&Bs[cur][wc*64 + n*16 + lr][lk]);
            #pragma unroll
            for (int m = 0; m < 4; ++m)
                #pragma unroll
                for (int n = 0; n < 4; ++n)
                    acc[m][n] = MFMA16(af[m], bf[n], acc[m][n]);
        }
        if (kt + 1 < 12) {
            #pragma unroll
            for (int i = 0; i < 4; ++i) {
                int chunk = t + i*256;
                *reinterpret_cast<s8*>(&As[cur^1][chunk>>3][(chunk&7)*8]) = pa[i];
                *reinterpret_cast<s8*>(&Bs[cur^1][chunk>>3][(chunk&7)*8]) = pbv[i];
            }
        }
        __syncthreads();
    }
    #pragma unroll
    for (int m = 0; m < 4; ++m) {
        int rbase = m0 + wr*64 + m*16 + (lane >> 4) * 4;
        #pragma unroll
        for (int n = 0; n < 4; ++n) {
            int col = n0 + wc*64 + n*16 + (lane & 15);
            #pragma unroll
            for (int r = 0; r < 4; ++r) {
                int row = rbase + r;
                float v = acc[m][n][r];
                if (bias) {
                    float bb = bias2 ? ((col < 768) ? bias[col] : bias2[col - 768]) : bias[col];
                    v += bb;
                }
                if (act == 1) v = 0.5f * v * (1.0f + erff(v * 0.70710678118654752f));
                u16 b = f2bf(v);
                Cb[(long)row * N + col] = b;
                if (vt && col >= 1536) {
                    int z = (row >> 8) * 12 + ((col - 1536) >> 6);
                    vt[((long)z * 64 + (col & 63)) * 256 + (row & 255)] = b;
                }
            }
        }
    }
}

// ============ batched patch-embed (+QH from fp32 txt) GEMM, emits LN1 stats ============
struct PeDesc {
    const u16* A[3];
    const u16* Bt[4];
    const float* bias[4];
    const float* pos[3];
    int K[4];
    int M[4];
};

__global__ __launch_bounds__(256) void gemm_pe(PeDesc d, const float* __restrict__ txtf,
                                               float* __restrict__ C, u16* __restrict__ QHb,
                                               float* __restrict__ stats1) {
    int z = blockIdx.z;
    int M = d.M[z], K = d.K[z];
    int m0 = blockIdx.y * 64, n0 = blockIdx.x * 64;
    if (m0 >= M) return;
    __shared__ u16 As[2][64][136];
    __shared__ u16 Bs[2][64][136];
    const u16* Bb = d.Bt[z];
    const float* bias = d.bias[z];
    int t = threadIdx.x;
    int wave = t >> 6, lane = t & 63;
    int wr = wave >> 1, wc = wave & 1;
    int lr = lane & 15;
    f4 acc[2][2];
    #pragma unroll
    for (int m = 0; m < 2; ++m)
        #pragma unroll
        for (int n = 0; n < 2; ++n)
            #pragma unroll
            for (int r = 0; r < 4; ++r) acc[m][n][r] = 0.f;
    int nk = (K + 127) >> 7;
    s8 pa[4], pbv[4];
    if (z < 3) load_tile(d.A[z], K, M, K, m0, 0, t, pa);
    else       load_tile_f32(txtf, K, M, K, m0, 0, t, pa);
    load_tile(Bb, K, 768, K, n0, 0, t, pbv);
    write_tile(As[0], t, pa);
    write_tile(Bs[0], t, pbv);
    __syncthreads();
    for (int kt = 0; kt < nk; ++kt) {
        int cur = kt & 1;
        if (kt + 1 < nk) {
            if (z < 3) load_tile(d.A[z], K, M, K, m0, (kt+1) << 7, t, pa);
            else       load_tile_f32(txtf, K, M, K, m0, (kt+1) << 7, t, pa);
            load_tile(Bb, K, 768, K, n0, (kt+1) << 7, t, pbv);
        }
        mfma_tile(As[cur], Bs[cur], wr, wc, lane, acc);
        if (kt + 1 < nk) {
            write_tile(As[cur^1], t, pa);
            write_tile(Bs[cur^1], t, pbv);
        }
        __syncthreads();
    }
    float ps[2][4], psq[2][4];
    #pragma unroll
    for (int m = 0; m < 2; ++m)
        #pragma unroll
        for (int r = 0; r < 4; ++r) { ps[m][r] = 0.f; psq[m][r] = 0.f; }
    #pragma unroll
    for (int m = 0; m < 2; ++m) {
        int rbase = m0 + wr*32 + m*16 + (lane >> 4) * 4;
        #pragma unroll
        for (int n = 0; n < 2; ++n) {
            int col = n0 + wc*32 + n*16 + lr;
            #pragma unroll
            for (int r = 0; r < 4; ++r) {
                int row = rbase + r;
                if (row >= M) continue;
                float v = acc[m][n][r] + bias[col];
                if (z < 3) {
                    v += d.pos[z][(long)(row & 255)*768 + col];
                    C[((long)z*512 + row) * 768 + col] = v;
                    ps[m][r] += v; psq[m][r] += v*v;
                } else {
                    QHb[(long)row * 768 + col] = f2bf(v);
                }
            }
        }
    }
    if (z < 3) {
        #pragma unroll
        for (int m = 0; m < 2; ++m) {
            int rbase = m0 + wr*32 + m*16 + (lane >> 4) * 4;
            #pragma unroll
            for (int r = 0; r < 4; ++r) {
                float p = ps[m][r], q = psq[m][r];
                #pragma unroll
                for (int o = 1; o < 16; o <<= 1) {
                    p += __shfl_xor(p, o);
                    q += __shfl_xor(q, o);
                }
                if (lr == 0) {
                    int grow = z*512 + rbase + r;
                    atomicAdd(&stats1[grow*2],   p);
                    atomicAdd(&stats1[grow*2+1], q);
                }
            }
        }
    }
}

// ============ output-proj GEMM + fused unpatchify ============
struct OwDesc {
    const u16* Bt[3];
    float* plane[3];
    const float* bias[3];
    int N[3];
    int p2[3];
    int Wd[3];
};

__global__ __launch_bounds__(256) void gemm_ow(OwDesc d, const u16* __restrict__ A,
                                               const float* __restrict__ vwp) {
    int z = blockIdx.z;
    int N = d.N[z];
    int n0 = blockIdx.x * 64;
    if (n0 >= N) return;
    __shared__ u16 As[2][64][136];
    __shared__ u16 Bs[2][64][136];
    const u16* Ab = A + (long)z * 512 * 768;
    const u16* Bb = d.Bt[z];
    int t = threadIdx.x;
    int m0 = blockIdx.y * 64;
    int wave = t >> 6, lane = t & 63;
    int wr = wave >> 1, wc = wave & 1;
    f4 acc[2][2];
    #pragma unroll
    for (int m = 0; m < 2; ++m)
        #pragma unroll
        for (int n = 0; n < 2; ++n)
            #pragma unroll
            for (int r = 0; r < 4; ++r) acc[m][n][r] = 0.f;
    s8 pa[4], pbv[4];
    load_tile(Ab, 768, 512, 768, m0, 0, t, pa);
    load_tile(Bb, 768, N, 768, n0, 0, t, pbv);
    write_tile(As[0], t, pa);
    write_tile(Bs[0], t, pbv);
    __syncthreads();
    for (int kt = 0; kt < 6; ++kt) {
        int cur = kt & 1;
        if (kt + 1 < 6) {
            load_tile(Ab, 768, 512, 768, m0, (kt+1) << 7, t, pa);
            load_tile(Bb, 768, N, 768, n0, (kt+1) << 7, t, pbv);
        }
        mfma_tile(As[cur], Bs[cur], wr, wc, lane, acc);
        if (kt + 1 < 6) {
            write_tile(As[cur^1], t, pa);
            write_tile(Bs[cur^1], t, pbv);
        }
        __syncthreads();
    }
    float* plane = d.plane[z];
    const float* bias = d.bias[z];
    int p2 = d.p2[z], Wd = d.Wd[z];
    float wt = vwp[z];
    #pragma unroll
    for (int m = 0; m < 2; ++m) {
        int rbase = m0 + wr*32 + m*16 + (lane >> 4) * 4;
        #pragma unroll
        for (int n = 0; n < 2; ++n) {
            int col = n0 + wc*32 + n*16 + (lane & 15);
            if (col >= N) continue;
            int pp = col >> 5, c = col & 31;
            int pp1 = pp / p2, pp2 = pp % p2;
            float bv = bias[col];
            #pragma unroll
            for (int r = 0; r < 4; ++r) {
                int row = rbase + r;
                int b = row >> 8, nn = row & 255;
                int hh = nn >> 4, ww = nn & 15;
                plane[((long)(b*32 + c)*112 + hh*7 + pp1)*Wd + ww*p2 + pp2]
                    = wt * (acc[m][n][r] + bv);
            }
        }
    }
}

// ============ fully fused self-attention ============
__global__ __launch_bounds__(256) void attn_k(const u16* __restrict__ QKV,
                                              const u16* __restrict__ Vt,
                                              u16* __restrict__ O) {
    __shared__ u16 Ks[256][72];
    __shared__ u16 Ps[128][264];
    __shared__ u16 Vs[64][264];
    int zz = blockIdx.x;
    int bh = zz >> 1, half = zz & 1;
    int bb = bh / 12, h = bh % 12;
    long qrow0 = (long)bb*256 + half*128;
    int hcol = h*64;
    int t = threadIdx.x;
    int wave = t >> 6, lane = t & 63;
    int lr = lane & 15, lg = lane >> 4;
    #pragma unroll
    for (int i = 0; i < 8; ++i) {
        int chunk = t + i*256;
        int row = chunk >> 3, c8 = (chunk & 7)*8;
        *reinterpret_cast<s8*>(&Ks[row][c8]) =
            *reinterpret_cast<const s8*>(QKV + ((long)bb*256 + row)*2304 + 768 + hcol + c8);
    }
    #pragma unroll
    for (int i = 0; i < 8; ++i) {
        int chunk = t + i*256;
        int d = chunk >> 5, j8 = (chunk & 31)*8;
        *reinterpret_cast<s8*>(&Vs[d][j8]) =
            *reinterpret_cast<const s8*>(Vt + (long)bh*16384 + (long)d*256 + j8);
    }
    __syncthreads();
    f4 acc[2][16];
    #pragma unroll
    for (int m = 0; m < 2; ++m)
        #pragma unroll
        for (int n = 0; n < 16; ++n)
            #pragma unroll
            for (int r = 0; r < 4; ++r) acc[m][n][r] = 0.f;
    #pragma unroll
    for (int kh = 0; kh < 2; ++kh) {
        s8 af0 = *reinterpret_cast<const s8*>(QKV + (qrow0 + wave*32 + lr)*2304 + hcol + kh*32 + lg*8);
        s8 af1 = *reinterpret_cast<const s8*>(QKV + (qrow0 + wave*32 + 16 + lr)*2304 + hcol + kh*32 + lg*8);
        #pragma unroll
        for (int n = 0; n < 16; ++n) {
            s8 bf = *reinterpret_cast<const s8*>(&Ks[n*16 + lr][kh*32 + lg*8]);
            acc[0][n] = MFMA16(af0, bf, acc[0][n]);
            acc[1][n] = MFMA16(af1, bf, acc[1][n]);
        }
    }
    #pragma unroll
    for (int m = 0; m < 2; ++m)
        #pragma unroll
        for (int r = 0; r < 4; ++r) {
            float mx = -1e30f;
            #pragma unroll
            for (int n = 0; n < 16; ++n) mx = fmaxf(mx, acc[m][n][r]);
            #pragma unroll
            for (int o = 8; o; o >>= 1) mx = fmaxf(mx, __shfl_xor(mx, o));
            float l = 0.f;
            float p[16];
            #pragma unroll
            for (int n = 0; n < 16; ++n) {
                p[n] = __expf((acc[m][n][r] - mx) * 0.125f);
                l += p[n];
            }
            #pragma unroll
            for (int o = 8; o; o >>= 1) l += __shfl_xor(l, o);
            float inv = 1.f / l;
            int prow = wave*32 + m*16 + lg*4 + r;
            #pragma unroll
            for (int n = 0; n < 16; ++n)
                Ps[prow][n*16 + lr] = f2bf(p[n] * inv);
        }
    __syncthreads();
    f4 o2[2][4];
    #pragma unroll
    for (int m = 0; m < 2; ++m)
        #pragma unroll
        for (int n = 0; n < 4; ++n)
            #pragma unroll
            for (int r = 0; r < 4; ++r) o2[m][n][r] = 0.f;
    #pragma unroll
    for (int kh = 0; kh < 8; ++kh) {
        s8 pf0 = *reinterpret_cast<const s8*>(&Ps[wave*32 + lr][kh*32 + lg*8]);
        s8 pf1 = *reinterpret_cast<const s8*>(&Ps[wave*32 + 16 + lr][kh*32 + lg*8]);
        #pragma unroll
        for (int n = 0; n < 4; ++n) {
            s8 vf = *reinterpret_cast<const s8*>(&Vs[n*16 + lr][kh*32 + lg*8]);
            o2[0][n] = MFMA16(pf0, vf, o2[0][n]);
            o2[1][n] = MFMA16(pf1, vf, o2[1][n]);
        }
    }
    #pragma unroll
    for (int m = 0; m < 2; ++m)
        #pragma unroll
        for (int n = 0; n < 4; ++n)
            #pragma unroll
            for (int r = 0; r < 4; ++r)
                O[(qrow0 + wave*32 + m*16 + lg*4 + r)*768 + hcol + n*16 + lr] = f2bf(o2[m][n][r]);
}

// ============ fully fused cross-attention ============
__global__ __launch_bounds__(256) void ca_fused(const u16* __restrict__ QHb,
                                                const u16* __restrict__ KVHb,
                                                u16* __restrict__ O) {
    __shared__ u16 QHs[80][72];
    __shared__ u16 KHs[256][72];
    __shared__ float rmax[80][4];
    __shared__ float rsum[80][4];
    __shared__ float Wj[256];
    int bh = blockIdx.x;
    int rowblk = bh / 12, h = bh % 12;
    int bsel = rowblk & 1;
    int t = threadIdx.x;
    int wave = t >> 6, lane = t & 63;
    int lr = lane & 15, lg = lane >> 4;
    #pragma unroll
    for (int i = 0; i < 3; ++i) {
        int chunk = t + i*256;
        if (chunk < 640) {
            int row = chunk >> 3, c8 = (chunk & 7)*8;
            s8 v;
            #pragma unroll
            for (int q = 0; q < 8; ++q) v[q] = 0;
            if (row < 77)
                v = *reinterpret_cast<const s8*>(QHb + ((long)(bsel*77 + row))*768 + h*64 + c8);
            *reinterpret_cast<s8*>(&QHs[row][c8]) = v;
        }
    }
    #pragma unroll
    for (int i = 0; i < 8; ++i) {
        int chunk = t + i*256;
        int row = chunk >> 3, c8 = (chunk & 7)*8;
        *reinterpret_cast<s8*>(&KHs[row][c8]) =
            *reinterpret_cast<const s8*>(KVHb + ((long)rowblk*256 + row)*1536 + h*64 + c8);
    }
    __syncthreads();
    f4 acc[5][4];
    #pragma unroll
    for (int m = 0; m < 5; ++m)
        #pragma unroll
        for (int n = 0; n < 4; ++n)
            #pragma unroll
            for (int r = 0; r < 4; ++r) acc[m][n][r] = 0.f;
    #pragma unroll
    for (int kh = 0; kh < 2; ++kh) {
        s8 af[5], bf[4];
        #pragma unroll
        for (int m = 0; m < 5; ++m)
            af[m] = *reinterpret_cast<const s8*>(&QHs[m*16 + lr][kh*32 + lg*8]);
        #pragma unroll
        for (int n = 0; n < 4; ++n)
            bf[n] = *reinterpret_cast<const s8*>(&KHs[wave*64 + n*16 + lr][kh*32 + lg*8]);
        #pragma unroll
        for (int m = 0; m < 5; ++m)
            #pragma unroll
            for (int n = 0; n < 4; ++n)
                acc[m][n] = MFMA16(af[m], bf[n], acc[m][n]);
    }
    #pragma unroll
    for (int m = 0; m < 5; ++m)
        #pragma unroll
        for (int r = 0; r < 4; ++r) {
            float mx = -1e30f;
            #pragma unroll
            for (int n = 0; n < 4; ++n) mx = fmaxf(mx, acc[m][n][r]);
            #pragma unroll
            for (int o = 8; o; o >>= 1) mx = fmaxf(mx, __shfl_xor(mx, o));
            if (lr == 0) rmax[m*16 + lg*4 + r][wave] = mx;
        }
    __syncthreads();
    #pragma unroll
    for (int m = 0; m < 5; ++m)
        #pragma unroll
        for (int r = 0; r < 4; ++r) {
            int i = m*16 + lg*4 + r;
            float mi = fmaxf(fmaxf(rmax[i][0], rmax[i][1]), fmaxf(rmax[i][2], rmax[i][3]));
            float s = 0.f;
            #pragma unroll
            for (int n = 0; n < 4; ++n) s += __expf((acc[m][n][r] - mi) * 0.125f);
            #pragma unroll
            for (int o = 8; o; o >>= 1) s += __shfl_xor(s, o);
            if (lr == 0) rsum[i][wave] = s;
        }
    __syncthreads();
    float wn[4] = {0.f, 0.f, 0.f, 0.f};
    #pragma unroll
    for (int m = 0; m < 5; ++m)
        #pragma unroll
        for (int r = 0; r < 4; ++r) {
            int i = m*16 + lg*4 + r;
            if (i < 77) {
                float mi = fmaxf(fmaxf(rmax[i][0], rmax[i][1]), fmaxf(rmax[i][2], rmax[i][3]));
                float li = rsum[i][0] + rsum[i][1] + rsum[i][2] + rsum[i][3];
                float inv = 1.f / li;
                #pragma unroll
                for (int n = 0; n < 4; ++n)
                    wn[n] += __expf((acc[m][n][r] - mi) * 0.125f) * inv;
            }
        }
    #pragma unroll
    for (int n = 0; n < 4; ++n) {
        wn[n] += __shfl_xor(wn[n], 16);
        wn[n] += __shfl_xor(wn[n], 32);
    }
    if (lane < 16) {
        #pragma unroll
        for (int n = 0; n < 4; ++n) Wj[wave*64 + n*16 + lr] = wn[n];
    }
    __syncthreads();
    int d = t & 63;
    #pragma unroll 4
    for (int it = 0; it < 64; ++it) {
        int j = it*4 + (t >> 6);
        long row = (long)rowblk*256 + j;
        float vh = bf2f(KVHb[row*1536 + 768 + h*64 + d]);
        O[row*768 + h*64 + d] = f2bf(Wj[j] * vh);
    }
}

// ============ streaming final combine ============
__global__ __launch_bounds__(256) void final_k(const float* __restrict__ img,
                                               const float* __restrict__ Aax,
                                               const float* __restrict__ Asag,
                                               const float* __restrict__ Acor,
                                               float* __restrict__ out) {
    int blk = blockIdx.x;
    int bc = blk / 112;
    const float4* ip = reinterpret_cast<const float4*>(img + (size_t)blk * 8960);
    const float4* ap = reinterpret_cast<const float4*>(Aax + (size_t)bc * 8960);
    const float4* sp = reinterpret_cast<const float4*>(Asag + (size_t)blk * 80);
    const float*  cp = Acor + (size_t)blk * 112;
    float4* op = reinterpret_cast<float4*>(out + (size_t)blk * 8960);
    int t = threadIdx.x;
    for (int q = t; q < 2240; q += 256) {
        int h = q / 20, w4 = q % 20;
        float4 iv = ip[q], av = ap[q], sv = sp[w4];
        float cv = cp[h];
        float4 o;
        o.x = iv.x + av.x + sv.x + cv;
        o.y = iv.y + av.y + sv.y + cv;
        o.z = iv.z + av.z + sv.z + cv;
        o.w = iv.w + av.w + sv.w + cv;
        op[q] = o;
    }
}

extern "C" void kernel_launch(void* const* d_in, const int* in_sizes, int n_in,
                              void* d_out, int out_size, void* d_ws, size_t ws_size,
                              hipStream_t stream) {
    (void)in_sizes; (void)n_in; (void)out_size; (void)ws_size;
    const float* img    = (const float*)d_in[0];
    const float* txt    = (const float*)d_in[1];
    const float* pe_w[3] = {(const float*)d_in[2], (const float*)d_in[4], (const float*)d_in[6]};
    const float* pe_b[3] = {(const float*)d_in[3], (const float*)d_in[5], (const float*)d_in[7]};
    const float* pos[3]  = {(const float*)d_in[8], (const float*)d_in[9], (const float*)d_in[10]};
    const float* qw = (const float*)d_in[11];
    const float* kw = (const float*)d_in[12];
    const float* vw_attn = (const float*)d_in[13];
    const float* pw = (const float*)d_in[14];
    const float* pb = (const float*)d_in[15];
    const float* caq_w = (const float*)d_in[16];
    const float* caq_b = (const float*)d_in[17];
    const float* cak_w = (const float*)d_in[18];
    const float* cak_b = (const float*)d_in[19];
    const float* cav_w = (const float*)d_in[20];
    const float* cav_b = (const float*)d_in[21];
    const float* cao_w = (const float*)d_in[22];
    const float* cao_b = (const float*)d_in[23];
    const float* mlp_w1 = (const float*)d_in[24];
    const float* mlp_b1 = (const float*)d_in[25];
    const float* mlp_w2 = (const float*)d_in[26];
    const float* mlp_b2 = (const float*)d_in[27];
    const float* ow[3] = {(const float*)d_in[28], (const float*)d_in[30], (const float*)d_in[32]};
    const float* ob[3] = {(const float*)d_in[29], (const float*)d_in[31], (const float*)d_in[33]};
    const float* view_w = (const float*)d_in[34];
    const float* n_g[3] = {(const float*)d_in[35], (const float*)d_in[36], (const float*)d_in[37]};
    const float* n_b[3] = {(const float*)d_in[38], (const float*)d_in[39], (const float*)d_in[40]};

    typedef unsigned short u16t;
    unsigned char* sb = (unsigned char*)d_out;
    size_t off = 0;
    auto B = [&](size_t bytes) -> void* {
        void* p = sb + off; off += (bytes + 511) & ~(size_t)511; return p;
    };
    u16t* qkvT  = (u16t*)B((size_t)2304*768*2);
    u16t* pwT   = (u16t*)B(768*768*2);
    u16t* caqT  = (u16t*)B(768*768*2);
    u16t* cakvT = (u16t*)B((size_t)1536*768*2);
    u16t* caoT  = (u16t*)B(768*768*2);
    u16t* mlp1T = (u16t*)B((size_t)3072*768*2);
    u16t* mlp2T = (u16t*)B((size_t)768*3072*2);
    u16t* peT[3]; peT[0] = (u16t*)B((size_t)768*1120*2); peT[1] = (u16t*)B((size_t)768*1120*2); peT[2] = (u16t*)B((size_t)768*1568*2);
    u16t* owT[3]; owT[0] = (u16t*)B((size_t)1120*768*2); owT[1] = (u16t*)B((size_t)1120*768*2); owT[2] = (u16t*)B((size_t)1568*768*2);
    float* axp   = (float*)B((size_t)16*573440*4);
    float* m_sag = (float*)B(573440*4);
    float* m_cor = (float*)B(802816*4);
    u16t* P0 = (u16t*)B((size_t)512*1120*2);
    u16t* P1 = (u16t*)B((size_t)512*1120*2);
    u16t* P2 = (u16t*)B((size_t)512*1568*2);
    float* X0  = (float*)B((size_t)1536*768*4);
    float* X2  = (float*)B((size_t)1536*768*4);
    float* X4  = (float*)B((size_t)1536*768*4);
    u16t* X6b = (u16t*)B((size_t)1536*768*2);
    u16t* QKVb = (u16t*)B((size_t)1536*2304*2);
    u16t* Obf = (u16t*)B((size_t)1536*768*2);
    u16t* Vt  = (u16t*)B((size_t)72*64*256*2);
    u16t* Hb  = (u16t*)B((size_t)1536*3072*2);
    u16t* KVHb = (u16t*)B((size_t)1536*1536*2);
    u16t* QHb  = (u16t*)B((size_t)154*768*2);
    float* stats = (float*)B((size_t)3*1536*2*4);   // [stats1 | stats2 | stats3]
    float* stats1 = stats;
    float* stats2 = stats + 1536*2;
    float* stats3 = stats + 2*1536*2;

    float* ws = (float*)d_ws;
    float* Aax  = ws;
    float* Asag = ws + 573440;
    float* Acor = ws + 1146880;

    // ---- prep: transposes + means + stats zero (1 launch) ----
    TT tab;
    {
        const float* ins[16] = {qw, kw, vw_attn, pw, caq_w, cak_w, cav_w, cao_w,
                                mlp_w1, mlp_w2, pe_w[0], pe_w[1], pe_w[2], ow[0], ow[1], ow[2]};
        u16t* outs[16] = {qkvT, qkvT + 768*768, qkvT + 2*768*768, pwT, caqT, cakvT,
                          cakvT + 768*768, caoT, mlp1T, mlp2T, peT[0], peT[1], peT[2],
                          owT[0], owT[1], owT[2]};
        int Ks[16] = {768,768,768,768,768,768,768,768, 768,3072, 1120,1120,1568, 768,768,768};
        int Ns[16] = {768,768,768,768,768,768,768,768, 3072,768, 768,768,768, 1120,1120,1568};
        int st = 0;
        for (int i = 0; i < 16; ++i) {
            tab.in[i] = ins[i]; tab.out[i] = outs[i]; tab.K[i] = Ks[i]; tab.N[i] = Ns[i];
            tab.start[i] = st;
            st += (Ks[i] >> 5) * (Ns[i] >> 5);
        }
        tab.total = st;
        prep_k<<<1024 + st + 1, 256, 0, stream>>>(tab, img, axp, m_sag, m_cor, stats);
    }

    patchify3_k<<<dim3(224,3), 256, 0, stream>>>(axp, m_sag, m_cor, P0, P1, P2);

    // pe (z<3, emits LN1 stats) + QH projection (z=3)
    {
        PeDesc d;
        d.A[0] = P0; d.A[1] = P1; d.A[2] = P2;
        d.Bt[0] = peT[0]; d.Bt[1] = peT[1]; d.Bt[2] = peT[2]; d.Bt[3] = caqT;
        d.bias[0] = pe_b[0]; d.bias[1] = pe_b[1]; d.bias[2] = pe_b[2]; d.bias[3] = caq_b;
        d.pos[0] = pos[0]; d.pos[1] = pos[1]; d.pos[2] = pos[2];
        d.K[0] = 1120; d.K[1] = 1120; d.K[2] = 1568; d.K[3] = 768;
        d.M[0] = 512; d.M[1] = 512; d.M[2] = 512; d.M[3] = 154;
        gemm_pe<<<dim3(12,8,4), 256, 0, stream>>>(d, txt, X0, QHb, stats1);
    }

    // QKV = LN1(X0) @ qkvT  (inline LN in A-load) + Vt scatter
    gemm_big<<<dim3(18,12), 256, 0, stream>>>(X0, stats1, n_g[0], n_b[0],
                                              qkvT, QKVb, Vt, 2304, nullptr, nullptr, 0);
    attn_k<<<144, 256, 0, stream>>>(QKVb, Vt, Obf);
    // X2 = Obf@pwT + pb + LN1(X0)   [emits LN2 stats]
    gemm_bf<<<dim3(12,24), 256, 0, stream>>>(Obf, pwT, X2, nullptr, 1536, 768, 768,
                                             pb, X0, stats1, n_g[0], n_b[0], stats2, 0);
    // KVHb = LN2(X2) @ cakvT + [cak_b|cav_b]
    gemm_big<<<dim3(12,12), 256, 0, stream>>>(X2, stats2, n_g[1], n_b[1],
                                              cakvT, KVHb, nullptr, 1536, cak_b, cav_b, 0);
    ca_fused<<<72, 256, 0, stream>>>(QHb, KVHb, Obf);
    // X4 = Obf@caoT + cao_b + LN2(X2)   [emits LN3 stats]
    gemm_bf<<<dim3(12,24), 256, 0, stream>>>(Obf, caoT, X4, nullptr, 1536, 768, 768,
                                             cao_b, X2, stats2, n_g[1], n_b[1], stats3, 0);
    // Hb = gelu(LN3(X4) @ mlp1T + mb1)
    gemm_big<<<dim3(24,12), 256, 0, stream>>>(X4, stats3, n_g[2], n_b[2],
                                              mlp1T, Hb, nullptr, 3072, mlp_b1, nullptr, 1);
    // X6b = Hb@mlp2T + mb2 + X4
    gemm_bf<<<dim3(12,24), 256, 0, stream>>>(Hb, mlp2T, nullptr, X6b, 1536, 768, 3072,
                                             mlp_b2, X4, nullptr, nullptr, nullptr, nullptr, 0);
    // output projections + fused unpatchify
    {
        OwDesc d;
        d.Bt[0] = owT[0]; d.Bt[1] = owT[1]; d.Bt[2] = owT[2];
        d.plane[0] = Aax; d.plane[1] = Asag; d.plane[2] = Acor;
        d.bias[0] = ob[0]; d.bias[1] = ob[1]; d.bias[2] = ob[2];
        d.N[0] = 1120; d.N[1] = 1120; d.N[2] = 1568;
        d.p2[0] = 5; d.p2[1] = 5; d.p2[2] = 7;
        d.Wd[0] = 80; d.Wd[1] = 80; d.Wd[2] = 112;
        gemm_ow<<<dim3(25,8,3), 256, 0, stream>>>(d, X6b, view_w);
    }

    final_k<<<7168, 256, 0, stream>>>(img, Aax, Asag, Acor, (float*)d_out);
}

// Round 12
// 439.823 us; speedup vs baseline: 2.0124x; 1.1027x over previous
//
#include <hip/hip_runtime.h>
#include <math.h>

typedef __attribute__((ext_vector_type(8))) short s8;
typedef __attribute__((ext_vector_type(4))) float f4;
typedef unsigned short u16;

__device__ inline u16 f2bf(float f) {
    unsigned u = __float_as_uint(f);
    u += 0x7fffu + ((u >> 16) & 1u);
    return (u16)(u >> 16);
}
__device__ inline float bf2f(u16 x) {
    return __uint_as_float(((unsigned)x) << 16);
}
#define MFMA16(a, b, c) __builtin_amdgcn_mfma_f32_16x16x32_bf16(a, b, c, 0, 0, 0)

// ============ prep: weight transposes + axis means (1 launch) ============
struct TT {
    const float* in[16];
    u16* out[16];
    int K[16];
    int N[16];
    int start[16];
    int total;
};

__global__ __launch_bounds__(256) void prep_k(TT tab, const float* __restrict__ img,
                                              float* __restrict__ axp,
                                              float* __restrict__ sag,
                                              float* __restrict__ cor) {
    __shared__ float sl[112*81];
    int bid = blockIdx.x;
    int t = threadIdx.x;
    if (bid < 1024) {
        int dc = bid & 15, bc = bid >> 4;
        int d0 = dc * 7;
        f4 axr[9];
        #pragma unroll
        for (int k = 0; k < 9; ++k) axr[k] = (f4){0.f,0.f,0.f,0.f};
        const float* base = img + (size_t)bc * 1003520 + (size_t)d0 * 8960;
        for (int sidx = 0; sidx < 7; ++sidx) {
            const f4* sp = reinterpret_cast<const f4*>(base + (size_t)sidx * 8960);
            #pragma unroll
            for (int k = 0; k < 9; ++k) {
                int q = t + k * 256;
                if (q < 2240) {
                    f4 v = sp[q];
                    axr[k] += v;
                    int h = q / 20, w4 = q % 20;
                    float* row = &sl[h * 81 + w4 * 4];
                    row[0] = v[0]; row[1] = v[1]; row[2] = v[2]; row[3] = v[3];
                }
            }
            __syncthreads();
            if (t < 112) {
                float acc = 0.f;
                #pragma unroll 8
                for (int w = 0; w < 80; ++w) acc += sl[t * 81 + w];
                cor[((size_t)bc * 112 + d0 + sidx) * 112 + t] = acc * (1.f / 80.f);
            } else if (t < 192) {
                int w = t - 112;
                float acc = 0.f;
                #pragma unroll 8
                for (int h = 0; h < 112; ++h) acc += sl[h * 81 + w];
                sag[((size_t)bc * 112 + d0 + sidx) * 80 + w] = acc * (1.f / 112.f);
            }
            __syncthreads();
        }
        float* axo = axp + ((size_t)dc * 64 + bc) * 8960;
        #pragma unroll
        for (int k = 0; k < 9; ++k) {
            int q = t + k * 256;
            if (q < 2240) *reinterpret_cast<f4*>(axo + q * 4) = axr[k];
        }
        return;
    }
    int tb = bid - 1024;
    // ---- transpose tile ----
    float (*tl)[33] = reinterpret_cast<float(*)[33]>(sl);
    int e = 0;
    #pragma unroll
    for (int i = 1; i < 16; ++i) if (tb >= tab.start[i]) e = i;
    const float* in = tab.in[e];
    u16* out = tab.out[e];
    int K = tab.K[e], N = tab.N[e];
    int tid = tb - tab.start[e];
    int nt = N >> 5;
    int k0 = (tid / nt) * 32, n0 = (tid % nt) * 32;
    int r = t >> 5, c = t & 31;
    #pragma unroll
    for (int i = 0; i < 4; ++i) tl[r + i*8][c] = in[(long)(k0 + r + i*8)*N + n0 + c];
    __syncthreads();
    #pragma unroll
    for (int i = 0; i < 4; ++i) out[(long)(n0 + r + i*8)*K + k0 + c] = f2bf(tl[c][r + i*8]);
}

// ============ patchify, 3 branches; br0 sums ax partials ============
__global__ __launch_bounds__(256) void patchify3_k(const float* __restrict__ axp,
                                                   const float* __restrict__ m_sag,
                                                   const float* __restrict__ m_cor,
                                                   u16* __restrict__ P0, u16* __restrict__ P1,
                                                   u16* __restrict__ P2) {
    __shared__ float sl[32][113];
    int br = blockIdx.y;
    int X = blockIdx.x;
    int b = X / 112, rem = X % 112;
    int hh = rem / 7, pp1 = rem % 7;
    const float* src; u16* dst; int Wt, p2, PD;
    if (br == 0)      { src = nullptr; dst = P0; Wt = 80;  p2 = 5; PD = 1120; }
    else if (br == 1) { src = m_sag;   dst = P1; Wt = 80;  p2 = 5; PD = 1120; }
    else              { src = m_cor;   dst = P2; Wt = 112; p2 = 7; PD = 1568; }
    int t = threadIdx.x;
    int row = hh*7 + pp1;
    int wq = Wt >> 2;
    if (br == 0) {
        for (int i = t; i < 32*20; i += 256) {
            int c = i / 20, w4 = i % 20;
            f4 s = (f4){0.f,0.f,0.f,0.f};
            size_t base = ((size_t)(b*32 + c)*112 + row)*80 + w4*4;
            #pragma unroll
            for (int p = 0; p < 16; ++p)
                s += *reinterpret_cast<const f4*>(axp + (size_t)p*573440 + base);
            s *= (1.f/112.f);
            sl[c][w4*4+0] = s[0]; sl[c][w4*4+1] = s[1]; sl[c][w4*4+2] = s[2]; sl[c][w4*4+3] = s[3];
        }
    } else {
        for (int i = t; i < 32*wq; i += 256) {
            int c = i / wq, w4 = i % wq;
            float4 v = *reinterpret_cast<const float4*>(
                src + ((size_t)(b*32 + c)*112 + row)*Wt + w4*4);
            sl[c][w4*4+0] = v.x; sl[c][w4*4+1] = v.y; sl[c][w4*4+2] = v.z; sl[c][w4*4+3] = v.w;
        }
    }
    __syncthreads();
    int tot = 16 * p2 * 32;
    for (int o = t; o < tot; o += 256) {
        int ww = o / (p2*32), rest = o % (p2*32);
        int pp2 = rest >> 5, c = rest & 31;
        dst[((size_t)(b*256 + hh*16 + ww))*PD + (pp1*p2 + pp2)*32 + c]
            = f2bf(sl[c][ww*p2 + pp2]);
    }
}

// ============ GEMM building blocks (64-tile): BK=128, double-buffered LDS ============
__device__ inline void load_tile(const u16* __restrict__ P, int ld, int nrows, int K,
                                 int r0, int k0, int t, s8 v[4]) {
    #pragma unroll
    for (int i = 0; i < 4; ++i) {
        int chunk = t + i*256;
        int row = chunk >> 4, c8 = (chunk & 15) * 8;
        s8 x;
        #pragma unroll
        for (int q = 0; q < 8; ++q) x[q] = 0;
        if (r0 + row < nrows && k0 + c8 < K)
            x = *reinterpret_cast<const s8*>(P + (long)(r0 + row)*ld + k0 + c8);
        v[i] = x;
    }
}
__device__ inline void load_tile_f32(const float* __restrict__ P, int ld, int nrows, int K,
                                     int r0, int k0, int t, s8 v[4]) {
    #pragma unroll
    for (int i = 0; i < 4; ++i) {
        int chunk = t + i*256;
        int row = chunk >> 4, c8 = (chunk & 15) * 8;
        s8 x;
        #pragma unroll
        for (int q = 0; q < 8; ++q) x[q] = 0;
        if (r0 + row < nrows && k0 + c8 < K) {
            const float* src = P + (long)(r0 + row)*ld + k0 + c8;
            #pragma unroll
            for (int q = 0; q < 8; ++q) x[q] = (short)f2bf(src[q]);
        }
        v[i] = x;
    }
}
__device__ inline void write_tile(u16 (*S)[136], int t, const s8 v[4]) {
    #pragma unroll
    for (int i = 0; i < 4; ++i) {
        int chunk = t + i*256;
        *reinterpret_cast<s8*>(&S[chunk >> 4][(chunk & 15)*8]) = v[i];
    }
}
__device__ inline void mfma_tile(const u16 (*As)[136], const u16 (*Bs)[136],
                                 int wr, int wc, int lane, f4 acc[2][2]) {
    int lrow = lane & 15;
    #pragma unroll
    for (int kh = 0; kh < 4; ++kh) {
        int lk = kh*32 + (lane >> 4) * 8;
        s8 af0 = *reinterpret_cast<const s8*>(&As[wr*32 + lrow][lk]);
        s8 af1 = *reinterpret_cast<const s8*>(&As[wr*32 + 16 + lrow][lk]);
        s8 bg0 = *reinterpret_cast<const s8*>(&Bs[wc*32 + lrow][lk]);
        s8 bg1 = *reinterpret_cast<const s8*>(&Bs[wc*32 + 16 + lrow][lk]);
        acc[0][0] = MFMA16(af0, bg0, acc[0][0]);
        acc[0][1] = MFMA16(af0, bg1, acc[0][1]);
        acc[1][0] = MFMA16(af1, bg0, acc[1][0]);
        acc[1][1] = MFMA16(af1, bg1, acc[1][1]);
    }
}

// ============ bf16 MFMA GEMM (64-tile): epilogue w/ split-bias, resid, act, Vt scatter ====
__global__ __launch_bounds__(256) void gemm_bf(
    const u16* __restrict__ A, const u16* __restrict__ Bt,
    float* __restrict__ Cf, u16* __restrict__ Cb,
    int M, int N, int K,
    const float* __restrict__ bias, const float* __restrict__ bias2,
    const float* __restrict__ resid, int act, u16* __restrict__ vt)
{
    __shared__ u16 As[2][64][136];
    __shared__ u16 Bs[2][64][136];
    int t = threadIdx.x;
    int m0 = blockIdx.y * 64, n0 = blockIdx.x * 64;
    int wave = t >> 6, lane = t & 63;
    int wr = wave >> 1, wc = wave & 1;
    f4 acc[2][2];
    #pragma unroll
    for (int m = 0; m < 2; ++m)
        #pragma unroll
        for (int n = 0; n < 2; ++n)
            #pragma unroll
            for (int r = 0; r < 4; ++r) acc[m][n][r] = 0.f;
    int nk = (K + 127) >> 7;
    s8 pa[4], pbv[4];
    load_tile(A, K, M, K, m0, 0, t, pa);
    load_tile(Bt, K, N, K, n0, 0, t, pbv);
    write_tile(As[0], t, pa);
    write_tile(Bs[0], t, pbv);
    __syncthreads();
    for (int kt = 0; kt < nk; ++kt) {
        int cur = kt & 1;
        if (kt + 1 < nk) {
            load_tile(A, K, M, K, m0, (kt+1) << 7, t, pa);
            load_tile(Bt, K, N, K, n0, (kt+1) << 7, t, pbv);
        }
        mfma_tile(As[cur], Bs[cur], wr, wc, lane, acc);
        if (kt + 1 < nk) {
            write_tile(As[cur^1], t, pa);
            write_tile(Bs[cur^1], t, pbv);
        }
        __syncthreads();
    }
    #pragma unroll
    for (int m = 0; m < 2; ++m) {
        int rbase = m0 + wr*32 + m*16 + (lane >> 4) * 4;
        #pragma unroll
        for (int n = 0; n < 2; ++n) {
            int col = n0 + wc*32 + n*16 + (lane & 15);
            if (col >= N) continue;
            #pragma unroll
            for (int r = 0; r < 4; ++r) {
                int row = rbase + r;
                if (row >= M) continue;
                float v = acc[m][n][r];
                if (bias) {
                    float bb = bias2 ? ((col < 768) ? bias[col] : bias2[col - 768]) : bias[col];
                    v += bb;
                }
                if (resid) v += resid[(long)row * N + col];
                if (act == 1) v = 0.5f * v * (1.0f + erff(v * 0.70710678118654752f));
                long ci = (long)row * N + col;
                u16 b = f2bf(v);
                if (Cf) Cf[ci] = v;
                if (Cb) Cb[ci] = b;
                if (vt && col >= 1536) {
                    int z = (row >> 8) * 12 + ((col - 1536) >> 6);
                    vt[((long)z * 64 + (col & 63)) * 256 + (row & 255)] = b;
                }
            }
        }
    }
}

// ============ batched patch-embed (+QH from fp32 txt) GEMM ============
struct PeDesc {
    const u16* A[3];
    const u16* Bt[4];
    const float* bias[4];
    const float* pos[3];
    int K[4];
    int M[4];
};

__global__ __launch_bounds__(256) void gemm_pe(PeDesc d, const float* __restrict__ txtf,
                                               float* __restrict__ C, u16* __restrict__ QHb) {
    int z = blockIdx.z;
    int M = d.M[z], K = d.K[z];
    int m0 = blockIdx.y * 64, n0 = blockIdx.x * 64;
    if (m0 >= M) return;
    __shared__ u16 As[2][64][136];
    __shared__ u16 Bs[2][64][136];
    const u16* Bb = d.Bt[z];
    const float* bias = d.bias[z];
    int t = threadIdx.x;
    int wave = t >> 6, lane = t & 63;
    int wr = wave >> 1, wc = wave & 1;
    f4 acc[2][2];
    #pragma unroll
    for (int m = 0; m < 2; ++m)
        #pragma unroll
        for (int n = 0; n < 2; ++n)
            #pragma unroll
            for (int r = 0; r < 4; ++r) acc[m][n][r] = 0.f;
    int nk = (K + 127) >> 7;
    s8 pa[4], pbv[4];
    if (z < 3) load_tile(d.A[z], K, M, K, m0, 0, t, pa);
    else       load_tile_f32(txtf, K, M, K, m0, 0, t, pa);
    load_tile(Bb, K, 768, K, n0, 0, t, pbv);
    write_tile(As[0], t, pa);
    write_tile(Bs[0], t, pbv);
    __syncthreads();
    for (int kt = 0; kt < nk; ++kt) {
        int cur = kt & 1;
        if (kt + 1 < nk) {
            if (z < 3) load_tile(d.A[z], K, M, K, m0, (kt+1) << 7, t, pa);
            else       load_tile_f32(txtf, K, M, K, m0, (kt+1) << 7, t, pa);
            load_tile(Bb, K, 768, K, n0, (kt+1) << 7, t, pbv);
        }
        mfma_tile(As[cur], Bs[cur], wr, wc, lane, acc);
        if (kt + 1 < nk) {
            write_tile(As[cur^1], t, pa);
            write_tile(Bs[cur^1], t, pbv);
        }
        __syncthreads();
    }
    #pragma unroll
    for (int m = 0; m < 2; ++m) {
        int rbase = m0 + wr*32 + m*16 + (lane >> 4) * 4;
        #pragma unroll
        for (int n = 0; n < 2; ++n) {
            int col = n0 + wc*32 + n*16 + (lane & 15);
            #pragma unroll
            for (int r = 0; r < 4; ++r) {
                int row = rbase + r;
                if (row >= M) continue;
                float v = acc[m][n][r] + bias[col];
                if (z < 3) {
                    v += d.pos[z][(long)(row & 255)*768 + col];
                    C[((long)z*512 + row) * 768 + col] = v;
                } else {
                    QHb[(long)row * 768 + col] = f2bf(v);
                }
            }
        }
    }
}

// ============ output-proj GEMM + fused unpatchify ============
struct OwDesc {
    const u16* Bt[3];
    float* plane[3];
    const float* bias[3];
    int N[3];
    int p2[3];
    int Wd[3];
};

__global__ __launch_bounds__(256) void gemm_ow(OwDesc d, const u16* __restrict__ A,
                                               const float* __restrict__ vwp) {
    int z = blockIdx.z;
    int N = d.N[z];
    int n0 = blockIdx.x * 64;
    if (n0 >= N) return;
    __shared__ u16 As[2][64][136];
    __shared__ u16 Bs[2][64][136];
    const u16* Ab = A + (long)z * 512 * 768;
    const u16* Bb = d.Bt[z];
    int t = threadIdx.x;
    int m0 = blockIdx.y * 64;
    int wave = t >> 6, lane = t & 63;
    int wr = wave >> 1, wc = wave & 1;
    f4 acc[2][2];
    #pragma unroll
    for (int m = 0; m < 2; ++m)
        #pragma unroll
        for (int n = 0; n < 2; ++n)
            #pragma unroll
            for (int r = 0; r < 4; ++r) acc[m][n][r] = 0.f;
    s8 pa[4], pbv[4];
    load_tile(Ab, 768, 512, 768, m0, 0, t, pa);
    load_tile(Bb, 768, N, 768, n0, 0, t, pbv);
    write_tile(As[0], t, pa);
    write_tile(Bs[0], t, pbv);
    __syncthreads();
    for (int kt = 0; kt < 6; ++kt) {
        int cur = kt & 1;
        if (kt + 1 < 6) {
            load_tile(Ab, 768, 512, 768, m0, (kt+1) << 7, t, pa);
            load_tile(Bb, 768, N, 768, n0, (kt+1) << 7, t, pbv);
        }
        mfma_tile(As[cur], Bs[cur], wr, wc, lane, acc);
        if (kt + 1 < 6) {
            write_tile(As[cur^1], t, pa);
            write_tile(Bs[cur^1], t, pbv);
        }
        __syncthreads();
    }
    float* plane = d.plane[z];
    const float* bias = d.bias[z];
    int p2 = d.p2[z], Wd = d.Wd[z];
    float wt = vwp[z];
    #pragma unroll
    for (int m = 0; m < 2; ++m) {
        int rbase = m0 + wr*32 + m*16 + (lane >> 4) * 4;
        #pragma unroll
        for (int n = 0; n < 2; ++n) {
            int col = n0 + wc*32 + n*16 + (lane & 15);
            if (col >= N) continue;
            int pp = col >> 5, c = col & 31;
            int pp1 = pp / p2, pp2 = pp % p2;
            float bv = bias[col];
            #pragma unroll
            for (int r = 0; r < 4; ++r) {
                int row = rbase + r;
                int b = row >> 8, nn = row & 255;
                int hh = nn >> 4, ww = nn & 15;
                plane[((long)(b*32 + c)*112 + hh*7 + pp1)*Wd + ww*p2 + pp2]
                    = wt * (acc[m][n][r] + bv);
            }
        }
    }
}

// ============ LayerNorm rows of 768 ============
__global__ __launch_bounds__(256) void ln_k(const float* __restrict__ in,
                                            float* __restrict__ outf,
                                            u16* __restrict__ outb,
                                            const float* __restrict__ g,
                                            const float* __restrict__ bta) {
    constexpr int N = 768;
    int row = blockIdx.x;
    const float* x = in + (size_t)row * N;
    int t = threadIdx.x;
    float v0 = x[t], v1 = x[t+256], v2 = x[t+512];
    float s = v0+v1+v2, s2 = v0*v0+v1*v1+v2*v2;
    #pragma unroll
    for (int off = 32; off > 0; off >>= 1) { s += __shfl_down(s, off); s2 += __shfl_down(s2, off); }
    __shared__ float red[8];
    int wid = t >> 6, lane = t & 63;
    if (lane == 0) { red[wid] = s; red[wid+4] = s2; }
    __syncthreads();
    if (t == 0) {
        float S = red[0]+red[1]+red[2]+red[3];
        float S2 = red[4]+red[5]+red[6]+red[7];
        float mean = S * (1.f/N);
        float var = S2 * (1.f/N) - mean*mean;
        red[0] = mean; red[1] = rsqrtf(var + 1e-5f);
    }
    __syncthreads();
    float mean = red[0], rstd = red[1];
    float y0 = (v0-mean)*rstd*g[t]     + bta[t];
    float y1 = (v1-mean)*rstd*g[t+256] + bta[t+256];
    float y2 = (v2-mean)*rstd*g[t+512] + bta[t+512];
    if (outf) {
        float* y = outf + (size_t)row * N;
        y[t] = y0; y[t+256] = y1; y[t+512] = y2;
    }
    if (outb) {
        u16* y = outb + (size_t)row * N;
        y[t] = f2bf(y0); y[t+256] = f2bf(y1); y[t+512] = f2bf(y2);
    }
}

// ============ fully fused self-attention ============
__global__ __launch_bounds__(256) void attn_k(const u16* __restrict__ QKV,
                                              const u16* __restrict__ Vt,
                                              u16* __restrict__ O) {
    __shared__ u16 Ks[256][72];
    __shared__ u16 Ps[128][264];
    __shared__ u16 Vs[64][264];
    int zz = blockIdx.x;
    int bh = zz >> 1, half = zz & 1;
    int bb = bh / 12, h = bh % 12;
    long qrow0 = (long)bb*256 + half*128;
    int hcol = h*64;
    int t = threadIdx.x;
    int wave = t >> 6, lane = t & 63;
    int lr = lane & 15, lg = lane >> 4;
    #pragma unroll
    for (int i = 0; i < 8; ++i) {
        int chunk = t + i*256;
        int row = chunk >> 3, c8 = (chunk & 7)*8;
        *reinterpret_cast<s8*>(&Ks[row][c8]) =
            *reinterpret_cast<const s8*>(QKV + ((long)bb*256 + row)*2304 + 768 + hcol + c8);
    }
    #pragma unroll
    for (int i = 0; i < 8; ++i) {
        int chunk = t + i*256;
        int d = chunk >> 5, j8 = (chunk & 31)*8;
        *reinterpret_cast<s8*>(&Vs[d][j8]) =
            *reinterpret_cast<const s8*>(Vt + (long)bh*16384 + (long)d*256 + j8);
    }
    __syncthreads();
    f4 acc[2][16];
    #pragma unroll
    for (int m = 0; m < 2; ++m)
        #pragma unroll
        for (int n = 0; n < 16; ++n)
            #pragma unroll
            for (int r = 0; r < 4; ++r) acc[m][n][r] = 0.f;
    #pragma unroll
    for (int kh = 0; kh < 2; ++kh) {
        s8 af0 = *reinterpret_cast<const s8*>(QKV + (qrow0 + wave*32 + lr)*2304 + hcol + kh*32 + lg*8);
        s8 af1 = *reinterpret_cast<const s8*>(QKV + (qrow0 + wave*32 + 16 + lr)*2304 + hcol + kh*32 + lg*8);
        #pragma unroll
        for (int n = 0; n < 16; ++n) {
            s8 bf = *reinterpret_cast<const s8*>(&Ks[n*16 + lr][kh*32 + lg*8]);
            acc[0][n] = MFMA16(af0, bf, acc[0][n]);
            acc[1][n] = MFMA16(af1, bf, acc[1][n]);
        }
    }
    #pragma unroll
    for (int m = 0; m < 2; ++m)
        #pragma unroll
        for (int r = 0; r < 4; ++r) {
            float mx = -1e30f;
            #pragma unroll
            for (int n = 0; n < 16; ++n) mx = fmaxf(mx, acc[m][n][r]);
            #pragma unroll
            for (int o = 8; o; o >>= 1) mx = fmaxf(mx, __shfl_xor(mx, o));
            float l = 0.f;
            float p[16];
            #pragma unroll
            for (int n = 0; n < 16; ++n) {
                p[n] = __expf((acc[m][n][r] - mx) * 0.125f);
                l += p[n];
            }
            #pragma unroll
            for (int o = 8; o; o >>= 1) l += __shfl_xor(l, o);
            float inv = 1.f / l;
            int prow = wave*32 + m*16 + lg*4 + r;
            #pragma unroll
            for (int n = 0; n < 16; ++n)
                Ps[prow][n*16 + lr] = f2bf(p[n] * inv);
        }
    __syncthreads();
    f4 o2[2][4];
    #pragma unroll
    for (int m = 0; m < 2; ++m)
        #pragma unroll
        for (int n = 0; n < 4; ++n)
            #pragma unroll
            for (int r = 0; r < 4; ++r) o2[m][n][r] = 0.f;
    #pragma unroll
    for (int kh = 0; kh < 8; ++kh) {
        s8 pf0 = *reinterpret_cast<const s8*>(&Ps[wave*32 + lr][kh*32 + lg*8]);
        s8 pf1 = *reinterpret_cast<const s8*>(&Ps[wave*32 + 16 + lr][kh*32 + lg*8]);
        #pragma unroll
        for (int n = 0; n < 4; ++n) {
            s8 vf = *reinterpret_cast<const s8*>(&Vs[n*16 + lr][kh*32 + lg*8]);
            o2[0][n] = MFMA16(pf0, vf, o2[0][n]);
            o2[1][n] = MFMA16(pf1, vf, o2[1][n]);
        }
    }
    #pragma unroll
    for (int m = 0; m < 2; ++m)
        #pragma unroll
        for (int n = 0; n < 4; ++n)
            #pragma unroll
            for (int r = 0; r < 4; ++r)
                O[(qrow0 + wave*32 + m*16 + lg*4 + r)*768 + hcol + n*16 + lr] = f2bf(o2[m][n][r]);
}

// ============ fully fused cross-attention ============
__global__ __launch_bounds__(256) void ca_fused(const u16* __restrict__ QHb,
                                                const u16* __restrict__ KVHb,
                                                u16* __restrict__ O) {
    __shared__ u16 QHs[80][72];
    __shared__ u16 KHs[256][72];
    __shared__ float rmax[80][4];
    __shared__ float rsum[80][4];
    __shared__ float Wj[256];
    int bh = blockIdx.x;
    int rowblk = bh / 12, h = bh % 12;
    int bsel = rowblk & 1;
    int t = threadIdx.x;
    int wave = t >> 6, lane = t & 63;
    int lr = lane & 15, lg = lane >> 4;
    #pragma unroll
    for (int i = 0; i < 3; ++i) {
        int chunk = t + i*256;
        if (chunk < 640) {
            int row = chunk >> 3, c8 = (chunk & 7)*8;
            s8 v;
            #pragma unroll
            for (int q = 0; q < 8; ++q) v[q] = 0;
            if (row < 77)
                v = *reinterpret_cast<const s8*>(QHb + ((long)(bsel*77 + row))*768 + h*64 + c8);
            *reinterpret_cast<s8*>(&QHs[row][c8]) = v;
        }
    }
    #pragma unroll
    for (int i = 0; i < 8; ++i) {
        int chunk = t + i*256;
        int row = chunk >> 3, c8 = (chunk & 7)*8;
        *reinterpret_cast<s8*>(&KHs[row][c8]) =
            *reinterpret_cast<const s8*>(KVHb + ((long)rowblk*256 + row)*1536 + h*64 + c8);
    }
    __syncthreads();
    f4 acc[5][4];
    #pragma unroll
    for (int m = 0; m < 5; ++m)
        #pragma unroll
        for (int n = 0; n < 4; ++n)
            #pragma unroll
            for (int r = 0; r < 4; ++r) acc[m][n][r] = 0.f;
    #pragma unroll
    for (int kh = 0; kh < 2; ++kh) {
        s8 af[5], bf[4];
        #pragma unroll
        for (int m = 0; m < 5; ++m)
            af[m] = *reinterpret_cast<const s8*>(&QHs[m*16 + lr][kh*32 + lg*8]);
        #pragma unroll
        for (int n = 0; n < 4; ++n)
            bf[n] = *reinterpret_cast<const s8*>(&KHs[wave*64 + n*16 + lr][kh*32 + lg*8]);
        #pragma unroll
        for (int m = 0; m < 5; ++m)
            #pragma unroll
            for (int n = 0; n < 4; ++n)
                acc[m][n] = MFMA16(af[m], bf[n], acc[m][n]);
    }
    #pragma unroll
    for (int m = 0; m < 5; ++m)
        #pragma unroll
        for (int r = 0; r < 4; ++r) {
            float mx = -1e30f;
            #pragma unroll
            for (int n = 0; n < 4; ++n) mx = fmaxf(mx, acc[m][n][r]);
            #pragma unroll
            for (int o = 8; o; o >>= 1) mx = fmaxf(mx, __shfl_xor(mx, o));
            if (lr == 0) rmax[m*16 + lg*4 + r][wave] = mx;
        }
    __syncthreads();
    #pragma unroll
    for (int m = 0; m < 5; ++m)
        #pragma unroll
        for (int r = 0; r < 4; ++r) {
            int i = m*16 + lg*4 + r;
            float mi = fmaxf(fmaxf(rmax[i][0], rmax[i][1]), fmaxf(rmax[i][2], rmax[i][3]));
            float s = 0.f;
            #pragma unroll
            for (int n = 0; n < 4; ++n) s += __expf((acc[m][n][r] - mi) * 0.125f);
            #pragma unroll
            for (int o = 8; o; o >>= 1) s += __shfl_xor(s, o);
            if (lr == 0) rsum[i][wave] = s;
        }
    __syncthreads();
    float wn[4] = {0.f, 0.f, 0.f, 0.f};
    #pragma unroll
    for (int m = 0; m < 5; ++m)
        #pragma unroll
        for (int r = 0; r < 4; ++r) {
            int i = m*16 + lg*4 + r;
            if (i < 77) {
                float mi = fmaxf(fmaxf(rmax[i][0], rmax[i][1]), fmaxf(rmax[i][2], rmax[i][3]));
                float li = rsum[i][0] + rsum[i][1] + rsum[i][2] + rsum[i][3];
                float inv = 1.f / li;
                #pragma unroll
                for (int n = 0; n < 4; ++n)
                    wn[n] += __expf((acc[m][n][r] - mi) * 0.125f) * inv;
            }
        }
    #pragma unroll
    for (int n = 0; n < 4; ++n) {
        wn[n] += __shfl_xor(wn[n], 16);
        wn[n] += __shfl_xor(wn[n], 32);
    }
    if (lane < 16) {
        #pragma unroll
        for (int n = 0; n < 4; ++n) Wj[wave*64 + n*16 + lr] = wn[n];
    }
    __syncthreads();
    int d = t & 63;
    #pragma unroll 4
    for (int it = 0; it < 64; ++it) {
        int j = it*4 + (t >> 6);
        long row = (long)rowblk*256 + j;
        float vh = bf2f(KVHb[row*1536 + 768 + h*64 + d]);
        O[row*768 + h*64 + d] = f2bf(Wj[j] * vh);
    }
}

// ============ streaming final combine ============
__global__ __launch_bounds__(256) void final_k(const float* __restrict__ img,
                                               const float* __restrict__ Aax,
                                               const float* __restrict__ Asag,
                                               const float* __restrict__ Acor,
                                               float* __restrict__ out) {
    int blk = blockIdx.x;
    int bc = blk / 112;
    const float4* ip = reinterpret_cast<const float4*>(img + (size_t)blk * 8960);
    const float4* ap = reinterpret_cast<const float4*>(Aax + (size_t)bc * 8960);
    const float4* sp = reinterpret_cast<const float4*>(Asag + (size_t)blk * 80);
    const float*  cp = Acor + (size_t)blk * 112;
    float4* op = reinterpret_cast<float4*>(out + (size_t)blk * 8960);
    int t = threadIdx.x;
    for (int q = t; q < 2240; q += 256) {
        int h = q / 20, w4 = q % 20;
        float4 iv = ip[q], av = ap[q], sv = sp[w4];
        float cv = cp[h];
        float4 o;
        o.x = iv.x + av.x + sv.x + cv;
        o.y = iv.y + av.y + sv.y + cv;
        o.z = iv.z + av.z + sv.z + cv;
        o.w = iv.w + av.w + sv.w + cv;
        op[q] = o;
    }
}

extern "C" void kernel_launch(void* const* d_in, const int* in_sizes, int n_in,
                              void* d_out, int out_size, void* d_ws, size_t ws_size,
                              hipStream_t stream) {
    (void)in_sizes; (void)n_in; (void)out_size; (void)ws_size;
    const float* img    = (const float*)d_in[0];
    const float* txt    = (const float*)d_in[1];
    const float* pe_w[3] = {(const float*)d_in[2], (const float*)d_in[4], (const float*)d_in[6]};
    const float* pe_b[3] = {(const float*)d_in[3], (const float*)d_in[5], (const float*)d_in[7]};
    const float* pos[3]  = {(const float*)d_in[8], (const float*)d_in[9], (const float*)d_in[10]};
    const float* qw = (const float*)d_in[11];
    const float* kw = (const float*)d_in[12];
    const float* vw_attn = (const float*)d_in[13];
    const float* pw = (const float*)d_in[14];
    const float* pb = (const float*)d_in[15];
    const float* caq_w = (const float*)d_in[16];
    const float* caq_b = (const float*)d_in[17];
    const float* cak_w = (const float*)d_in[18];
    const float* cak_b = (const float*)d_in[19];
    const float* cav_w = (const float*)d_in[20];
    const float* cav_b = (const float*)d_in[21];
    const float* cao_w = (const float*)d_in[22];
    const float* cao_b = (const float*)d_in[23];
    const float* mlp_w1 = (const float*)d_in[24];
    const float* mlp_b1 = (const float*)d_in[25];
    const float* mlp_w2 = (const float*)d_in[26];
    const float* mlp_b2 = (const float*)d_in[27];
    const float* ow[3] = {(const float*)d_in[28], (const float*)d_in[30], (const float*)d_in[32]};
    const float* ob[3] = {(const float*)d_in[29], (const float*)d_in[31], (const float*)d_in[33]};
    const float* view_w = (const float*)d_in[34];
    const float* n_g[3] = {(const float*)d_in[35], (const float*)d_in[36], (const float*)d_in[37]};
    const float* n_b[3] = {(const float*)d_in[38], (const float*)d_in[39], (const float*)d_in[40]};

    typedef unsigned short u16t;
    unsigned char* sb = (unsigned char*)d_out;
    size_t off = 0;
    auto B = [&](size_t bytes) -> void* {
        void* p = sb + off; off += (bytes + 511) & ~(size_t)511; return p;
    };
    u16t* qkvT  = (u16t*)B((size_t)2304*768*2);
    u16t* pwT   = (u16t*)B(768*768*2);
    u16t* caqT  = (u16t*)B(768*768*2);
    u16t* cakvT = (u16t*)B((size_t)1536*768*2);
    u16t* caoT  = (u16t*)B(768*768*2);
    u16t* mlp1T = (u16t*)B((size_t)3072*768*2);
    u16t* mlp2T = (u16t*)B((size_t)768*3072*2);
    u16t* peT[3]; peT[0] = (u16t*)B((size_t)768*1120*2); peT[1] = (u16t*)B((size_t)768*1120*2); peT[2] = (u16t*)B((size_t)768*1568*2);
    u16t* owT[3]; owT[0] = (u16t*)B((size_t)1120*768*2); owT[1] = (u16t*)B((size_t)1120*768*2); owT[2] = (u16t*)B((size_t)1568*768*2);
    float* axp   = (float*)B((size_t)16*573440*4);
    float* m_sag = (float*)B(573440*4);
    float* m_cor = (float*)B(802816*4);
    u16t* P0 = (u16t*)B((size_t)512*1120*2);
    u16t* P1 = (u16t*)B((size_t)512*1120*2);
    u16t* P2 = (u16t*)B((size_t)512*1568*2);
    float* X0  = (float*)B((size_t)1536*768*4);
    float* X1f = (float*)B((size_t)1536*768*4);
    float* X2  = (float*)B((size_t)1536*768*4);
    float* X3f = (float*)B((size_t)1536*768*4);
    float* X4  = (float*)B((size_t)1536*768*4);
    u16t* X1b = (u16t*)B((size_t)1536*768*2);
    u16t* X3b = (u16t*)B((size_t)1536*768*2);
    u16t* X5b = (u16t*)B((size_t)1536*768*2);
    u16t* X6b = (u16t*)B((size_t)1536*768*2);
    u16t* QKVb = (u16t*)B((size_t)1536*2304*2);
    u16t* Obf = (u16t*)B((size_t)1536*768*2);
    u16t* Vt  = (u16t*)B((size_t)72*64*256*2);
    u16t* Hb  = (u16t*)B((size_t)1536*3072*2);
    u16t* KVHb = (u16t*)B((size_t)1536*1536*2);
    u16t* QHb  = (u16t*)B((size_t)154*768*2);

    float* ws = (float*)d_ws;
    float* Aax  = ws;
    float* Asag = ws + 573440;
    float* Acor = ws + 1146880;

    // ---- prep: transposes + means (1 launch) ----
    TT tab;
    {
        const float* ins[16] = {qw, kw, vw_attn, pw, caq_w, cak_w, cav_w, cao_w,
                                mlp_w1, mlp_w2, pe_w[0], pe_w[1], pe_w[2], ow[0], ow[1], ow[2]};
        u16t* outs[16] = {qkvT, qkvT + 768*768, qkvT + 2*768*768, pwT, caqT, cakvT,
                          cakvT + 768*768, caoT, mlp1T, mlp2T, peT[0], peT[1], peT[2],
                          owT[0], owT[1], owT[2]};
        int Ks[16] = {768,768,768,768,768,768,768,768, 768,3072, 1120,1120,1568, 768,768,768};
        int Ns[16] = {768,768,768,768,768,768,768,768, 3072,768, 768,768,768, 1120,1120,1568};
        int st = 0;
        for (int i = 0; i < 16; ++i) {
            tab.in[i] = ins[i]; tab.out[i] = outs[i]; tab.K[i] = Ks[i]; tab.N[i] = Ns[i];
            tab.start[i] = st;
            st += (Ks[i] >> 5) * (Ns[i] >> 5);
        }
        tab.total = st;
        prep_k<<<1024 + st, 256, 0, stream>>>(tab, img, axp, m_sag, m_cor);
    }

    patchify3_k<<<dim3(224,3), 256, 0, stream>>>(axp, m_sag, m_cor, P0, P1, P2);

    auto gemm = [&](const u16t* A, const u16t* Bt, float* Cf, u16t* Cb,
                    int M, int N, int K, const float* bias, const float* bias2,
                    const float* resid, int act, u16t* vt) {
        dim3 g((N+63)/64, (M+63)/64, 1);
        gemm_bf<<<g, 256, 0, stream>>>(A, Bt, Cf, Cb, M, N, K, bias, bias2, resid, act, vt);
    };

    // pe (z<3) + QH projection (z=3), one launch
    {
        PeDesc d;
        d.A[0] = P0; d.A[1] = P1; d.A[2] = P2;
        d.Bt[0] = peT[0]; d.Bt[1] = peT[1]; d.Bt[2] = peT[2]; d.Bt[3] = caqT;
        d.bias[0] = pe_b[0]; d.bias[1] = pe_b[1]; d.bias[2] = pe_b[2]; d.bias[3] = caq_b;
        d.pos[0] = pos[0]; d.pos[1] = pos[1]; d.pos[2] = pos[2];
        d.K[0] = 1120; d.K[1] = 1120; d.K[2] = 1568; d.K[3] = 768;
        d.M[0] = 512; d.M[1] = 512; d.M[2] = 512; d.M[3] = 154;
        gemm_pe<<<dim3(12,8,4), 256, 0, stream>>>(d, txt, X0, QHb);
    }

    ln_k<<<1536, 256, 0, stream>>>(X0, X1f, X1b, n_g[0], n_b[0]);
    // QKV projection (64-tile, 864 blocks) + fused Vt scatter
    gemm(X1b, qkvT, nullptr, QKVb, 1536, 2304, 768, nullptr, nullptr, nullptr, 0, Vt);
    attn_k<<<144, 256, 0, stream>>>(QKVb, Vt, Obf);
    gemm(Obf, pwT, X2, nullptr, 1536, 768, 768, pb, nullptr, X1f, 0, nullptr);
    ln_k<<<1536, 256, 0, stream>>>(X2, X3f, X3b, n_g[1], n_b[1]);
    // cak||cav (64-tile, 576 blocks, split bias)
    gemm(X3b, cakvT, nullptr, KVHb, 1536, 1536, 768, cak_b, cav_b, nullptr, 0, nullptr);
    ca_fused<<<72, 256, 0, stream>>>(QHb, KVHb, Obf);
    gemm(Obf, caoT, X4, nullptr, 1536, 768, 768, cao_b, nullptr, X3f, 0, nullptr);
    ln_k<<<1536, 256, 0, stream>>>(X4, nullptr, X5b, n_g[2], n_b[2]);
    // MLP1 (64-tile, 1152 blocks, gelu)
    gemm(X5b, mlp1T, nullptr, Hb, 1536, 3072, 768, mlp_b1, nullptr, nullptr, 1, nullptr);
    gemm(Hb, mlp2T, nullptr, X6b, 1536, 768, 3072, mlp_b2, nullptr, X4, 0, nullptr);
    // output projections + fused unpatchify
    {
        OwDesc d;
        d.Bt[0] = owT[0]; d.Bt[1] = owT[1]; d.Bt[2] = owT[2];
        d.plane[0] = Aax; d.plane[1] = Asag; d.plane[2] = Acor;
        d.bias[0] = ob[0]; d.bias[1] = ob[1]; d.bias[2] = ob[2];
        d.N[0] = 1120; d.N[1] = 1120; d.N[2] = 1568;
        d.p2[0] = 5; d.p2[1] = 5; d.p2[2] = 7;
        d.Wd[0] = 80; d.Wd[1] = 80; d.Wd[2] = 112;
        gemm_ow<<<dim3(25,8,3), 256, 0, stream>>>(d, X6b, view_w);
    }

    final_k<<<7168, 256, 0, stream>>>(img, Aax, Asag, Acor, (float*)d_out);
}

// Round 14
// 416.234 us; speedup vs baseline: 2.1264x; 1.0567x over previous
//
#include <hip/hip_runtime.h>
#include <math.h>

typedef __attribute__((ext_vector_type(8))) short s8;
typedef __attribute__((ext_vector_type(4))) float f4;
typedef unsigned short u16;

__device__ inline u16 f2bf(float f) {
    unsigned u = __float_as_uint(f);
    u += 0x7fffu + ((u >> 16) & 1u);
    return (u16)(u >> 16);
}
__device__ inline float bf2f(u16 x) {
    return __uint_as_float(((unsigned)x) << 16);
}
#define MFMA16(a, b, c) __builtin_amdgcn_mfma_f32_16x16x32_bf16(a, b, c, 0, 0, 0)

// ============ prep: weight transposes + axis means (1 launch) ============
struct TT {
    const float* in[16];
    u16* out[16];
    int K[16];
    int N[16];
    int start[16];
    int total;
};

__global__ __launch_bounds__(256) void prep_k(TT tab, const float* __restrict__ img,
                                              float* __restrict__ axp,
                                              float* __restrict__ sag,
                                              float* __restrict__ cor) {
    __shared__ float sl[112*81];
    int bid = blockIdx.x;
    int t = threadIdx.x;
    if (bid < 1024) {
        int dc = bid & 15, bc = bid >> 4;
        int d0 = dc * 7;
        f4 axr[9];
        #pragma unroll
        for (int k = 0; k < 9; ++k) axr[k] = (f4){0.f,0.f,0.f,0.f};
        const float* base = img + (size_t)bc * 1003520 + (size_t)d0 * 8960;
        for (int sidx = 0; sidx < 7; ++sidx) {
            const f4* sp = reinterpret_cast<const f4*>(base + (size_t)sidx * 8960);
            #pragma unroll
            for (int k = 0; k < 9; ++k) {
                int q = t + k * 256;
                if (q < 2240) {
                    f4 v = __builtin_nontemporal_load(&sp[q]);
                    axr[k] += v;
                    int h = q / 20, w4 = q % 20;
                    float* row = &sl[h * 81 + w4 * 4];
                    row[0] = v[0]; row[1] = v[1]; row[2] = v[2]; row[3] = v[3];
                }
            }
            __syncthreads();
            if (t < 112) {
                float acc = 0.f;
                #pragma unroll 8
                for (int w = 0; w < 80; ++w) acc += sl[t * 81 + w];
                cor[((size_t)bc * 112 + d0 + sidx) * 112 + t] = acc * (1.f / 80.f);
            } else if (t < 192) {
                int w = t - 112;
                float acc = 0.f;
                #pragma unroll 8
                for (int h = 0; h < 112; ++h) acc += sl[h * 81 + w];
                sag[((size_t)bc * 112 + d0 + sidx) * 80 + w] = acc * (1.f / 112.f);
            }
            __syncthreads();
        }
        float* axo = axp + ((size_t)dc * 64 + bc) * 8960;
        #pragma unroll
        for (int k = 0; k < 9; ++k) {
            int q = t + k * 256;
            if (q < 2240) *reinterpret_cast<f4*>(axo + q * 4) = axr[k];
        }
        return;
    }
    int tb = bid - 1024;
    // ---- transpose tile ----
    float (*tl)[33] = reinterpret_cast<float(*)[33]>(sl);
    int e = 0;
    #pragma unroll
    for (int i = 1; i < 16; ++i) if (tb >= tab.start[i]) e = i;
    const float* in = tab.in[e];
    u16* out = tab.out[e];
    int K = tab.K[e], N = tab.N[e];
    int tid = tb - tab.start[e];
    int nt = N >> 5;
    int k0 = (tid / nt) * 32, n0 = (tid % nt) * 32;
    int r = t >> 5, c = t & 31;
    #pragma unroll
    for (int i = 0; i < 4; ++i) tl[r + i*8][c] = in[(long)(k0 + r + i*8)*N + n0 + c];
    __syncthreads();
    #pragma unroll
    for (int i = 0; i < 4; ++i) out[(long)(n0 + r + i*8)*K + k0 + c] = f2bf(tl[c][r + i*8]);
}

// ============ patchify, 3 branches; br0 sums ax partials ============
__global__ __launch_bounds__(256) void patchify3_k(const float* __restrict__ axp,
                                                   const float* __restrict__ m_sag,
                                                   const float* __restrict__ m_cor,
                                                   u16* __restrict__ P0, u16* __restrict__ P1,
                                                   u16* __restrict__ P2) {
    __shared__ float sl[32][113];
    int br = blockIdx.y;
    int X = blockIdx.x;
    int b = X / 112, rem = X % 112;
    int hh = rem / 7, pp1 = rem % 7;
    const float* src; u16* dst; int Wt, p2, PD;
    if (br == 0)      { src = nullptr; dst = P0; Wt = 80;  p2 = 5; PD = 1120; }
    else if (br == 1) { src = m_sag;   dst = P1; Wt = 80;  p2 = 5; PD = 1120; }
    else              { src = m_cor;   dst = P2; Wt = 112; p2 = 7; PD = 1568; }
    int t = threadIdx.x;
    int row = hh*7 + pp1;
    int wq = Wt >> 2;
    if (br == 0) {
        for (int i = t; i < 32*20; i += 256) {
            int c = i / 20, w4 = i % 20;
            f4 s = (f4){0.f,0.f,0.f,0.f};
            size_t base = ((size_t)(b*32 + c)*112 + row)*80 + w4*4;
            #pragma unroll
            for (int p = 0; p < 16; ++p)
                s += *reinterpret_cast<const f4*>(axp + (size_t)p*573440 + base);
            s *= (1.f/112.f);
            sl[c][w4*4+0] = s[0]; sl[c][w4*4+1] = s[1]; sl[c][w4*4+2] = s[2]; sl[c][w4*4+3] = s[3];
        }
    } else {
        for (int i = t; i < 32*wq; i += 256) {
            int c = i / wq, w4 = i % wq;
            float4 v = *reinterpret_cast<const float4*>(
                src + ((size_t)(b*32 + c)*112 + row)*Wt + w4*4);
            sl[c][w4*4+0] = v.x; sl[c][w4*4+1] = v.y; sl[c][w4*4+2] = v.z; sl[c][w4*4+3] = v.w;
        }
    }
    __syncthreads();
    int tot = 16 * p2 * 32;
    for (int o = t; o < tot; o += 256) {
        int ww = o / (p2*32), rest = o % (p2*32);
        int pp2 = rest >> 5, c = rest & 31;
        dst[((size_t)(b*256 + hh*16 + ww))*PD + (pp1*p2 + pp2)*32 + c]
            = f2bf(sl[c][ww*p2 + pp2]);
    }
}

// ============ GEMM building blocks (64-tile): BK=128, double-buffered LDS ============
__device__ inline void load_tile(const u16* __restrict__ P, int ld, int nrows, int K,
                                 int r0, int k0, int t, s8 v[4]) {
    #pragma unroll
    for (int i = 0; i < 4; ++i) {
        int chunk = t + i*256;
        int row = chunk >> 4, c8 = (chunk & 15) * 8;
        s8 x;
        #pragma unroll
        for (int q = 0; q < 8; ++q) x[q] = 0;
        if (r0 + row < nrows && k0 + c8 < K)
            x = *reinterpret_cast<const s8*>(P + (long)(r0 + row)*ld + k0 + c8);
        v[i] = x;
    }
}
__device__ inline void load_tile_f32(const float* __restrict__ P, int ld, int nrows, int K,
                                     int r0, int k0, int t, s8 v[4]) {
    #pragma unroll
    for (int i = 0; i < 4; ++i) {
        int chunk = t + i*256;
        int row = chunk >> 4, c8 = (chunk & 15) * 8;
        s8 x;
        #pragma unroll
        for (int q = 0; q < 8; ++q) x[q] = 0;
        if (r0 + row < nrows && k0 + c8 < K) {
            const float* src = P + (long)(r0 + row)*ld + k0 + c8;
            #pragma unroll
            for (int q = 0; q < 8; ++q) x[q] = (short)f2bf(src[q]);
        }
        v[i] = x;
    }
}
__device__ inline void write_tile(u16 (*S)[136], int t, const s8 v[4]) {
    #pragma unroll
    for (int i = 0; i < 4; ++i) {
        int chunk = t + i*256;
        *reinterpret_cast<s8*>(&S[chunk >> 4][(chunk & 15)*8]) = v[i];
    }
}
__device__ inline void mfma_tile(const u16 (*As)[136], const u16 (*Bs)[136],
                                 int wr, int wc, int lane, f4 acc[2][2]) {
    int lrow = lane & 15;
    #pragma unroll
    for (int kh = 0; kh < 4; ++kh) {
        int lk = kh*32 + (lane >> 4) * 8;
        s8 af0 = *reinterpret_cast<const s8*>(&As[wr*32 + lrow][lk]);
        s8 af1 = *reinterpret_cast<const s8*>(&As[wr*32 + 16 + lrow][lk]);
        s8 bg0 = *reinterpret_cast<const s8*>(&Bs[wc*32 + lrow][lk]);
        s8 bg1 = *reinterpret_cast<const s8*>(&Bs[wc*32 + 16 + lrow][lk]);
        acc[0][0] = MFMA16(af0, bg0, acc[0][0]);
        acc[0][1] = MFMA16(af0, bg1, acc[0][1]);
        acc[1][0] = MFMA16(af1, bg0, acc[1][0]);
        acc[1][1] = MFMA16(af1, bg1, acc[1][1]);
    }
}

// ============ bf16 MFMA GEMM (64-tile): epilogue w/ split-bias, resid, act, Vt scatter ====
__global__ __launch_bounds__(256) void gemm_bf(
    const u16* __restrict__ A, const u16* __restrict__ Bt,
    float* __restrict__ Cf, u16* __restrict__ Cb,
    int M, int N, int K,
    const float* __restrict__ bias, const float* __restrict__ bias2,
    const float* __restrict__ resid, int act, u16* __restrict__ vt)
{
    __shared__ u16 As[2][64][136];
    __shared__ u16 Bs[2][64][136];
    int t = threadIdx.x;
    int m0 = blockIdx.y * 64, n0 = blockIdx.x * 64;
    int wave = t >> 6, lane = t & 63;
    int wr = wave >> 1, wc = wave & 1;
    f4 acc[2][2];
    #pragma unroll
    for (int m = 0; m < 2; ++m)
        #pragma unroll
        for (int n = 0; n < 2; ++n)
            #pragma unroll
            for (int r = 0; r < 4; ++r) acc[m][n][r] = 0.f;
    int nk = (K + 127) >> 7;
    s8 pa[4], pbv[4];
    load_tile(A, K, M, K, m0, 0, t, pa);
    load_tile(Bt, K, N, K, n0, 0, t, pbv);
    write_tile(As[0], t, pa);
    write_tile(Bs[0], t, pbv);
    __syncthreads();
    for (int kt = 0; kt < nk; ++kt) {
        int cur = kt & 1;
        if (kt + 1 < nk) {
            load_tile(A, K, M, K, m0, (kt+1) << 7, t, pa);
            load_tile(Bt, K, N, K, n0, (kt+1) << 7, t, pbv);
        }
        mfma_tile(As[cur], Bs[cur], wr, wc, lane, acc);
        if (kt + 1 < nk) {
            write_tile(As[cur^1], t, pa);
            write_tile(Bs[cur^1], t, pbv);
        }
        __syncthreads();
    }
    #pragma unroll
    for (int m = 0; m < 2; ++m) {
        int rbase = m0 + wr*32 + m*16 + (lane >> 4) * 4;
        #pragma unroll
        for (int n = 0; n < 2; ++n) {
            int col = n0 + wc*32 + n*16 + (lane & 15);
            if (col >= N) continue;
            #pragma unroll
            for (int r = 0; r < 4; ++r) {
                int row = rbase + r;
                if (row >= M) continue;
                float v = acc[m][n][r];
                if (bias) {
                    float bb = bias2 ? ((col < 768) ? bias[col] : bias2[col - 768]) : bias[col];
                    v += bb;
                }
                if (resid) v += resid[(long)row * N + col];
                if (act == 1) v = 0.5f * v * (1.0f + erff(v * 0.70710678118654752f));
                long ci = (long)row * N + col;
                u16 b = f2bf(v);
                if (Cf) Cf[ci] = v;
                if (Cb) Cb[ci] = b;
                if (vt && col >= 1536) {
                    int z = (row >> 8) * 12 + ((col - 1536) >> 6);
                    vt[((long)z * 64 + (col & 63)) * 256 + (row & 255)] = b;
                }
            }
        }
    }
}

// ============ batched patch-embed (+QH from fp32 txt) GEMM ============
struct PeDesc {
    const u16* A[3];
    const u16* Bt[4];
    const float* bias[4];
    const float* pos[3];
    int K[4];
    int M[4];
};

__global__ __launch_bounds__(256) void gemm_pe(PeDesc d, const float* __restrict__ txtf,
                                               float* __restrict__ C, u16* __restrict__ QHb) {
    int z = blockIdx.z;
    int M = d.M[z], K = d.K[z];
    int m0 = blockIdx.y * 64, n0 = blockIdx.x * 64;
    if (m0 >= M) return;
    __shared__ u16 As[2][64][136];
    __shared__ u16 Bs[2][64][136];
    const u16* Bb = d.Bt[z];
    const float* bias = d.bias[z];
    int t = threadIdx.x;
    int wave = t >> 6, lane = t & 63;
    int wr = wave >> 1, wc = wave & 1;
    f4 acc[2][2];
    #pragma unroll
    for (int m = 0; m < 2; ++m)
        #pragma unroll
        for (int n = 0; n < 2; ++n)
            #pragma unroll
            for (int r = 0; r < 4; ++r) acc[m][n][r] = 0.f;
    int nk = (K + 127) >> 7;
    s8 pa[4], pbv[4];
    if (z < 3) load_tile(d.A[z], K, M, K, m0, 0, t, pa);
    else       load_tile_f32(txtf, K, M, K, m0, 0, t, pa);
    load_tile(Bb, K, 768, K, n0, 0, t, pbv);
    write_tile(As[0], t, pa);
    write_tile(Bs[0], t, pbv);
    __syncthreads();
    for (int kt = 0; kt < nk; ++kt) {
        int cur = kt & 1;
        if (kt + 1 < nk) {
            if (z < 3) load_tile(d.A[z], K, M, K, m0, (kt+1) << 7, t, pa);
            else       load_tile_f32(txtf, K, M, K, m0, (kt+1) << 7, t, pa);
            load_tile(Bb, K, 768, K, n0, (kt+1) << 7, t, pbv);
        }
        mfma_tile(As[cur], Bs[cur], wr, wc, lane, acc);
        if (kt + 1 < nk) {
            write_tile(As[cur^1], t, pa);
            write_tile(Bs[cur^1], t, pbv);
        }
        __syncthreads();
    }
    #pragma unroll
    for (int m = 0; m < 2; ++m) {
        int rbase = m0 + wr*32 + m*16 + (lane >> 4) * 4;
        #pragma unroll
        for (int n = 0; n < 2; ++n) {
            int col = n0 + wc*32 + n*16 + (lane & 15);
            #pragma unroll
            for (int r = 0; r < 4; ++r) {
                int row = rbase + r;
                if (row >= M) continue;
                float v = acc[m][n][r] + bias[col];
                if (z < 3) {
                    v += d.pos[z][(long)(row & 255)*768 + col];
                    C[((long)z*512 + row) * 768 + col] = v;
                } else {
                    QHb[(long)row * 768 + col] = f2bf(v);
                }
            }
        }
    }
}

// ============ output-proj GEMM + fused unpatchify ============
struct OwDesc {
    const u16* Bt[3];
    float* plane[3];
    const float* bias[3];
    int N[3];
    int p2[3];
    int Wd[3];
};

__global__ __launch_bounds__(256) void gemm_ow(OwDesc d, const u16* __restrict__ A,
                                               const float* __restrict__ vwp) {
    int z = blockIdx.z;
    int N = d.N[z];
    int n0 = blockIdx.x * 64;
    if (n0 >= N) return;
    __shared__ u16 As[2][64][136];
    __shared__ u16 Bs[2][64][136];
    const u16* Ab = A + (long)z * 512 * 768;
    const u16* Bb = d.Bt[z];
    int t = threadIdx.x;
    int m0 = blockIdx.y * 64;
    int wave = t >> 6, lane = t & 63;
    int wr = wave >> 1, wc = wave & 1;
    f4 acc[2][2];
    #pragma unroll
    for (int m = 0; m < 2; ++m)
        #pragma unroll
        for (int n = 0; n < 2; ++n)
            #pragma unroll
            for (int r = 0; r < 4; ++r) acc[m][n][r] = 0.f;
    s8 pa[4], pbv[4];
    load_tile(Ab, 768, 512, 768, m0, 0, t, pa);
    load_tile(Bb, 768, N, 768, n0, 0, t, pbv);
    write_tile(As[0], t, pa);
    write_tile(Bs[0], t, pbv);
    __syncthreads();
    for (int kt = 0; kt < 6; ++kt) {
        int cur = kt & 1;
        if (kt + 1 < 6) {
            load_tile(Ab, 768, 512, 768, m0, (kt+1) << 7, t, pa);
            load_tile(Bb, 768, N, 768, n0, (kt+1) << 7, t, pbv);
        }
        mfma_tile(As[cur], Bs[cur], wr, wc, lane, acc);
        if (kt + 1 < 6) {
            write_tile(As[cur^1], t, pa);
            write_tile(Bs[cur^1], t, pbv);
        }
        __syncthreads();
    }
    float* plane = d.plane[z];
    const float* bias = d.bias[z];
    int p2 = d.p2[z], Wd = d.Wd[z];
    float wt = vwp[z];
    #pragma unroll
    for (int m = 0; m < 2; ++m) {
        int rbase = m0 + wr*32 + m*16 + (lane >> 4) * 4;
        #pragma unroll
        for (int n = 0; n < 2; ++n) {
            int col = n0 + wc*32 + n*16 + (lane & 15);
            if (col >= N) continue;
            int pp = col >> 5, c = col & 31;
            int pp1 = pp / p2, pp2 = pp % p2;
            float bv = bias[col];
            #pragma unroll
            for (int r = 0; r < 4; ++r) {
                int row = rbase + r;
                int b = row >> 8, nn = row & 255;
                int hh = nn >> 4, ww = nn & 15;
                plane[((long)(b*32 + c)*112 + hh*7 + pp1)*Wd + ww*p2 + pp2]
                    = wt * (acc[m][n][r] + bv);
            }
        }
    }
}

// ============ LayerNorm rows of 768 ============
__global__ __launch_bounds__(256) void ln_k(const float* __restrict__ in,
                                            float* __restrict__ outf,
                                            u16* __restrict__ outb,
                                            const float* __restrict__ g,
                                            const float* __restrict__ bta) {
    constexpr int N = 768;
    int row = blockIdx.x;
    const float* x = in + (size_t)row * N;
    int t = threadIdx.x;
    float v0 = x[t], v1 = x[t+256], v2 = x[t+512];
    float s = v0+v1+v2, s2 = v0*v0+v1*v1+v2*v2;
    #pragma unroll
    for (int off = 32; off > 0; off >>= 1) { s += __shfl_down(s, off); s2 += __shfl_down(s2, off); }
    __shared__ float red[8];
    int wid = t >> 6, lane = t & 63;
    if (lane == 0) { red[wid] = s; red[wid+4] = s2; }
    __syncthreads();
    if (t == 0) {
        float S = red[0]+red[1]+red[2]+red[3];
        float S2 = red[4]+red[5]+red[6]+red[7];
        float mean = S * (1.f/N);
        float var = S2 * (1.f/N) - mean*mean;
        red[0] = mean; red[1] = rsqrtf(var + 1e-5f);
    }
    __syncthreads();
    float mean = red[0], rstd = red[1];
    float y0 = (v0-mean)*rstd*g[t]     + bta[t];
    float y1 = (v1-mean)*rstd*g[t+256] + bta[t+256];
    float y2 = (v2-mean)*rstd*g[t+512] + bta[t+512];
    if (outf) {
        float* y = outf + (size_t)row * N;
        y[t] = y0; y[t+256] = y1; y[t+512] = y2;
    }
    if (outb) {
        u16* y = outb + (size_t)row * N;
        y[t] = f2bf(y0); y[t+256] = f2bf(y1); y[t+512] = f2bf(y2);
    }
}

// ============ fully fused self-attention ============
__global__ __launch_bounds__(256) void attn_k(const u16* __restrict__ QKV,
                                              const u16* __restrict__ Vt,
                                              u16* __restrict__ O) {
    __shared__ u16 Ks[256][72];
    __shared__ u16 Ps[128][264];
    __shared__ u16 Vs[64][264];
    int zz = blockIdx.x;
    int bh = zz >> 1, half = zz & 1;
    int bb = bh / 12, h = bh % 12;
    long qrow0 = (long)bb*256 + half*128;
    int hcol = h*64;
    int t = threadIdx.x;
    int wave = t >> 6, lane = t & 63;
    int lr = lane & 15, lg = lane >> 4;
    #pragma unroll
    for (int i = 0; i < 8; ++i) {
        int chunk = t + i*256;
        int row = chunk >> 3, c8 = (chunk & 7)*8;
        *reinterpret_cast<s8*>(&Ks[row][c8]) =
            *reinterpret_cast<const s8*>(QKV + ((long)bb*256 + row)*2304 + 768 + hcol + c8);
    }
    #pragma unroll
    for (int i = 0; i < 8; ++i) {
        int chunk = t + i*256;
        int d = chunk >> 5, j8 = (chunk & 31)*8;
        *reinterpret_cast<s8*>(&Vs[d][j8]) =
            *reinterpret_cast<const s8*>(Vt + (long)bh*16384 + (long)d*256 + j8);
    }
    __syncthreads();
    f4 acc[2][16];
    #pragma unroll
    for (int m = 0; m < 2; ++m)
        #pragma unroll
        for (int n = 0; n < 16; ++n)
            #pragma unroll
            for (int r = 0; r < 4; ++r) acc[m][n][r] = 0.f;
    #pragma unroll
    for (int kh = 0; kh < 2; ++kh) {
        s8 af0 = *reinterpret_cast<const s8*>(QKV + (qrow0 + wave*32 + lr)*2304 + hcol + kh*32 + lg*8);
        s8 af1 = *reinterpret_cast<const s8*>(QKV + (qrow0 + wave*32 + 16 + lr)*2304 + hcol + kh*32 + lg*8);
        #pragma unroll
        for (int n = 0; n < 16; ++n) {
            s8 bf = *reinterpret_cast<const s8*>(&Ks[n*16 + lr][kh*32 + lg*8]);
            acc[0][n] = MFMA16(af0, bf, acc[0][n]);
            acc[1][n] = MFMA16(af1, bf, acc[1][n]);
        }
    }
    #pragma unroll
    for (int m = 0; m < 2; ++m)
        #pragma unroll
        for (int r = 0; r < 4; ++r) {
            float mx = -1e30f;
            #pragma unroll
            for (int n = 0; n < 16; ++n) mx = fmaxf(mx, acc[m][n][r]);
            #pragma unroll
            for (int o = 8; o; o >>= 1) mx = fmaxf(mx, __shfl_xor(mx, o));
            float l = 0.f;
            float p[16];
            #pragma unroll
            for (int n = 0; n < 16; ++n) {
                p[n] = __expf((acc[m][n][r] - mx) * 0.125f);
                l += p[n];
            }
            #pragma unroll
            for (int o = 8; o; o >>= 1) l += __shfl_xor(l, o);
            float inv = 1.f / l;
            int prow = wave*32 + m*16 + lg*4 + r;
            #pragma unroll
            for (int n = 0; n < 16; ++n)
                Ps[prow][n*16 + lr] = f2bf(p[n] * inv);
        }
    __syncthreads();
    f4 o2[2][4];
    #pragma unroll
    for (int m = 0; m < 2; ++m)
        #pragma unroll
        for (int n = 0; n < 4; ++n)
            #pragma unroll
            for (int r = 0; r < 4; ++r) o2[m][n][r] = 0.f;
    #pragma unroll
    for (int kh = 0; kh < 8; ++kh) {
        s8 pf0 = *reinterpret_cast<const s8*>(&Ps[wave*32 + lr][kh*32 + lg*8]);
        s8 pf1 = *reinterpret_cast<const s8*>(&Ps[wave*32 + 16 + lr][kh*32 + lg*8]);
        #pragma unroll
        for (int n = 0; n < 4; ++n) {
            s8 vf = *reinterpret_cast<const s8*>(&Vs[n*16 + lr][kh*32 + lg*8]);
            o2[0][n] = MFMA16(pf0, vf, o2[0][n]);
            o2[1][n] = MFMA16(pf1, vf, o2[1][n]);
        }
    }
    #pragma unroll
    for (int m = 0; m < 2; ++m)
        #pragma unroll
        for (int n = 0; n < 4; ++n)
            #pragma unroll
            for (int r = 0; r < 4; ++r)
                O[(qrow0 + wave*32 + m*16 + lg*4 + r)*768 + hcol + n*16 + lr] = f2bf(o2[m][n][r]);
}

// ============ fully fused cross-attention ============
__global__ __launch_bounds__(256) void ca_fused(const u16* __restrict__ QHb,
                                                const u16* __restrict__ KVHb,
                                                u16* __restrict__ O) {
    __shared__ u16 QHs[80][72];
    __shared__ u16 KHs[256][72];
    __shared__ float rmax[80][4];
    __shared__ float rsum[80][4];
    __shared__ float Wj[256];
    int bh = blockIdx.x;
    int rowblk = bh / 12, h = bh % 12;
    int bsel = rowblk & 1;
    int t = threadIdx.x;
    int wave = t >> 6, lane = t & 63;
    int lr = lane & 15, lg = lane >> 4;
    #pragma unroll
    for (int i = 0; i < 3; ++i) {
        int chunk = t + i*256;
        if (chunk < 640) {
            int row = chunk >> 3, c8 = (chunk & 7)*8;
            s8 v;
            #pragma unroll
            for (int q = 0; q < 8; ++q) v[q] = 0;
            if (row < 77)
                v = *reinterpret_cast<const s8*>(QHb + ((long)(bsel*77 + row))*768 + h*64 + c8);
            *reinterpret_cast<s8*>(&QHs[row][c8]) = v;
        }
    }
    #pragma unroll
    for (int i = 0; i < 8; ++i) {
        int chunk = t + i*256;
        int row = chunk >> 3, c8 = (chunk & 7)*8;
        *reinterpret_cast<s8*>(&KHs[row][c8]) =
            *reinterpret_cast<const s8*>(KVHb + ((long)rowblk*256 + row)*1536 + h*64 + c8);
    }
    __syncthreads();
    f4 acc[5][4];
    #pragma unroll
    for (int m = 0; m < 5; ++m)
        #pragma unroll
        for (int n = 0; n < 4; ++n)
            #pragma unroll
            for (int r = 0; r < 4; ++r) acc[m][n][r] = 0.f;
    #pragma unroll
    for (int kh = 0; kh < 2; ++kh) {
        s8 af[5], bf[4];
        #pragma unroll
        for (int m = 0; m < 5; ++m)
            af[m] = *reinterpret_cast<const s8*>(&QHs[m*16 + lr][kh*32 + lg*8]);
        #pragma unroll
        for (int n = 0; n < 4; ++n)
            bf[n] = *reinterpret_cast<const s8*>(&KHs[wave*64 + n*16 + lr][kh*32 + lg*8]);
        #pragma unroll
        for (int m = 0; m < 5; ++m)
            #pragma unroll
            for (int n = 0; n < 4; ++n)
                acc[m][n] = MFMA16(af[m], bf[n], acc[m][n]);
    }
    #pragma unroll
    for (int m = 0; m < 5; ++m)
        #pragma unroll
        for (int r = 0; r < 4; ++r) {
            float mx = -1e30f;
            #pragma unroll
            for (int n = 0; n < 4; ++n) mx = fmaxf(mx, acc[m][n][r]);
            #pragma unroll
            for (int o = 8; o; o >>= 1) mx = fmaxf(mx, __shfl_xor(mx, o));
            if (lr == 0) rmax[m*16 + lg*4 + r][wave] = mx;
        }
    __syncthreads();
    #pragma unroll
    for (int m = 0; m < 5; ++m)
        #pragma unroll
        for (int r = 0; r < 4; ++r) {
            int i = m*16 + lg*4 + r;
            float mi = fmaxf(fmaxf(rmax[i][0], rmax[i][1]), fmaxf(rmax[i][2], rmax[i][3]));
            float s = 0.f;
            #pragma unroll
            for (int n = 0; n < 4; ++n) s += __expf((acc[m][n][r] - mi) * 0.125f);
            #pragma unroll
            for (int o = 8; o; o >>= 1) s += __shfl_xor(s, o);
            if (lr == 0) rsum[i][wave] = s;
        }
    __syncthreads();
    float wn[4] = {0.f, 0.f, 0.f, 0.f};
    #pragma unroll
    for (int m = 0; m < 5; ++m)
        #pragma unroll
        for (int r = 0; r < 4; ++r) {
            int i = m*16 + lg*4 + r;
            if (i < 77) {
                float mi = fmaxf(fmaxf(rmax[i][0], rmax[i][1]), fmaxf(rmax[i][2], rmax[i][3]));
                float li = rsum[i][0] + rsum[i][1] + rsum[i][2] + rsum[i][3];
                float inv = 1.f / li;
                #pragma unroll
                for (int n = 0; n < 4; ++n)
                    wn[n] += __expf((acc[m][n][r] - mi) * 0.125f) * inv;
            }
        }
    #pragma unroll
    for (int n = 0; n < 4; ++n) {
        wn[n] += __shfl_xor(wn[n], 16);
        wn[n] += __shfl_xor(wn[n], 32);
    }
    if (lane < 16) {
        #pragma unroll
        for (int n = 0; n < 4; ++n) Wj[wave*64 + n*16 + lr] = wn[n];
    }
    __syncthreads();
    int d = t & 63;
    #pragma unroll 4
    for (int it = 0; it < 64; ++it) {
        int j = it*4 + (t >> 6);
        long row = (long)rowblk*256 + j;
        float vh = bf2f(KVHb[row*1536 + 768 + h*64 + d]);
        O[row*768 + h*64 + d] = f2bf(Wj[j] * vh);
    }
}

// ============ streaming final combine (non-temporal img/out) ============
__global__ __launch_bounds__(256) void final_k(const float* __restrict__ img,
                                               const float* __restrict__ Aax,
                                               const float* __restrict__ Asag,
                                               const float* __restrict__ Acor,
                                               float* __restrict__ out) {
    int blk = blockIdx.x;                 // bc*112 + d
    int bc = blk / 112;
    const f4* ip = reinterpret_cast<const f4*>(img + (size_t)blk * 8960);
    const f4* ap = reinterpret_cast<const f4*>(Aax + (size_t)bc * 8960);
    const f4* sp = reinterpret_cast<const f4*>(Asag + (size_t)blk * 80);
    const float* cp = Acor + (size_t)blk * 112;
    f4* op = reinterpret_cast<f4*>(out + (size_t)blk * 8960);
    int t = threadIdx.x;
    #pragma unroll
    for (int k = 0; k < 9; ++k) {
        int q = t + k * 256;
        if (q < 2240) {
            f4 iv = __builtin_nontemporal_load(&ip[q]);
            int h = q / 20, w4 = q % 20;
            float cv = cp[h];
            f4 r = iv + ap[q] + sp[w4] + (f4){cv, cv, cv, cv};
            __builtin_nontemporal_store(r, &op[q]);
        }
    }
}

extern "C" void kernel_launch(void* const* d_in, const int* in_sizes, int n_in,
                              void* d_out, int out_size, void* d_ws, size_t ws_size,
                              hipStream_t stream) {
    (void)in_sizes; (void)n_in; (void)out_size; (void)ws_size;
    const float* img    = (const float*)d_in[0];
    const float* txt    = (const float*)d_in[1];
    const float* pe_w[3] = {(const float*)d_in[2], (const float*)d_in[4], (const float*)d_in[6]};
    const float* pe_b[3] = {(const float*)d_in[3], (const float*)d_in[5], (const float*)d_in[7]};
    const float* pos[3]  = {(const float*)d_in[8], (const float*)d_in[9], (const float*)d_in[10]};
    const float* qw = (const float*)d_in[11];
    const float* kw = (const float*)d_in[12];
    const float* vw_attn = (const float*)d_in[13];
    const float* pw = (const float*)d_in[14];
    const float* pb = (const float*)d_in[15];
    const float* caq_w = (const float*)d_in[16];
    const float* caq_b = (const float*)d_in[17];
    const float* cak_w = (const float*)d_in[18];
    const float* cak_b = (const float*)d_in[19];
    const float* cav_w = (const float*)d_in[20];
    const float* cav_b = (const float*)d_in[21];
    const float* cao_w = (const float*)d_in[22];
    const float* cao_b = (const float*)d_in[23];
    const float* mlp_w1 = (const float*)d_in[24];
    const float* mlp_b1 = (const float*)d_in[25];
    const float* mlp_w2 = (const float*)d_in[26];
    const float* mlp_b2 = (const float*)d_in[27];
    const float* ow[3] = {(const float*)d_in[28], (const float*)d_in[30], (const float*)d_in[32]};
    const float* ob[3] = {(const float*)d_in[29], (const float*)d_in[31], (const float*)d_in[33]};
    const float* view_w = (const float*)d_in[34];
    const float* n_g[3] = {(const float*)d_in[35], (const float*)d_in[36], (const float*)d_in[37]};
    const float* n_b[3] = {(const float*)d_in[38], (const float*)d_in[39], (const float*)d_in[40]};

    typedef unsigned short u16t;
    unsigned char* sb = (unsigned char*)d_out;
    size_t off = 0;
    auto B = [&](size_t bytes) -> void* {
        void* p = sb + off; off += (bytes + 511) & ~(size_t)511; return p;
    };
    u16t* qkvT  = (u16t*)B((size_t)2304*768*2);
    u16t* pwT   = (u16t*)B(768*768*2);
    u16t* caqT  = (u16t*)B(768*768*2);
    u16t* cakvT = (u16t*)B((size_t)1536*768*2);
    u16t* caoT  = (u16t*)B(768*768*2);
    u16t* mlp1T = (u16t*)B((size_t)3072*768*2);
    u16t* mlp2T = (u16t*)B((size_t)768*3072*2);
    u16t* peT[3]; peT[0] = (u16t*)B((size_t)768*1120*2); peT[1] = (u16t*)B((size_t)768*1120*2); peT[2] = (u16t*)B((size_t)768*1568*2);
    u16t* owT[3]; owT[0] = (u16t*)B((size_t)1120*768*2); owT[1] = (u16t*)B((size_t)1120*768*2); owT[2] = (u16t*)B((size_t)1568*768*2);
    float* axp   = (float*)B((size_t)16*573440*4);
    float* m_sag = (float*)B(573440*4);
    float* m_cor = (float*)B(802816*4);
    u16t* P0 = (u16t*)B((size_t)512*1120*2);
    u16t* P1 = (u16t*)B((size_t)512*1120*2);
    u16t* P2 = (u16t*)B((size_t)512*1568*2);
    float* X0  = (float*)B((size_t)1536*768*4);
    float* X1f = (float*)B((size_t)1536*768*4);
    float* X2  = (float*)B((size_t)1536*768*4);
    float* X3f = (float*)B((size_t)1536*768*4);
    float* X4  = (float*)B((size_t)1536*768*4);
    u16t* X1b = (u16t*)B((size_t)1536*768*2);
    u16t* X3b = (u16t*)B((size_t)1536*768*2);
    u16t* X5b = (u16t*)B((size_t)1536*768*2);
    u16t* X6b = (u16t*)B((size_t)1536*768*2);
    u16t* QKVb = (u16t*)B((size_t)1536*2304*2);
    u16t* Obf = (u16t*)B((size_t)1536*768*2);
    u16t* Vt  = (u16t*)B((size_t)72*64*256*2);
    u16t* Hb  = (u16t*)B((size_t)1536*3072*2);
    u16t* KVHb = (u16t*)B((size_t)1536*1536*2);
    u16t* QHb  = (u16t*)B((size_t)154*768*2);

    float* ws = (float*)d_ws;
    float* Aax  = ws;
    float* Asag = ws + 573440;
    float* Acor = ws + 1146880;

    // ---- prep: transposes + means (1 launch) ----
    TT tab;
    {
        const float* ins[16] = {qw, kw, vw_attn, pw, caq_w, cak_w, cav_w, cao_w,
                                mlp_w1, mlp_w2, pe_w[0], pe_w[1], pe_w[2], ow[0], ow[1], ow[2]};
        u16t* outs[16] = {qkvT, qkvT + 768*768, qkvT + 2*768*768, pwT, caqT, cakvT,
                          cakvT + 768*768, caoT, mlp1T, mlp2T, peT[0], peT[1], peT[2],
                          owT[0], owT[1], owT[2]};
        int Ks[16] = {768,768,768,768,768,768,768,768, 768,3072, 1120,1120,1568, 768,768,768};
        int Ns[16] = {768,768,768,768,768,768,768,768, 3072,768, 768,768,768, 1120,1120,1568};
        int st = 0;
        for (int i = 0; i < 16; ++i) {
            tab.in[i] = ins[i]; tab.out[i] = outs[i]; tab.K[i] = Ks[i]; tab.N[i] = Ns[i];
            tab.start[i] = st;
            st += (Ks[i] >> 5) * (Ns[i] >> 5);
        }
        tab.total = st;
        prep_k<<<1024 + st, 256, 0, stream>>>(tab, img, axp, m_sag, m_cor);
    }

    patchify3_k<<<dim3(224,3), 256, 0, stream>>>(axp, m_sag, m_cor, P0, P1, P2);

    auto gemm = [&](const u16t* A, const u16t* Bt, float* Cf, u16t* Cb,
                    int M, int N, int K, const float* bias, const float* bias2,
                    const float* resid, int act, u16t* vt) {
        dim3 g((N+63)/64, (M+63)/64, 1);
        gemm_bf<<<g, 256, 0, stream>>>(A, Bt, Cf, Cb, M, N, K, bias, bias2, resid, act, vt);
    };

    // pe (z<3) + QH projection (z=3), one launch
    {
        PeDesc d;
        d.A[0] = P0; d.A[1] = P1; d.A[2] = P2;
        d.Bt[0] = peT[0]; d.Bt[1] = peT[1]; d.Bt[2] = peT[2]; d.Bt[3] = caqT;
        d.bias[0] = pe_b[0]; d.bias[1] = pe_b[1]; d.bias[2] = pe_b[2]; d.bias[3] = caq_b;
        d.pos[0] = pos[0]; d.pos[1] = pos[1]; d.pos[2] = pos[2];
        d.K[0] = 1120; d.K[1] = 1120; d.K[2] = 1568; d.K[3] = 768;
        d.M[0] = 512; d.M[1] = 512; d.M[2] = 512; d.M[3] = 154;
        gemm_pe<<<dim3(12,8,4), 256, 0, stream>>>(d, txt, X0, QHb);
    }

    ln_k<<<1536, 256, 0, stream>>>(X0, X1f, X1b, n_g[0], n_b[0]);
    gemm(X1b, qkvT, nullptr, QKVb, 1536, 2304, 768, nullptr, nullptr, nullptr, 0, Vt);
    attn_k<<<144, 256, 0, stream>>>(QKVb, Vt, Obf);
    gemm(Obf, pwT, X2, nullptr, 1536, 768, 768, pb, nullptr, X1f, 0, nullptr);
    ln_k<<<1536, 256, 0, stream>>>(X2, X3f, X3b, n_g[1], n_b[1]);
    gemm(X3b, cakvT, nullptr, KVHb, 1536, 1536, 768, cak_b, cav_b, nullptr, 0, nullptr);
    ca_fused<<<72, 256, 0, stream>>>(QHb, KVHb, Obf);
    gemm(Obf, caoT, X4, nullptr, 1536, 768, 768, cao_b, nullptr, X3f, 0, nullptr);
    ln_k<<<1536, 256, 0, stream>>>(X4, nullptr, X5b, n_g[2], n_b[2]);
    gemm(X5b, mlp1T, nullptr, Hb, 1536, 3072, 768, mlp_b1, nullptr, nullptr, 1, nullptr);
    gemm(Hb, mlp2T, nullptr, X6b, 1536, 768, 3072, mlp_b2, nullptr, X4, 0, nullptr);
    {
        OwDesc d;
        d.Bt[0] = owT[0]; d.Bt[1] = owT[1]; d.Bt[2] = owT[2];
        d.plane[0] = Aax; d.plane[1] = Asag; d.plane[2] = Acor;
        d.bias[0] = ob[0]; d.bias[1] = ob[1]; d.bias[2] = ob[2];
        d.N[0] = 1120; d.N[1] = 1120; d.N[2] = 1568;
        d.p2[0] = 5; d.p2[1] = 5; d.p2[2] = 7;
        d.Wd[0] = 80; d.Wd[1] = 80; d.Wd[2] = 112;
        gemm_ow<<<dim3(25,8,3), 256, 0, stream>>>(d, X6b, view_w);
    }

    final_k<<<7168, 256, 0, stream>>>(img, Aax, Asag, Acor, (float*)d_out);
}

// Round 15
// 405.679 us; speedup vs baseline: 2.1817x; 1.0260x over previous
//
#include <hip/hip_runtime.h>
#include <math.h>

typedef __attribute__((ext_vector_type(8))) short s8;
typedef __attribute__((ext_vector_type(4))) float f4;
typedef unsigned short u16;

__device__ inline u16 f2bf(float f) {
    unsigned u = __float_as_uint(f);
    u += 0x7fffu + ((u >> 16) & 1u);
    return (u16)(u >> 16);
}
__device__ inline float bf2f(u16 x) {
    return __uint_as_float(((unsigned)x) << 16);
}
#define MFMA16(a, b, c) __builtin_amdgcn_mfma_f32_16x16x32_bf16(a, b, c, 0, 0, 0)

// ============ prep: weight transposes + axis means (1 launch) ============
struct TT {
    const float* in[16];
    u16* out[16];
    int K[16];
    int N[16];
    int start[16];
    int total;
};

__global__ __launch_bounds__(256) void prep_k(TT tab, const float* __restrict__ img,
                                              float* __restrict__ axp,
                                              float* __restrict__ sag,
                                              float* __restrict__ cor) {
    __shared__ float sl[112*81];
    int bid = blockIdx.x;
    int t = threadIdx.x;
    if (bid < 1024) {
        int dc = bid & 15, bc = bid >> 4;
        int d0 = dc * 7;
        f4 axr[9];
        #pragma unroll
        for (int k = 0; k < 9; ++k) axr[k] = (f4){0.f,0.f,0.f,0.f};
        const float* base = img + (size_t)bc * 1003520 + (size_t)d0 * 8960;
        for (int sidx = 0; sidx < 7; ++sidx) {
            const f4* sp = reinterpret_cast<const f4*>(base + (size_t)sidx * 8960);
            #pragma unroll
            for (int k = 0; k < 9; ++k) {
                int q = t + k * 256;
                if (q < 2240) {
                    f4 v = __builtin_nontemporal_load(&sp[q]);
                    axr[k] += v;
                    int h = q / 20, w4 = q % 20;
                    float* row = &sl[h * 81 + w4 * 4];
                    row[0] = v[0]; row[1] = v[1]; row[2] = v[2]; row[3] = v[3];
                }
            }
            __syncthreads();
            if (t < 112) {
                float acc = 0.f;
                #pragma unroll 8
                for (int w = 0; w < 80; ++w) acc += sl[t * 81 + w];
                cor[((size_t)bc * 112 + d0 + sidx) * 112 + t] = acc * (1.f / 80.f);
            } else if (t < 192) {
                int w = t - 112;
                float acc = 0.f;
                #pragma unroll 8
                for (int h = 0; h < 112; ++h) acc += sl[h * 81 + w];
                sag[((size_t)bc * 112 + d0 + sidx) * 80 + w] = acc * (1.f / 112.f);
            }
            __syncthreads();
        }
        float* axo = axp + ((size_t)dc * 64 + bc) * 8960;
        #pragma unroll
        for (int k = 0; k < 9; ++k) {
            int q = t + k * 256;
            if (q < 2240) *reinterpret_cast<f4*>(axo + q * 4) = axr[k];
        }
        return;
    }
    int tb = bid - 1024;
    float (*tl)[33] = reinterpret_cast<float(*)[33]>(sl);
    int e = 0;
    #pragma unroll
    for (int i = 1; i < 16; ++i) if (tb >= tab.start[i]) e = i;
    const float* in = tab.in[e];
    u16* out = tab.out[e];
    int K = tab.K[e], N = tab.N[e];
    int tid = tb - tab.start[e];
    int nt = N >> 5;
    int k0 = (tid / nt) * 32, n0 = (tid % nt) * 32;
    int r = t >> 5, c = t & 31;
    #pragma unroll
    for (int i = 0; i < 4; ++i) tl[r + i*8][c] = in[(long)(k0 + r + i*8)*N + n0 + c];
    __syncthreads();
    #pragma unroll
    for (int i = 0; i < 4; ++i) out[(long)(n0 + r + i*8)*K + k0 + c] = f2bf(tl[c][r + i*8]);
}

// ============ patchify, 3 branches; br0 sums ax partials ============
__global__ __launch_bounds__(256) void patchify3_k(const float* __restrict__ axp,
                                                   const float* __restrict__ m_sag,
                                                   const float* __restrict__ m_cor,
                                                   u16* __restrict__ P0, u16* __restrict__ P1,
                                                   u16* __restrict__ P2) {
    __shared__ float sl[32][113];
    int br = blockIdx.y;
    int X = blockIdx.x;
    int b = X / 112, rem = X % 112;
    int hh = rem / 7, pp1 = rem % 7;
    const float* src; u16* dst; int Wt, p2, PD;
    if (br == 0)      { src = nullptr; dst = P0; Wt = 80;  p2 = 5; PD = 1120; }
    else if (br == 1) { src = m_sag;   dst = P1; Wt = 80;  p2 = 5; PD = 1120; }
    else              { src = m_cor;   dst = P2; Wt = 112; p2 = 7; PD = 1568; }
    int t = threadIdx.x;
    int row = hh*7 + pp1;
    int wq = Wt >> 2;
    if (br == 0) {
        for (int i = t; i < 32*20; i += 256) {
            int c = i / 20, w4 = i % 20;
            f4 s = (f4){0.f,0.f,0.f,0.f};
            size_t base = ((size_t)(b*32 + c)*112 + row)*80 + w4*4;
            #pragma unroll
            for (int p = 0; p < 16; ++p)
                s += *reinterpret_cast<const f4*>(axp + (size_t)p*573440 + base);
            s *= (1.f/112.f);
            sl[c][w4*4+0] = s[0]; sl[c][w4*4+1] = s[1]; sl[c][w4*4+2] = s[2]; sl[c][w4*4+3] = s[3];
        }
    } else {
        for (int i = t; i < 32*wq; i += 256) {
            int c = i / wq, w4 = i % wq;
            float4 v = *reinterpret_cast<const float4*>(
                src + ((size_t)(b*32 + c)*112 + row)*Wt + w4*4);
            sl[c][w4*4+0] = v.x; sl[c][w4*4+1] = v.y; sl[c][w4*4+2] = v.z; sl[c][w4*4+3] = v.w;
        }
    }
    __syncthreads();
    int tot = 16 * p2 * 32;
    for (int o = t; o < tot; o += 256) {
        int ww = o / (p2*32), rest = o % (p2*32);
        int pp2 = rest >> 5, c = rest & 31;
        dst[((size_t)(b*256 + hh*16 + ww))*PD + (pp1*p2 + pp2)*32 + c]
            = f2bf(sl[c][ww*p2 + pp2]);
    }
}

// ============ legacy GEMM building blocks (64-tile, reg-staged, padded LDS) ============
__device__ inline void load_tile(const u16* __restrict__ P, int ld, int nrows, int K,
                                 int r0, int k0, int t, s8 v[4]) {
    #pragma unroll
    for (int i = 0; i < 4; ++i) {
        int chunk = t + i*256;
        int row = chunk >> 4, c8 = (chunk & 15) * 8;
        s8 x;
        #pragma unroll
        for (int q = 0; q < 8; ++q) x[q] = 0;
        if (r0 + row < nrows && k0 + c8 < K)
            x = *reinterpret_cast<const s8*>(P + (long)(r0 + row)*ld + k0 + c8);
        v[i] = x;
    }
}
__device__ inline void load_tile_f32(const float* __restrict__ P, int ld, int nrows, int K,
                                     int r0, int k0, int t, s8 v[4]) {
    #pragma unroll
    for (int i = 0; i < 4; ++i) {
        int chunk = t + i*256;
        int row = chunk >> 4, c8 = (chunk & 15) * 8;
        s8 x;
        #pragma unroll
        for (int q = 0; q < 8; ++q) x[q] = 0;
        if (r0 + row < nrows && k0 + c8 < K) {
            const float* src = P + (long)(r0 + row)*ld + k0 + c8;
            #pragma unroll
            for (int q = 0; q < 8; ++q) x[q] = (short)f2bf(src[q]);
        }
        v[i] = x;
    }
}
__device__ inline void write_tile(u16 (*S)[136], int t, const s8 v[4]) {
    #pragma unroll
    for (int i = 0; i < 4; ++i) {
        int chunk = t + i*256;
        *reinterpret_cast<s8*>(&S[chunk >> 4][(chunk & 15)*8]) = v[i];
    }
}
__device__ inline void mfma_tile(const u16 (*As)[136], const u16 (*Bs)[136],
                                 int wr, int wc, int lane, f4 acc[2][2]) {
    int lrow = lane & 15;
    #pragma unroll
    for (int kh = 0; kh < 4; ++kh) {
        int lk = kh*32 + (lane >> 4) * 8;
        s8 af0 = *reinterpret_cast<const s8*>(&As[wr*32 + lrow][lk]);
        s8 af1 = *reinterpret_cast<const s8*>(&As[wr*32 + 16 + lrow][lk]);
        s8 bg0 = *reinterpret_cast<const s8*>(&Bs[wc*32 + lrow][lk]);
        s8 bg1 = *reinterpret_cast<const s8*>(&Bs[wc*32 + 16 + lrow][lk]);
        acc[0][0] = MFMA16(af0, bg0, acc[0][0]);
        acc[0][1] = MFMA16(af0, bg1, acc[0][1]);
        acc[1][0] = MFMA16(af1, bg0, acc[1][0]);
        acc[1][1] = MFMA16(af1, bg1, acc[1][1]);
    }
}

// ============ gload_lds GEMM (64-tile, BK=128, dbuf, XOR-swizzled LDS) ============
// Requires M, N, K multiples of 64 and exact grid (no bounds checks).
__global__ __launch_bounds__(256) void gemm_gl(
    const u16* __restrict__ A, const u16* __restrict__ Bt,
    float* __restrict__ Cf, u16* __restrict__ Cb,
    int M, int N, int K,
    const float* __restrict__ bias, const float* __restrict__ bias2,
    const float* __restrict__ resid, int act, u16* __restrict__ vt)
{
    __shared__ u16 As[2][64*128];
    __shared__ u16 Bs[2][64*128];
    int t = threadIdx.x;
    int m0 = blockIdx.y * 64, n0 = blockIdx.x * 64;
    int wave = t >> 6, lane = t & 63;
    int wr = wave >> 1, wc = wave & 1;
    f4 acc[2][2];
    #pragma unroll
    for (int m = 0; m < 2; ++m)
        #pragma unroll
        for (int n = 0; n < 2; ++n)
            #pragma unroll
            for (int r = 0; r < 4; ++r) acc[m][n][r] = 0.f;
    int nk = K >> 7;
    // staging: chunk c = wave*256 + i*64 + lane; LDS linear; global pre-swizzled
    auto stage = [&](int buf, int k0) {
        #pragma unroll
        for (int i = 0; i < 4; ++i) {
            int c = wave*256 + i*64 + lane;
            int row = c >> 4, jl = c & 15;
            int jg = jl ^ (row & 7);
            const u16* ga = A  + (long)(m0 + row)*K + k0 + jg*8;
            const u16* gb = Bt + (long)(n0 + row)*K + k0 + jg*8;
            u16* la = &As[buf][(wave*256 + i*64) * 8];
            u16* lb = &Bs[buf][(wave*256 + i*64) * 8];
            __builtin_amdgcn_global_load_lds((const unsigned int*)ga, (unsigned int*)la, 16, 0, 0);
            __builtin_amdgcn_global_load_lds((const unsigned int*)gb, (unsigned int*)lb, 16, 0, 0);
        }
    };
    stage(0, 0);
    __syncthreads();
    int lrow = lane & 15, lg = lane >> 4;
    int r0a = wr*32 + lrow, r1a = r0a + 16;
    int r0b = wc*32 + lrow, r1b = r0b + 16;
    int sa = r0a & 7, sbx = r0b & 7;
    for (int kt = 0; kt < nk; ++kt) {
        int cur = kt & 1;
        if (kt + 1 < nk) stage(cur ^ 1, (kt + 1) << 7);
        #pragma unroll
        for (int kh = 0; kh < 4; ++kh) {
            int j = kh*4 + lg;                 // logical 16B chunk 0..15
            s8 af0 = *reinterpret_cast<const s8*>(&As[cur][r0a*128 + ((j ^ sa) << 3)]);
            s8 af1 = *reinterpret_cast<const s8*>(&As[cur][r1a*128 + ((j ^ sa) << 3)]);
            s8 bg0 = *reinterpret_cast<const s8*>(&Bs[cur][r0b*128 + ((j ^ sbx) << 3)]);
            s8 bg1 = *reinterpret_cast<const s8*>(&Bs[cur][r1b*128 + ((j ^ sbx) << 3)]);
            acc[0][0] = MFMA16(af0, bg0, acc[0][0]);
            acc[0][1] = MFMA16(af0, bg1, acc[0][1]);
            acc[1][0] = MFMA16(af1, bg0, acc[1][0]);
            acc[1][1] = MFMA16(af1, bg1, acc[1][1]);
        }
        __syncthreads();
    }
    #pragma unroll
    for (int m = 0; m < 2; ++m) {
        int rbase = m0 + wr*32 + m*16 + lg*4;
        #pragma unroll
        for (int n = 0; n < 2; ++n) {
            int col = n0 + wc*32 + n*16 + lrow;
            #pragma unroll
            for (int r = 0; r < 4; ++r) {
                int row = rbase + r;
                float v = acc[m][n][r];
                if (bias) {
                    float bb = bias2 ? ((col < 768) ? bias[col] : bias2[col - 768]) : bias[col];
                    v += bb;
                }
                if (resid) v += resid[(long)row * N + col];
                if (act == 1) v = 0.5f * v * (1.0f + erff(v * 0.70710678118654752f));
                long ci = (long)row * N + col;
                u16 b = f2bf(v);
                if (Cf) Cf[ci] = v;
                if (Cb) Cb[ci] = b;
                if (vt && col >= 1536) {
                    int z = (row >> 8) * 12 + ((col - 1536) >> 6);
                    vt[((long)z * 64 + (col & 63)) * 256 + (row & 255)] = b;
                }
            }
        }
    }
}

// ============ batched patch-embed (+QH from fp32 txt) GEMM ============
struct PeDesc {
    const u16* A[3];
    const u16* Bt[4];
    const float* bias[4];
    const float* pos[3];
    int K[4];
    int M[4];
};

__global__ __launch_bounds__(256) void gemm_pe(PeDesc d, const float* __restrict__ txtf,
                                               float* __restrict__ C, u16* __restrict__ QHb) {
    int z = blockIdx.z;
    int M = d.M[z], K = d.K[z];
    int m0 = blockIdx.y * 64, n0 = blockIdx.x * 64;
    if (m0 >= M) return;
    __shared__ u16 As[2][64][136];
    __shared__ u16 Bs[2][64][136];
    const u16* Bb = d.Bt[z];
    const float* bias = d.bias[z];
    int t = threadIdx.x;
    int wave = t >> 6, lane = t & 63;
    int wr = wave >> 1, wc = wave & 1;
    f4 acc[2][2];
    #pragma unroll
    for (int m = 0; m < 2; ++m)
        #pragma unroll
        for (int n = 0; n < 2; ++n)
            #pragma unroll
            for (int r = 0; r < 4; ++r) acc[m][n][r] = 0.f;
    int nk = (K + 127) >> 7;
    s8 pa[4], pbv[4];
    if (z < 3) load_tile(d.A[z], K, M, K, m0, 0, t, pa);
    else       load_tile_f32(txtf, K, M, K, m0, 0, t, pa);
    load_tile(Bb, K, 768, K, n0, 0, t, pbv);
    write_tile(As[0], t, pa);
    write_tile(Bs[0], t, pbv);
    __syncthreads();
    for (int kt = 0; kt < nk; ++kt) {
        int cur = kt & 1;
        if (kt + 1 < nk) {
            if (z < 3) load_tile(d.A[z], K, M, K, m0, (kt+1) << 7, t, pa);
            else       load_tile_f32(txtf, K, M, K, m0, (kt+1) << 7, t, pa);
            load_tile(Bb, K, 768, K, n0, (kt+1) << 7, t, pbv);
        }
        mfma_tile(As[cur], Bs[cur], wr, wc, lane, acc);
        if (kt + 1 < nk) {
            write_tile(As[cur^1], t, pa);
            write_tile(Bs[cur^1], t, pbv);
        }
        __syncthreads();
    }
    #pragma unroll
    for (int m = 0; m < 2; ++m) {
        int rbase = m0 + wr*32 + m*16 + (lane >> 4) * 4;
        #pragma unroll
        for (int n = 0; n < 2; ++n) {
            int col = n0 + wc*32 + n*16 + (lane & 15);
            #pragma unroll
            for (int r = 0; r < 4; ++r) {
                int row = rbase + r;
                if (row >= M) continue;
                float v = acc[m][n][r] + bias[col];
                if (z < 3) {
                    v += d.pos[z][(long)(row & 255)*768 + col];
                    C[((long)z*512 + row) * 768 + col] = v;
                } else {
                    QHb[(long)row * 768 + col] = f2bf(v);
                }
            }
        }
    }
}

// ============ output-proj GEMM + fused unpatchify ============
struct OwDesc {
    const u16* Bt[3];
    float* plane[3];
    const float* bias[3];
    int N[3];
    int p2[3];
    int Wd[3];
};

__global__ __launch_bounds__(256) void gemm_ow(OwDesc d, const u16* __restrict__ A,
                                               const float* __restrict__ vwp) {
    int z = blockIdx.z;
    int N = d.N[z];
    int n0 = blockIdx.x * 64;
    if (n0 >= N) return;
    __shared__ u16 As[2][64][136];
    __shared__ u16 Bs[2][64][136];
    const u16* Ab = A + (long)z * 512 * 768;
    const u16* Bb = d.Bt[z];
    int t = threadIdx.x;
    int m0 = blockIdx.y * 64;
    int wave = t >> 6, lane = t & 63;
    int wr = wave >> 1, wc = wave & 1;
    f4 acc[2][2];
    #pragma unroll
    for (int m = 0; m < 2; ++m)
        #pragma unroll
        for (int n = 0; n < 2; ++n)
            #pragma unroll
            for (int r = 0; r < 4; ++r) acc[m][n][r] = 0.f;
    s8 pa[4], pbv[4];
    load_tile(Ab, 768, 512, 768, m0, 0, t, pa);
    load_tile(Bb, 768, N, 768, n0, 0, t, pbv);
    write_tile(As[0], t, pa);
    write_tile(Bs[0], t, pbv);
    __syncthreads();
    for (int kt = 0; kt < 6; ++kt) {
        int cur = kt & 1;
        if (kt + 1 < 6) {
            load_tile(Ab, 768, 512, 768, m0, (kt+1) << 7, t, pa);
            load_tile(Bb, 768, N, 768, n0, (kt+1) << 7, t, pbv);
        }
        mfma_tile(As[cur], Bs[cur], wr, wc, lane, acc);
        if (kt + 1 < 6) {
            write_tile(As[cur^1], t, pa);
            write_tile(Bs[cur^1], t, pbv);
        }
        __syncthreads();
    }
    float* plane = d.plane[z];
    const float* bias = d.bias[z];
    int p2 = d.p2[z], Wd = d.Wd[z];
    float wt = vwp[z];
    #pragma unroll
    for (int m = 0; m < 2; ++m) {
        int rbase = m0 + wr*32 + m*16 + (lane >> 4) * 4;
        #pragma unroll
        for (int n = 0; n < 2; ++n) {
            int col = n0 + wc*32 + n*16 + (lane & 15);
            if (col >= N) continue;
            int pp = col >> 5, c = col & 31;
            int pp1 = pp / p2, pp2 = pp % p2;
            float bv = bias[col];
            #pragma unroll
            for (int r = 0; r < 4; ++r) {
                int row = rbase + r;
                int b = row >> 8, nn = row & 255;
                int hh = nn >> 4, ww = nn & 15;
                plane[((long)(b*32 + c)*112 + hh*7 + pp1)*Wd + ww*p2 + pp2]
                    = wt * (acc[m][n][r] + bv);
            }
        }
    }
}

// ============ LayerNorm rows of 768 ============
__global__ __launch_bounds__(256) void ln_k(const float* __restrict__ in,
                                            float* __restrict__ outf,
                                            u16* __restrict__ outb,
                                            const float* __restrict__ g,
                                            const float* __restrict__ bta) {
    constexpr int N = 768;
    int row = blockIdx.x;
    const float* x = in + (size_t)row * N;
    int t = threadIdx.x;
    float v0 = x[t], v1 = x[t+256], v2 = x[t+512];
    float s = v0+v1+v2, s2 = v0*v0+v1*v1+v2*v2;
    #pragma unroll
    for (int off = 32; off > 0; off >>= 1) { s += __shfl_down(s, off); s2 += __shfl_down(s2, off); }
    __shared__ float red[8];
    int wid = t >> 6, lane = t & 63;
    if (lane == 0) { red[wid] = s; red[wid+4] = s2; }
    __syncthreads();
    if (t == 0) {
        float S = red[0]+red[1]+red[2]+red[3];
        float S2 = red[4]+red[5]+red[6]+red[7];
        float mean = S * (1.f/N);
        float var = S2 * (1.f/N) - mean*mean;
        red[0] = mean; red[1] = rsqrtf(var + 1e-5f);
    }
    __syncthreads();
    float mean = red[0], rstd = red[1];
    float y0 = (v0-mean)*rstd*g[t]     + bta[t];
    float y1 = (v1-mean)*rstd*g[t+256] + bta[t+256];
    float y2 = (v2-mean)*rstd*g[t+512] + bta[t+512];
    if (outf) {
        float* y = outf + (size_t)row * N;
        y[t] = y0; y[t+256] = y1; y[t+512] = y2;
    }
    if (outb) {
        u16* y = outb + (size_t)row * N;
        y[t] = f2bf(y0); y[t+256] = f2bf(y1); y[t+512] = f2bf(y2);
    }
}

// ============ fully fused self-attention ============
__global__ __launch_bounds__(256) void attn_k(const u16* __restrict__ QKV,
                                              const u16* __restrict__ Vt,
                                              u16* __restrict__ O) {
    __shared__ u16 Ks[256][72];
    __shared__ u16 Ps[128][264];
    __shared__ u16 Vs[64][264];
    int zz = blockIdx.x;
    int bh = zz >> 1, half = zz & 1;
    int bb = bh / 12, h = bh % 12;
    long qrow0 = (long)bb*256 + half*128;
    int hcol = h*64;
    int t = threadIdx.x;
    int wave = t >> 6, lane = t & 63;
    int lr = lane & 15, lg = lane >> 4;
    #pragma unroll
    for (int i = 0; i < 8; ++i) {
        int chunk = t + i*256;
        int row = chunk >> 3, c8 = (chunk & 7)*8;
        *reinterpret_cast<s8*>(&Ks[row][c8]) =
            *reinterpret_cast<const s8*>(QKV + ((long)bb*256 + row)*2304 + 768 + hcol + c8);
    }
    #pragma unroll
    for (int i = 0; i < 8; ++i) {
        int chunk = t + i*256;
        int d = chunk >> 5, j8 = (chunk & 31)*8;
        *reinterpret_cast<s8*>(&Vs[d][j8]) =
            *reinterpret_cast<const s8*>(Vt + (long)bh*16384 + (long)d*256 + j8);
    }
    __syncthreads();
    f4 acc[2][16];
    #pragma unroll
    for (int m = 0; m < 2; ++m)
        #pragma unroll
        for (int n = 0; n < 16; ++n)
            #pragma unroll
            for (int r = 0; r < 4; ++r) acc[m][n][r] = 0.f;
    #pragma unroll
    for (int kh = 0; kh < 2; ++kh) {
        s8 af0 = *reinterpret_cast<const s8*>(QKV + (qrow0 + wave*32 + lr)*2304 + hcol + kh*32 + lg*8);
        s8 af1 = *reinterpret_cast<const s8*>(QKV + (qrow0 + wave*32 + 16 + lr)*2304 + hcol + kh*32 + lg*8);
        #pragma unroll
        for (int n = 0; n < 16; ++n) {
            s8 bf = *reinterpret_cast<const s8*>(&Ks[n*16 + lr][kh*32 + lg*8]);
            acc[0][n] = MFMA16(af0, bf, acc[0][n]);
            acc[1][n] = MFMA16(af1, bf, acc[1][n]);
        }
    }
    #pragma unroll
    for (int m = 0; m < 2; ++m)
        #pragma unroll
        for (int r = 0; r < 4; ++r) {
            float mx = -1e30f;
            #pragma unroll
            for (int n = 0; n < 16; ++n) mx = fmaxf(mx, acc[m][n][r]);
            #pragma unroll
            for (int o = 8; o; o >>= 1) mx = fmaxf(mx, __shfl_xor(mx, o));
            float l = 0.f;
            float p[16];
            #pragma unroll
            for (int n = 0; n < 16; ++n) {
                p[n] = __expf((acc[m][n][r] - mx) * 0.125f);
                l += p[n];
            }
            #pragma unroll
            for (int o = 8; o; o >>= 1) l += __shfl_xor(l, o);
            float inv = 1.f / l;
            int prow = wave*32 + m*16 + lg*4 + r;
            #pragma unroll
            for (int n = 0; n < 16; ++n)
                Ps[prow][n*16 + lr] = f2bf(p[n] * inv);
        }
    __syncthreads();
    f4 o2[2][4];
    #pragma unroll
    for (int m = 0; m < 2; ++m)
        #pragma unroll
        for (int n = 0; n < 4; ++n)
            #pragma unroll
            for (int r = 0; r < 4; ++r) o2[m][n][r] = 0.f;
    #pragma unroll
    for (int kh = 0; kh < 8; ++kh) {
        s8 pf0 = *reinterpret_cast<const s8*>(&Ps[wave*32 + lr][kh*32 + lg*8]);
        s8 pf1 = *reinterpret_cast<const s8*>(&Ps[wave*32 + 16 + lr][kh*32 + lg*8]);
        #pragma unroll
        for (int n = 0; n < 4; ++n) {
            s8 vf = *reinterpret_cast<const s8*>(&Vs[n*16 + lr][kh*32 + lg*8]);
            o2[0][n] = MFMA16(pf0, vf, o2[0][n]);
            o2[1][n] = MFMA16(pf1, vf, o2[1][n]);
        }
    }
    #pragma unroll
    for (int m = 0; m < 2; ++m)
        #pragma unroll
        for (int n = 0; n < 4; ++n)
            #pragma unroll
            for (int r = 0; r < 4; ++r)
                O[(qrow0 + wave*32 + m*16 + lg*4 + r)*768 + hcol + n*16 + lr] = f2bf(o2[m][n][r]);
}

// ============ fully fused cross-attention ============
__global__ __launch_bounds__(256) void ca_fused(const u16* __restrict__ QHb,
                                                const u16* __restrict__ KVHb,
                                                u16* __restrict__ O) {
    __shared__ u16 QHs[80][72];
    __shared__ u16 KHs[256][72];
    __shared__ float rmax[80][4];
    __shared__ float rsum[80][4];
    __shared__ float Wj[256];
    int bh = blockIdx.x;
    int rowblk = bh / 12, h = bh % 12;
    int bsel = rowblk & 1;
    int t = threadIdx.x;
    int wave = t >> 6, lane = t & 63;
    int lr = lane & 15, lg = lane >> 4;
    #pragma unroll
    for (int i = 0; i < 3; ++i) {
        int chunk = t + i*256;
        if (chunk < 640) {
            int row = chunk >> 3, c8 = (chunk & 7)*8;
            s8 v;
            #pragma unroll
            for (int q = 0; q < 8; ++q) v[q] = 0;
            if (row < 77)
                v = *reinterpret_cast<const s8*>(QHb + ((long)(bsel*77 + row))*768 + h*64 + c8);
            *reinterpret_cast<s8*>(&QHs[row][c8]) = v;
        }
    }
    #pragma unroll
    for (int i = 0; i < 8; ++i) {
        int chunk = t + i*256;
        int row = chunk >> 3, c8 = (chunk & 7)*8;
        *reinterpret_cast<s8*>(&KHs[row][c8]) =
            *reinterpret_cast<const s8*>(KVHb + ((long)rowblk*256 + row)*1536 + h*64 + c8);
    }
    __syncthreads();
    f4 acc[5][4];
    #pragma unroll
    for (int m = 0; m < 5; ++m)
        #pragma unroll
        for (int n = 0; n < 4; ++n)
            #pragma unroll
            for (int r = 0; r < 4; ++r) acc[m][n][r] = 0.f;
    #pragma unroll
    for (int kh = 0; kh < 2; ++kh) {
        s8 af[5], bf[4];
        #pragma unroll
        for (int m = 0; m < 5; ++m)
            af[m] = *reinterpret_cast<const s8*>(&QHs[m*16 + lr][kh*32 + lg*8]);
        #pragma unroll
        for (int n = 0; n < 4; ++n)
            bf[n] = *reinterpret_cast<const s8*>(&KHs[wave*64 + n*16 + lr][kh*32 + lg*8]);
        #pragma unroll
        for (int m = 0; m < 5; ++m)
            #pragma unroll
            for (int n = 0; n < 4; ++n)
                acc[m][n] = MFMA16(af[m], bf[n], acc[m][n]);
    }
    #pragma unroll
    for (int m = 0; m < 5; ++m)
        #pragma unroll
        for (int r = 0; r < 4; ++r) {
            float mx = -1e30f;
            #pragma unroll
            for (int n = 0; n < 4; ++n) mx = fmaxf(mx, acc[m][n][r]);
            #pragma unroll
            for (int o = 8; o; o >>= 1) mx = fmaxf(mx, __shfl_xor(mx, o));
            if (lr == 0) rmax[m*16 + lg*4 + r][wave] = mx;
        }
    __syncthreads();
    #pragma unroll
    for (int m = 0; m < 5; ++m)
        #pragma unroll
        for (int r = 0; r < 4; ++r) {
            int i = m*16 + lg*4 + r;
            float mi = fmaxf(fmaxf(rmax[i][0], rmax[i][1]), fmaxf(rmax[i][2], rmax[i][3]));
            float s = 0.f;
            #pragma unroll
            for (int n = 0; n < 4; ++n) s += __expf((acc[m][n][r] - mi) * 0.125f);
            #pragma unroll
            for (int o = 8; o; o >>= 1) s += __shfl_xor(s, o);
            if (lr == 0) rsum[i][wave] = s;
        }
    __syncthreads();
    float wn[4] = {0.f, 0.f, 0.f, 0.f};
    #pragma unroll
    for (int m = 0; m < 5; ++m)
        #pragma unroll
        for (int r = 0; r < 4; ++r) {
            int i = m*16 + lg*4 + r;
            if (i < 77) {
                float mi = fmaxf(fmaxf(rmax[i][0], rmax[i][1]), fmaxf(rmax[i][2], rmax[i][3]));
                float li = rsum[i][0] + rsum[i][1] + rsum[i][2] + rsum[i][3];
                float inv = 1.f / li;
                #pragma unroll
                for (int n = 0; n < 4; ++n)
                    wn[n] += __expf((acc[m][n][r] - mi) * 0.125f) * inv;
            }
        }
    #pragma unroll
    for (int n = 0; n < 4; ++n) {
        wn[n] += __shfl_xor(wn[n], 16);
        wn[n] += __shfl_xor(wn[n], 32);
    }
    if (lane < 16) {
        #pragma unroll
        for (int n = 0; n < 4; ++n) Wj[wave*64 + n*16 + lr] = wn[n];
    }
    __syncthreads();
    int d = t & 63;
    #pragma unroll 4
    for (int it = 0; it < 64; ++it) {
        int j = it*4 + (t >> 6);
        long row = (long)rowblk*256 + j;
        float vh = bf2f(KVHb[row*1536 + 768 + h*64 + d]);
        O[row*768 + h*64 + d] = f2bf(Wj[j] * vh);
    }
}

// ============ streaming final combine (non-temporal img/out) ============
__global__ __launch_bounds__(256) void final_k(const float* __restrict__ img,
                                               const float* __restrict__ Aax,
                                               const float* __restrict__ Asag,
                                               const float* __restrict__ Acor,
                                               float* __restrict__ out) {
    int blk = blockIdx.x;                 // bc*112 + d
    int bc = blk / 112;
    const f4* ip = reinterpret_cast<const f4*>(img + (size_t)blk * 8960);
    const f4* ap = reinterpret_cast<const f4*>(Aax + (size_t)bc * 8960);
    const f4* sp = reinterpret_cast<const f4*>(Asag + (size_t)blk * 80);
    const float* cp = Acor + (size_t)blk * 112;
    f4* op = reinterpret_cast<f4*>(out + (size_t)blk * 8960);
    int t = threadIdx.x;
    #pragma unroll
    for (int k = 0; k < 9; ++k) {
        int q = t + k * 256;
        if (q < 2240) {
            f4 iv = __builtin_nontemporal_load(&ip[q]);
            int h = q / 20, w4 = q % 20;
            float cv = cp[h];
            f4 r = iv + ap[q] + sp[w4] + (f4){cv, cv, cv, cv};
            __builtin_nontemporal_store(r, &op[q]);
        }
    }
}

extern "C" void kernel_launch(void* const* d_in, const int* in_sizes, int n_in,
                              void* d_out, int out_size, void* d_ws, size_t ws_size,
                              hipStream_t stream) {
    (void)in_sizes; (void)n_in; (void)out_size; (void)ws_size;
    const float* img    = (const float*)d_in[0];
    const float* txt    = (const float*)d_in[1];
    const float* pe_w[3] = {(const float*)d_in[2], (const float*)d_in[4], (const float*)d_in[6]};
    const float* pe_b[3] = {(const float*)d_in[3], (const float*)d_in[5], (const float*)d_in[7]};
    const float* pos[3]  = {(const float*)d_in[8], (const float*)d_in[9], (const float*)d_in[10]};
    const float* qw = (const float*)d_in[11];
    const float* kw = (const float*)d_in[12];
    const float* vw_attn = (const float*)d_in[13];
    const float* pw = (const float*)d_in[14];
    const float* pb = (const float*)d_in[15];
    const float* caq_w = (const float*)d_in[16];
    const float* caq_b = (const float*)d_in[17];
    const float* cak_w = (const float*)d_in[18];
    const float* cak_b = (const float*)d_in[19];
    const float* cav_w = (const float*)d_in[20];
    const float* cav_b = (const float*)d_in[21];
    const float* cao_w = (const float*)d_in[22];
    const float* cao_b = (const float*)d_in[23];
    const float* mlp_w1 = (const float*)d_in[24];
    const float* mlp_b1 = (const float*)d_in[25];
    const float* mlp_w2 = (const float*)d_in[26];
    const float* mlp_b2 = (const float*)d_in[27];
    const float* ow[3] = {(const float*)d_in[28], (const float*)d_in[30], (const float*)d_in[32]};
    const float* ob[3] = {(const float*)d_in[29], (const float*)d_in[31], (const float*)d_in[33]};
    const float* view_w = (const float*)d_in[34];
    const float* n_g[3] = {(const float*)d_in[35], (const float*)d_in[36], (const float*)d_in[37]};
    const float* n_b[3] = {(const float*)d_in[38], (const float*)d_in[39], (const float*)d_in[40]};

    typedef unsigned short u16t;
    unsigned char* sb = (unsigned char*)d_out;
    size_t off = 0;
    auto B = [&](size_t bytes) -> void* {
        void* p = sb + off; off += (bytes + 511) & ~(size_t)511; return p;
    };
    u16t* qkvT  = (u16t*)B((size_t)2304*768*2);
    u16t* pwT   = (u16t*)B(768*768*2);
    u16t* caqT  = (u16t*)B(768*768*2);
    u16t* cakvT = (u16t*)B((size_t)1536*768*2);
    u16t* caoT  = (u16t*)B(768*768*2);
    u16t* mlp1T = (u16t*)B((size_t)3072*768*2);
    u16t* mlp2T = (u16t*)B((size_t)768*3072*2);
    u16t* peT[3]; peT[0] = (u16t*)B((size_t)768*1120*2); peT[1] = (u16t*)B((size_t)768*1120*2); peT[2] = (u16t*)B((size_t)768*1568*2);
    u16t* owT[3]; owT[0] = (u16t*)B((size_t)1120*768*2); owT[1] = (u16t*)B((size_t)1120*768*2); owT[2] = (u16t*)B((size_t)1568*768*2);
    float* axp   = (float*)B((size_t)16*573440*4);
    float* m_sag = (float*)B(573440*4);
    float* m_cor = (float*)B(802816*4);
    u16t* P0 = (u16t*)B((size_t)512*1120*2);
    u16t* P1 = (u16t*)B((size_t)512*1120*2);
    u16t* P2 = (u16t*)B((size_t)512*1568*2);
    float* X0  = (float*)B((size_t)1536*768*4);
    float* X1f = (float*)B((size_t)1536*768*4);
    float* X2  = (float*)B((size_t)1536*768*4);
    float* X3f = (float*)B((size_t)1536*768*4);
    float* X4  = (float*)B((size_t)1536*768*4);
    u16t* X1b = (u16t*)B((size_t)1536*768*2);
    u16t* X3b = (u16t*)B((size_t)1536*768*2);
    u16t* X5b = (u16t*)B((size_t)1536*768*2);
    u16t* X6b = (u16t*)B((size_t)1536*768*2);
    u16t* QKVb = (u16t*)B((size_t)1536*2304*2);
    u16t* Obf = (u16t*)B((size_t)1536*768*2);
    u16t* Vt  = (u16t*)B((size_t)72*64*256*2);
    u16t* Hb  = (u16t*)B((size_t)1536*3072*2);
    u16t* KVHb = (u16t*)B((size_t)1536*1536*2);
    u16t* QHb  = (u16t*)B((size_t)154*768*2);

    float* ws = (float*)d_ws;
    float* Aax  = ws;
    float* Asag = ws + 573440;
    float* Acor = ws + 1146880;

    // ---- prep: transposes + means (1 launch) ----
    TT tab;
    {
        const float* ins[16] = {qw, kw, vw_attn, pw, caq_w, cak_w, cav_w, cao_w,
                                mlp_w1, mlp_w2, pe_w[0], pe_w[1], pe_w[2], ow[0], ow[1], ow[2]};
        u16t* outs[16] = {qkvT, qkvT + 768*768, qkvT + 2*768*768, pwT, caqT, cakvT,
                          cakvT + 768*768, caoT, mlp1T, mlp2T, peT[0], peT[1], peT[2],
                          owT[0], owT[1], owT[2]};
        int Ks[16] = {768,768,768,768,768,768,768,768, 768,3072, 1120,1120,1568, 768,768,768};
        int Ns[16] = {768,768,768,768,768,768,768,768, 3072,768, 768,768,768, 1120,1120,1568};
        int st = 0;
        for (int i = 0; i < 16; ++i) {
            tab.in[i] = ins[i]; tab.out[i] = outs[i]; tab.K[i] = Ks[i]; tab.N[i] = Ns[i];
            tab.start[i] = st;
            st += (Ks[i] >> 5) * (Ns[i] >> 5);
        }
        tab.total = st;
        prep_k<<<1024 + st, 256, 0, stream>>>(tab, img, axp, m_sag, m_cor);
    }

    patchify3_k<<<dim3(224,3), 256, 0, stream>>>(axp, m_sag, m_cor, P0, P1, P2);

    auto gemm = [&](const u16t* A, const u16t* Bt, float* Cf, u16t* Cb,
                    int M, int N, int K, const float* bias, const float* bias2,
                    const float* resid, int act, u16t* vt) {
        dim3 g(N/64, M/64, 1);
        gemm_gl<<<g, 256, 0, stream>>>(A, Bt, Cf, Cb, M, N, K, bias, bias2, resid, act, vt);
    };

    // pe (z<3) + QH projection (z=3), one launch
    {
        PeDesc d;
        d.A[0] = P0; d.A[1] = P1; d.A[2] = P2;
        d.Bt[0] = peT[0]; d.Bt[1] = peT[1]; d.Bt[2] = peT[2]; d.Bt[3] = caqT;
        d.bias[0] = pe_b[0]; d.bias[1] = pe_b[1]; d.bias[2] = pe_b[2]; d.bias[3] = caq_b;
        d.pos[0] = pos[0]; d.pos[1] = pos[1]; d.pos[2] = pos[2];
        d.K[0] = 1120; d.K[1] = 1120; d.K[2] = 1568; d.K[3] = 768;
        d.M[0] = 512; d.M[1] = 512; d.M[2] = 512; d.M[3] = 154;
        gemm_pe<<<dim3(12,8,4), 256, 0, stream>>>(d, txt, X0, QHb);
    }

    ln_k<<<1536, 256, 0, stream>>>(X0, X1f, X1b, n_g[0], n_b[0]);
    gemm(X1b, qkvT, nullptr, QKVb, 1536, 2304, 768, nullptr, nullptr, nullptr, 0, Vt);
    attn_k<<<144, 256, 0, stream>>>(QKVb, Vt, Obf);
    gemm(Obf, pwT, X2, nullptr, 1536, 768, 768, pb, nullptr, X1f, 0, nullptr);
    ln_k<<<1536, 256, 0, stream>>>(X2, X3f, X3b, n_g[1], n_b[1]);
    gemm(X3b, cakvT, nullptr, KVHb, 1536, 1536, 768, cak_b, cav_b, nullptr, 0, nullptr);
    ca_fused<<<72, 256, 0, stream>>>(QHb, KVHb, Obf);
    gemm(Obf, caoT, X4, nullptr, 1536, 768, 768, cao_b, nullptr, X3f, 0, nullptr);
    ln_k<<<1536, 256, 0, stream>>>(X4, nullptr, X5b, n_g[2], n_b[2]);
    gemm(X5b, mlp1T, nullptr, Hb, 1536, 3072, 768, mlp_b1, nullptr, nullptr, 1, nullptr);
    gemm(Hb, mlp2T, nullptr, X6b, 1536, 768, 3072, mlp_b2, nullptr, X4, 0, nullptr);
    {
        OwDesc d;
        d.Bt[0] = owT[0]; d.Bt[1] = owT[1]; d.Bt[2] = owT[2];
        d.plane[0] = Aax; d.plane[1] = Asag; d.plane[2] = Acor;
        d.bias[0] = ob[0]; d.bias[1] = ob[1]; d.bias[2] = ob[2];
        d.N[0] = 1120; d.N[1] = 1120; d.N[2] = 1568;
        d.p2[0] = 5; d.p2[1] = 5; d.p2[2] = 7;
        d.Wd[0] = 80; d.Wd[1] = 80; d.Wd[2] = 112;
        gemm_ow<<<dim3(25,8,3), 256, 0, stream>>>(d, X6b, view_w);
    }

    final_k<<<7168, 256, 0, stream>>>(img, Aax, Asag, Acor, (float*)d_out);
}

// Round 16
// 405.163 us; speedup vs baseline: 2.1845x; 1.0013x over previous
//
#include <hip/hip_runtime.h>
#include <math.h>

typedef __attribute__((ext_vector_type(8))) short s8;
typedef __attribute__((ext_vector_type(4))) float f4;
typedef unsigned short u16;

__device__ inline u16 f2bf(float f) {
    unsigned u = __float_as_uint(f);
    u += 0x7fffu + ((u >> 16) & 1u);
    return (u16)(u >> 16);
}
__device__ inline float bf2f(u16 x) {
    return __uint_as_float(((unsigned)x) << 16);
}
#define MFMA16(a, b, c) __builtin_amdgcn_mfma_f32_16x16x32_bf16(a, b, c, 0, 0, 0)

// ============ prep: weight transposes + axis means (1 launch) ============
struct TT {
    const float* in[16];
    u16* out[16];
    int K[16];
    int N[16];
    int start[16];
    int total;
};

__global__ __launch_bounds__(256) void prep_k(TT tab, const float* __restrict__ img,
                                              float* __restrict__ axp,
                                              float* __restrict__ sag,
                                              float* __restrict__ cor) {
    __shared__ float sl[112*81];
    int bid = blockIdx.x;
    int t = threadIdx.x;
    if (bid < 1024) {
        int dc = bid & 15, bc = bid >> 4;
        int d0 = dc * 7;
        f4 axr[9];
        #pragma unroll
        for (int k = 0; k < 9; ++k) axr[k] = (f4){0.f,0.f,0.f,0.f};
        const float* base = img + (size_t)bc * 1003520 + (size_t)d0 * 8960;
        for (int sidx = 0; sidx < 7; ++sidx) {
            const f4* sp = reinterpret_cast<const f4*>(base + (size_t)sidx * 8960);
            #pragma unroll
            for (int k = 0; k < 9; ++k) {
                int q = t + k * 256;
                if (q < 2240) {
                    f4 v = __builtin_nontemporal_load(&sp[q]);
                    axr[k] += v;
                    int h = q / 20, w4 = q % 20;
                    float* row = &sl[h * 81 + w4 * 4];
                    row[0] = v[0]; row[1] = v[1]; row[2] = v[2]; row[3] = v[3];
                }
            }
            __syncthreads();
            if (t < 112) {
                float acc = 0.f;
                #pragma unroll 8
                for (int w = 0; w < 80; ++w) acc += sl[t * 81 + w];
                cor[((size_t)bc * 112 + d0 + sidx) * 112 + t] = acc * (1.f / 80.f);
            } else if (t < 192) {
                int w = t - 112;
                float acc = 0.f;
                #pragma unroll 8
                for (int h = 0; h < 112; ++h) acc += sl[h * 81 + w];
                sag[((size_t)bc * 112 + d0 + sidx) * 80 + w] = acc * (1.f / 112.f);
            }
            __syncthreads();
        }
        float* axo = axp + ((size_t)dc * 64 + bc) * 8960;
        #pragma unroll
        for (int k = 0; k < 9; ++k) {
            int q = t + k * 256;
            if (q < 2240) *reinterpret_cast<f4*>(axo + q * 4) = axr[k];
        }
        return;
    }
    int tb = bid - 1024;
    float (*tl)[33] = reinterpret_cast<float(*)[33]>(sl);
    int e = 0;
    #pragma unroll
    for (int i = 1; i < 16; ++i) if (tb >= tab.start[i]) e = i;
    const float* in = tab.in[e];
    u16* out = tab.out[e];
    int K = tab.K[e], N = tab.N[e];
    int tid = tb - tab.start[e];
    int nt = N >> 5;
    int k0 = (tid / nt) * 32, n0 = (tid % nt) * 32;
    int r = t >> 5, c = t & 31;
    #pragma unroll
    for (int i = 0; i < 4; ++i) tl[r + i*8][c] = in[(long)(k0 + r + i*8)*N + n0 + c];
    __syncthreads();
    #pragma unroll
    for (int i = 0; i < 4; ++i) out[(long)(n0 + r + i*8)*K + k0 + c] = f2bf(tl[c][r + i*8]);
}

// ============ patchify, 3 branches; br0 sums ax partials ============
__global__ __launch_bounds__(256) void patchify3_k(const float* __restrict__ axp,
                                                   const float* __restrict__ m_sag,
                                                   const float* __restrict__ m_cor,
                                                   u16* __restrict__ P0, u16* __restrict__ P1,
                                                   u16* __restrict__ P2) {
    __shared__ float sl[32][113];
    int br = blockIdx.y;
    int X = blockIdx.x;
    int b = X / 112, rem = X % 112;
    int hh = rem / 7, pp1 = rem % 7;
    const float* src; u16* dst; int Wt, p2, PD;
    if (br == 0)      { src = nullptr; dst = P0; Wt = 80;  p2 = 5; PD = 1120; }
    else if (br == 1) { src = m_sag;   dst = P1; Wt = 80;  p2 = 5; PD = 1120; }
    else              { src = m_cor;   dst = P2; Wt = 112; p2 = 7; PD = 1568; }
    int t = threadIdx.x;
    int row = hh*7 + pp1;
    int wq = Wt >> 2;
    if (br == 0) {
        for (int i = t; i < 32*20; i += 256) {
            int c = i / 20, w4 = i % 20;
            f4 s = (f4){0.f,0.f,0.f,0.f};
            size_t base = ((size_t)(b*32 + c)*112 + row)*80 + w4*4;
            #pragma unroll
            for (int p = 0; p < 16; ++p)
                s += *reinterpret_cast<const f4*>(axp + (size_t)p*573440 + base);
            s *= (1.f/112.f);
            sl[c][w4*4+0] = s[0]; sl[c][w4*4+1] = s[1]; sl[c][w4*4+2] = s[2]; sl[c][w4*4+3] = s[3];
        }
    } else {
        for (int i = t; i < 32*wq; i += 256) {
            int c = i / wq, w4 = i % wq;
            float4 v = *reinterpret_cast<const float4*>(
                src + ((size_t)(b*32 + c)*112 + row)*Wt + w4*4);
            sl[c][w4*4+0] = v.x; sl[c][w4*4+1] = v.y; sl[c][w4*4+2] = v.z; sl[c][w4*4+3] = v.w;
        }
    }
    __syncthreads();
    int tot = 16 * p2 * 32;
    for (int o = t; o < tot; o += 256) {
        int ww = o / (p2*32), rest = o % (p2*32);
        int pp2 = rest >> 5, c = rest & 31;
        dst[((size_t)(b*256 + hh*16 + ww))*PD + (pp1*p2 + pp2)*32 + c]
            = f2bf(sl[c][ww*p2 + pp2]);
    }
}

// ============ legacy GEMM building blocks (64-tile, reg-staged, padded LDS) ============
__device__ inline void load_tile(const u16* __restrict__ P, int ld, int nrows, int K,
                                 int r0, int k0, int t, s8 v[4]) {
    #pragma unroll
    for (int i = 0; i < 4; ++i) {
        int chunk = t + i*256;
        int row = chunk >> 4, c8 = (chunk & 15) * 8;
        s8 x;
        #pragma unroll
        for (int q = 0; q < 8; ++q) x[q] = 0;
        if (r0 + row < nrows && k0 + c8 < K)
            x = *reinterpret_cast<const s8*>(P + (long)(r0 + row)*ld + k0 + c8);
        v[i] = x;
    }
}
__device__ inline void load_tile_f32(const float* __restrict__ P, int ld, int nrows, int K,
                                     int r0, int k0, int t, s8 v[4]) {
    #pragma unroll
    for (int i = 0; i < 4; ++i) {
        int chunk = t + i*256;
        int row = chunk >> 4, c8 = (chunk & 15) * 8;
        s8 x;
        #pragma unroll
        for (int q = 0; q < 8; ++q) x[q] = 0;
        if (r0 + row < nrows && k0 + c8 < K) {
            const float* src = P + (long)(r0 + row)*ld + k0 + c8;
            #pragma unroll
            for (int q = 0; q < 8; ++q) x[q] = (short)f2bf(src[q]);
        }
        v[i] = x;
    }
}
__device__ inline void write_tile(u16 (*S)[136], int t, const s8 v[4]) {
    #pragma unroll
    for (int i = 0; i < 4; ++i) {
        int chunk = t + i*256;
        *reinterpret_cast<s8*>(&S[chunk >> 4][(chunk & 15)*8]) = v[i];
    }
}
__device__ inline void mfma_tile(const u16 (*As)[136], const u16 (*Bs)[136],
                                 int wr, int wc, int lane, f4 acc[2][2]) {
    int lrow = lane & 15;
    #pragma unroll
    for (int kh = 0; kh < 4; ++kh) {
        int lk = kh*32 + (lane >> 4) * 8;
        s8 af0 = *reinterpret_cast<const s8*>(&As[wr*32 + lrow][lk]);
        s8 af1 = *reinterpret_cast<const s8*>(&As[wr*32 + 16 + lrow][lk]);
        s8 bg0 = *reinterpret_cast<const s8*>(&Bs[wc*32 + lrow][lk]);
        s8 bg1 = *reinterpret_cast<const s8*>(&Bs[wc*32 + 16 + lrow][lk]);
        acc[0][0] = MFMA16(af0, bg0, acc[0][0]);
        acc[0][1] = MFMA16(af0, bg1, acc[0][1]);
        acc[1][0] = MFMA16(af1, bg0, acc[1][0]);
        acc[1][1] = MFMA16(af1, bg1, acc[1][1]);
    }
}

// ============ gload_lds GEMM (64-tile, BK=128, dbuf, XOR-swizzled LDS) ============
// Requires M, N, K multiples of 64 and exact grid (no bounds checks).
__global__ __launch_bounds__(256) void gemm_gl(
    const u16* __restrict__ A, const u16* __restrict__ Bt,
    float* __restrict__ Cf, u16* __restrict__ Cb,
    int M, int N, int K,
    const float* __restrict__ bias, const float* __restrict__ bias2,
    const float* __restrict__ resid, int act, u16* __restrict__ vt)
{
    __shared__ u16 As[2][64*128];
    __shared__ u16 Bs[2][64*128];
    int t = threadIdx.x;
    int m0 = blockIdx.y * 64, n0 = blockIdx.x * 64;
    int wave = t >> 6, lane = t & 63;
    int wr = wave >> 1, wc = wave & 1;
    f4 acc[2][2];
    #pragma unroll
    for (int m = 0; m < 2; ++m)
        #pragma unroll
        for (int n = 0; n < 2; ++n)
            #pragma unroll
            for (int r = 0; r < 4; ++r) acc[m][n][r] = 0.f;
    int nk = K >> 7;
    auto stage = [&](int buf, int k0) {
        #pragma unroll
        for (int i = 0; i < 4; ++i) {
            int c = wave*256 + i*64 + lane;
            int row = c >> 4, jl = c & 15;
            int jg = jl ^ (row & 7);
            const u16* ga = A  + (long)(m0 + row)*K + k0 + jg*8;
            const u16* gb = Bt + (long)(n0 + row)*K + k0 + jg*8;
            u16* la = &As[buf][(wave*256 + i*64) * 8];
            u16* lb = &Bs[buf][(wave*256 + i*64) * 8];
            __builtin_amdgcn_global_load_lds((const unsigned int*)ga, (unsigned int*)la, 16, 0, 0);
            __builtin_amdgcn_global_load_lds((const unsigned int*)gb, (unsigned int*)lb, 16, 0, 0);
        }
    };
    stage(0, 0);
    __syncthreads();
    int lrow = lane & 15, lg = lane >> 4;
    int r0a = wr*32 + lrow, r1a = r0a + 16;
    int r0b = wc*32 + lrow, r1b = r0b + 16;
    int sa = r0a & 7, sbx = r0b & 7;
    for (int kt = 0; kt < nk; ++kt) {
        int cur = kt & 1;
        if (kt + 1 < nk) stage(cur ^ 1, (kt + 1) << 7);
        #pragma unroll
        for (int kh = 0; kh < 4; ++kh) {
            int j = kh*4 + lg;
            s8 af0 = *reinterpret_cast<const s8*>(&As[cur][r0a*128 + ((j ^ sa) << 3)]);
            s8 af1 = *reinterpret_cast<const s8*>(&As[cur][r1a*128 + ((j ^ sa) << 3)]);
            s8 bg0 = *reinterpret_cast<const s8*>(&Bs[cur][r0b*128 + ((j ^ sbx) << 3)]);
            s8 bg1 = *reinterpret_cast<const s8*>(&Bs[cur][r1b*128 + ((j ^ sbx) << 3)]);
            acc[0][0] = MFMA16(af0, bg0, acc[0][0]);
            acc[0][1] = MFMA16(af0, bg1, acc[0][1]);
            acc[1][0] = MFMA16(af1, bg0, acc[1][0]);
            acc[1][1] = MFMA16(af1, bg1, acc[1][1]);
        }
        __syncthreads();
    }
    #pragma unroll
    for (int m = 0; m < 2; ++m) {
        int rbase = m0 + wr*32 + m*16 + lg*4;
        #pragma unroll
        for (int n = 0; n < 2; ++n) {
            int col = n0 + wc*32 + n*16 + lrow;
            #pragma unroll
            for (int r = 0; r < 4; ++r) {
                int row = rbase + r;
                float v = acc[m][n][r];
                if (bias) {
                    float bb = bias2 ? ((col < 768) ? bias[col] : bias2[col - 768]) : bias[col];
                    v += bb;
                }
                if (resid) v += resid[(long)row * N + col];
                if (act == 1) v = 0.5f * v * (1.0f + erff(v * 0.70710678118654752f));
                long ci = (long)row * N + col;
                u16 b = f2bf(v);
                if (Cf) Cf[ci] = v;
                if (Cb) Cb[ci] = b;
                if (vt && col >= 1536) {
                    int z = (row >> 8) * 12 + ((col - 1536) >> 6);
                    vt[((long)z * 64 + (col & 63)) * 256 + (row & 255)] = b;
                }
            }
        }
    }
}

// ============ gload_lds GEMM (128x128 tile, BK=64, dbuf, XOR-swizzled LDS) ============
// Requires M, N multiples of 128, K multiple of 64; bf16 output only.
__global__ __launch_bounds__(256) void gemm_gl128(
    const u16* __restrict__ A, const u16* __restrict__ Bt,
    u16* __restrict__ Cb, u16* __restrict__ vt,
    int N, int K,
    const float* __restrict__ bias, const float* __restrict__ bias2, int act)
{
    __shared__ u16 As[2][128*64];
    __shared__ u16 Bs[2][128*64];
    int t = threadIdx.x;
    int m0 = blockIdx.y * 128, n0 = blockIdx.x * 128;
    int wave = t >> 6, lane = t & 63;
    int wr = wave >> 1, wc = wave & 1;
    int lrow = lane & 15, lg = lane >> 4;
    f4 acc[4][4];
    #pragma unroll
    for (int m = 0; m < 4; ++m)
        #pragma unroll
        for (int n = 0; n < 4; ++n)
            #pragma unroll
            for (int r = 0; r < 4; ++r) acc[m][n][r] = 0.f;
    int nk = K >> 6;
    // staging: 128 rows x 64 cols = 1024 16B-chunks (8 per row)
    auto stage = [&](int buf, int k0) {
        #pragma unroll
        for (int i = 0; i < 4; ++i) {
            int c = wave*256 + i*64 + lane;
            int row = c >> 3, jl = c & 7;
            int jg = jl ^ (row & 7);
            const u16* ga = A  + (long)(m0 + row)*K + k0 + jg*8;
            const u16* gb = Bt + (long)(n0 + row)*K + k0 + jg*8;
            u16* la = &As[buf][(wave*256 + i*64) * 8];
            u16* lb = &Bs[buf][(wave*256 + i*64) * 8];
            __builtin_amdgcn_global_load_lds((const unsigned int*)ga, (unsigned int*)la, 16, 0, 0);
            __builtin_amdgcn_global_load_lds((const unsigned int*)gb, (unsigned int*)lb, 16, 0, 0);
        }
    };
    stage(0, 0);
    __syncthreads();
    for (int kt = 0; kt < nk; ++kt) {
        int cur = kt & 1;
        if (kt + 1 < nk) stage(cur ^ 1, (kt + 1) << 6);
        #pragma unroll
        for (int kh = 0; kh < 2; ++kh) {
            int j = kh*4 + lg;              // logical chunk 0..7 within row
            s8 af[4], bf[4];
            #pragma unroll
            for (int m = 0; m < 4; ++m) {
                int ra = wr*64 + m*16 + lrow;
                af[m] = *reinterpret_cast<const s8*>(&As[cur][ra*64 + ((j ^ (ra & 7)) << 3)]);
            }
            #pragma unroll
            for (int n = 0; n < 4; ++n) {
                int rb = wc*64 + n*16 + lrow;
                bf[n] = *reinterpret_cast<const s8*>(&Bs[cur][rb*64 + ((j ^ (rb & 7)) << 3)]);
            }
            #pragma unroll
            for (int m = 0; m < 4; ++m)
                #pragma unroll
                for (int n = 0; n < 4; ++n)
                    acc[m][n] = MFMA16(af[m], bf[n], acc[m][n]);
        }
        __syncthreads();
    }
    #pragma unroll
    for (int m = 0; m < 4; ++m) {
        int rbase = m0 + wr*64 + m*16 + lg*4;
        #pragma unroll
        for (int n = 0; n < 4; ++n) {
            int col = n0 + wc*64 + n*16 + lrow;
            float bb = 0.f;
            if (bias) bb = bias2 ? ((col < 768) ? bias[col] : bias2[col - 768]) : bias[col];
            #pragma unroll
            for (int r = 0; r < 4; ++r) {
                int row = rbase + r;
                float v = acc[m][n][r] + bb;
                if (act == 1) v = 0.5f * v * (1.0f + erff(v * 0.70710678118654752f));
                u16 b = f2bf(v);
                Cb[(long)row * N + col] = b;
                if (vt && col >= 1536) {
                    int z = (row >> 8) * 12 + ((col - 1536) >> 6);
                    vt[((long)z * 64 + (col & 63)) * 256 + (row & 255)] = b;
                }
            }
        }
    }
}

// ============ batched patch-embed (+QH from fp32 txt) GEMM ============
struct PeDesc {
    const u16* A[3];
    const u16* Bt[4];
    const float* bias[4];
    const float* pos[3];
    int K[4];
    int M[4];
};

__global__ __launch_bounds__(256) void gemm_pe(PeDesc d, const float* __restrict__ txtf,
                                               float* __restrict__ C, u16* __restrict__ QHb) {
    int z = blockIdx.z;
    int M = d.M[z], K = d.K[z];
    int m0 = blockIdx.y * 64, n0 = blockIdx.x * 64;
    if (m0 >= M) return;
    __shared__ u16 As[2][64][136];
    __shared__ u16 Bs[2][64][136];
    const u16* Bb = d.Bt[z];
    const float* bias = d.bias[z];
    int t = threadIdx.x;
    int wave = t >> 6, lane = t & 63;
    int wr = wave >> 1, wc = wave & 1;
    f4 acc[2][2];
    #pragma unroll
    for (int m = 0; m < 2; ++m)
        #pragma unroll
        for (int n = 0; n < 2; ++n)
            #pragma unroll
            for (int r = 0; r < 4; ++r) acc[m][n][r] = 0.f;
    int nk = (K + 127) >> 7;
    s8 pa[4], pbv[4];
    if (z < 3) load_tile(d.A[z], K, M, K, m0, 0, t, pa);
    else       load_tile_f32(txtf, K, M, K, m0, 0, t, pa);
    load_tile(Bb, K, 768, K, n0, 0, t, pbv);
    write_tile(As[0], t, pa);
    write_tile(Bs[0], t, pbv);
    __syncthreads();
    for (int kt = 0; kt < nk; ++kt) {
        int cur = kt & 1;
        if (kt + 1 < nk) {
            if (z < 3) load_tile(d.A[z], K, M, K, m0, (kt+1) << 7, t, pa);
            else       load_tile_f32(txtf, K, M, K, m0, (kt+1) << 7, t, pa);
            load_tile(Bb, K, 768, K, n0, (kt+1) << 7, t, pbv);
        }
        mfma_tile(As[cur], Bs[cur], wr, wc, lane, acc);
        if (kt + 1 < nk) {
            write_tile(As[cur^1], t, pa);
            write_tile(Bs[cur^1], t, pbv);
        }
        __syncthreads();
    }
    #pragma unroll
    for (int m = 0; m < 2; ++m) {
        int rbase = m0 + wr*32 + m*16 + (lane >> 4) * 4;
        #pragma unroll
        for (int n = 0; n < 2; ++n) {
            int col = n0 + wc*32 + n*16 + (lane & 15);
            #pragma unroll
            for (int r = 0; r < 4; ++r) {
                int row = rbase + r;
                if (row >= M) continue;
                float v = acc[m][n][r] + bias[col];
                if (z < 3) {
                    v += d.pos[z][(long)(row & 255)*768 + col];
                    C[((long)z*512 + row) * 768 + col] = v;
                } else {
                    QHb[(long)row * 768 + col] = f2bf(v);
                }
            }
        }
    }
}

// ============ output-proj GEMM + fused unpatchify ============
struct OwDesc {
    const u16* Bt[3];
    float* plane[3];
    const float* bias[3];
    int N[3];
    int p2[3];
    int Wd[3];
};

__global__ __launch_bounds__(256) void gemm_ow(OwDesc d, const u16* __restrict__ A,
                                               const float* __restrict__ vwp) {
    int z = blockIdx.z;
    int N = d.N[z];
    int n0 = blockIdx.x * 64;
    if (n0 >= N) return;
    __shared__ u16 As[2][64][136];
    __shared__ u16 Bs[2][64][136];
    const u16* Ab = A + (long)z * 512 * 768;
    const u16* Bb = d.Bt[z];
    int t = threadIdx.x;
    int m0 = blockIdx.y * 64;
    int wave = t >> 6, lane = t & 63;
    int wr = wave >> 1, wc = wave & 1;
    f4 acc[2][2];
    #pragma unroll
    for (int m = 0; m < 2; ++m)
        #pragma unroll
        for (int n = 0; n < 2; ++n)
            #pragma unroll
            for (int r = 0; r < 4; ++r) acc[m][n][r] = 0.f;
    s8 pa[4], pbv[4];
    load_tile(Ab, 768, 512, 768, m0, 0, t, pa);
    load_tile(Bb, 768, N, 768, n0, 0, t, pbv);
    write_tile(As[0], t, pa);
    write_tile(Bs[0], t, pbv);
    __syncthreads();
    for (int kt = 0; kt < 6; ++kt) {
        int cur = kt & 1;
        if (kt + 1 < 6) {
            load_tile(Ab, 768, 512, 768, m0, (kt+1) << 7, t, pa);
            load_tile(Bb, 768, N, 768, n0, (kt+1) << 7, t, pbv);
        }
        mfma_tile(As[cur], Bs[cur], wr, wc, lane, acc);
        if (kt + 1 < 6) {
            write_tile(As[cur^1], t, pa);
            write_tile(Bs[cur^1], t, pbv);
        }
        __syncthreads();
    }
    float* plane = d.plane[z];
    const float* bias = d.bias[z];
    int p2 = d.p2[z], Wd = d.Wd[z];
    float wt = vwp[z];
    #pragma unroll
    for (int m = 0; m < 2; ++m) {
        int rbase = m0 + wr*32 + m*16 + (lane >> 4) * 4;
        #pragma unroll
        for (int n = 0; n < 2; ++n) {
            int col = n0 + wc*32 + n*16 + (lane & 15);
            if (col >= N) continue;
            int pp = col >> 5, c = col & 31;
            int pp1 = pp / p2, pp2 = pp % p2;
            float bv = bias[col];
            #pragma unroll
            for (int r = 0; r < 4; ++r) {
                int row = rbase + r;
                int b = row >> 8, nn = row & 255;
                int hh = nn >> 4, ww = nn & 15;
                plane[((long)(b*32 + c)*112 + hh*7 + pp1)*Wd + ww*p2 + pp2]
                    = wt * (acc[m][n][r] + bv);
            }
        }
    }
}

// ============ LayerNorm rows of 768 ============
__global__ __launch_bounds__(256) void ln_k(const float* __restrict__ in,
                                            float* __restrict__ outf,
                                            u16* __restrict__ outb,
                                            const float* __restrict__ g,
                                            const float* __restrict__ bta) {
    constexpr int N = 768;
    int row = blockIdx.x;
    const float* x = in + (size_t)row * N;
    int t = threadIdx.x;
    float v0 = x[t], v1 = x[t+256], v2 = x[t+512];
    float s = v0+v1+v2, s2 = v0*v0+v1*v1+v2*v2;
    #pragma unroll
    for (int off = 32; off > 0; off >>= 1) { s += __shfl_down(s, off); s2 += __shfl_down(s2, off); }
    __shared__ float red[8];
    int wid = t >> 6, lane = t & 63;
    if (lane == 0) { red[wid] = s; red[wid+4] = s2; }
    __syncthreads();
    if (t == 0) {
        float S = red[0]+red[1]+red[2]+red[3];
        float S2 = red[4]+red[5]+red[6]+red[7];
        float mean = S * (1.f/N);
        float var = S2 * (1.f/N) - mean*mean;
        red[0] = mean; red[1] = rsqrtf(var + 1e-5f);
    }
    __syncthreads();
    float mean = red[0], rstd = red[1];
    float y0 = (v0-mean)*rstd*g[t]     + bta[t];
    float y1 = (v1-mean)*rstd*g[t+256] + bta[t+256];
    float y2 = (v2-mean)*rstd*g[t+512] + bta[t+512];
    if (outf) {
        float* y = outf + (size_t)row * N;
        y[t] = y0; y[t+256] = y1; y[t+512] = y2;
    }
    if (outb) {
        u16* y = outb + (size_t)row * N;
        y[t] = f2bf(y0); y[t+256] = f2bf(y1); y[t+512] = f2bf(y2);
    }
}

// ============ fully fused self-attention ============
__global__ __launch_bounds__(256) void attn_k(const u16* __restrict__ QKV,
                                              const u16* __restrict__ Vt,
                                              u16* __restrict__ O) {
    __shared__ u16 Ks[256][72];
    __shared__ u16 Ps[128][264];
    __shared__ u16 Vs[64][264];
    int zz = blockIdx.x;
    int bh = zz >> 1, half = zz & 1;
    int bb = bh / 12, h = bh % 12;
    long qrow0 = (long)bb*256 + half*128;
    int hcol = h*64;
    int t = threadIdx.x;
    int wave = t >> 6, lane = t & 63;
    int lr = lane & 15, lg = lane >> 4;
    #pragma unroll
    for (int i = 0; i < 8; ++i) {
        int chunk = t + i*256;
        int row = chunk >> 3, c8 = (chunk & 7)*8;
        *reinterpret_cast<s8*>(&Ks[row][c8]) =
            *reinterpret_cast<const s8*>(QKV + ((long)bb*256 + row)*2304 + 768 + hcol + c8);
    }
    #pragma unroll
    for (int i = 0; i < 8; ++i) {
        int chunk = t + i*256;
        int d = chunk >> 5, j8 = (chunk & 31)*8;
        *reinterpret_cast<s8*>(&Vs[d][j8]) =
            *reinterpret_cast<const s8*>(Vt + (long)bh*16384 + (long)d*256 + j8);
    }
    __syncthreads();
    f4 acc[2][16];
    #pragma unroll
    for (int m = 0; m < 2; ++m)
        #pragma unroll
        for (int n = 0; n < 16; ++n)
            #pragma unroll
            for (int r = 0; r < 4; ++r) acc[m][n][r] = 0.f;
    #pragma unroll
    for (int kh = 0; kh < 2; ++kh) {
        s8 af0 = *reinterpret_cast<const s8*>(QKV + (qrow0 + wave*32 + lr)*2304 + hcol + kh*32 + lg*8);
        s8 af1 = *reinterpret_cast<const s8*>(QKV + (qrow0 + wave*32 + 16 + lr)*2304 + hcol + kh*32 + lg*8);
        #pragma unroll
        for (int n = 0; n < 16; ++n) {
            s8 bf = *reinterpret_cast<const s8*>(&Ks[n*16 + lr][kh*32 + lg*8]);
            acc[0][n] = MFMA16(af0, bf, acc[0][n]);
            acc[1][n] = MFMA16(af1, bf, acc[1][n]);
        }
    }
    #pragma unroll
    for (int m = 0; m < 2; ++m)
        #pragma unroll
        for (int r = 0; r < 4; ++r) {
            float mx = -1e30f;
            #pragma unroll
            for (int n = 0; n < 16; ++n) mx = fmaxf(mx, acc[m][n][r]);
            #pragma unroll
            for (int o = 8; o; o >>= 1) mx = fmaxf(mx, __shfl_xor(mx, o));
            float l = 0.f;
            float p[16];
            #pragma unroll
            for (int n = 0; n < 16; ++n) {
                p[n] = __expf((acc[m][n][r] - mx) * 0.125f);
                l += p[n];
            }
            #pragma unroll
            for (int o = 8; o; o >>= 1) l += __shfl_xor(l, o);
            float inv = 1.f / l;
            int prow = wave*32 + m*16 + lg*4 + r;
            #pragma unroll
            for (int n = 0; n < 16; ++n)
                Ps[prow][n*16 + lr] = f2bf(p[n] * inv);
        }
    __syncthreads();
    f4 o2[2][4];
    #pragma unroll
    for (int m = 0; m < 2; ++m)
        #pragma unroll
        for (int n = 0; n < 4; ++n)
            #pragma unroll
            for (int r = 0; r < 4; ++r) o2[m][n][r] = 0.f;
    #pragma unroll
    for (int kh = 0; kh < 8; ++kh) {
        s8 pf0 = *reinterpret_cast<const s8*>(&Ps[wave*32 + lr][kh*32 + lg*8]);
        s8 pf1 = *reinterpret_cast<const s8*>(&Ps[wave*32 + 16 + lr][kh*32 + lg*8]);
        #pragma unroll
        for (int n = 0; n < 4; ++n) {
            s8 vf = *reinterpret_cast<const s8*>(&Vs[n*16 + lr][kh*32 + lg*8]);
            o2[0][n] = MFMA16(pf0, vf, o2[0][n]);
            o2[1][n] = MFMA16(pf1, vf, o2[1][n]);
        }
    }
    #pragma unroll
    for (int m = 0; m < 2; ++m)
        #pragma unroll
        for (int n = 0; n < 4; ++n)
            #pragma unroll
            for (int r = 0; r < 4; ++r)
                O[(qrow0 + wave*32 + m*16 + lg*4 + r)*768 + hcol + n*16 + lr] = f2bf(o2[m][n][r]);
}

// ============ fully fused cross-attention ============
__global__ __launch_bounds__(256) void ca_fused(const u16* __restrict__ QHb,
                                                const u16* __restrict__ KVHb,
                                                u16* __restrict__ O) {
    __shared__ u16 QHs[80][72];
    __shared__ u16 KHs[256][72];
    __shared__ float rmax[80][4];
    __shared__ float rsum[80][4];
    __shared__ float Wj[256];
    int bh = blockIdx.x;
    int rowblk = bh / 12, h = bh % 12;
    int bsel = rowblk & 1;
    int t = threadIdx.x;
    int wave = t >> 6, lane = t & 63;
    int lr = lane & 15, lg = lane >> 4;
    #pragma unroll
    for (int i = 0; i < 3; ++i) {
        int chunk = t + i*256;
        if (chunk < 640) {
            int row = chunk >> 3, c8 = (chunk & 7)*8;
            s8 v;
            #pragma unroll
            for (int q = 0; q < 8; ++q) v[q] = 0;
            if (row < 77)
                v = *reinterpret_cast<const s8*>(QHb + ((long)(bsel*77 + row))*768 + h*64 + c8);
            *reinterpret_cast<s8*>(&QHs[row][c8]) = v;
        }
    }
    #pragma unroll
    for (int i = 0; i < 8; ++i) {
        int chunk = t + i*256;
        int row = chunk >> 3, c8 = (chunk & 7)*8;
        *reinterpret_cast<s8*>(&KHs[row][c8]) =
            *reinterpret_cast<const s8*>(KVHb + ((long)rowblk*256 + row)*1536 + h*64 + c8);
    }
    __syncthreads();
    f4 acc[5][4];
    #pragma unroll
    for (int m = 0; m < 5; ++m)
        #pragma unroll
        for (int n = 0; n < 4; ++n)
            #pragma unroll
            for (int r = 0; r < 4; ++r) acc[m][n][r] = 0.f;
    #pragma unroll
    for (int kh = 0; kh < 2; ++kh) {
        s8 af[5], bf[4];
        #pragma unroll
        for (int m = 0; m < 5; ++m)
            af[m] = *reinterpret_cast<const s8*>(&QHs[m*16 + lr][kh*32 + lg*8]);
        #pragma unroll
        for (int n = 0; n < 4; ++n)
            bf[n] = *reinterpret_cast<const s8*>(&KHs[wave*64 + n*16 + lr][kh*32 + lg*8]);
        #pragma unroll
        for (int m = 0; m < 5; ++m)
            #pragma unroll
            for (int n = 0; n < 4; ++n)
                acc[m][n] = MFMA16(af[m], bf[n], acc[m][n]);
    }
    #pragma unroll
    for (int m = 0; m < 5; ++m)
        #pragma unroll
        for (int r = 0; r < 4; ++r) {
            float mx = -1e30f;
            #pragma unroll
            for (int n = 0; n < 4; ++n) mx = fmaxf(mx, acc[m][n][r]);
            #pragma unroll
            for (int o = 8; o; o >>= 1) mx = fmaxf(mx, __shfl_xor(mx, o));
            if (lr == 0) rmax[m*16 + lg*4 + r][wave] = mx;
        }
    __syncthreads();
    #pragma unroll
    for (int m = 0; m < 5; ++m)
        #pragma unroll
        for (int r = 0; r < 4; ++r) {
            int i = m*16 + lg*4 + r;
            float mi = fmaxf(fmaxf(rmax[i][0], rmax[i][1]), fmaxf(rmax[i][2], rmax[i][3]));
            float s = 0.f;
            #pragma unroll
            for (int n = 0; n < 4; ++n) s += __expf((acc[m][n][r] - mi) * 0.125f);
            #pragma unroll
            for (int o = 8; o; o >>= 1) s += __shfl_xor(s, o);
            if (lr == 0) rsum[i][wave] = s;
        }
    __syncthreads();
    float wn[4] = {0.f, 0.f, 0.f, 0.f};
    #pragma unroll
    for (int m = 0; m < 5; ++m)
        #pragma unroll
        for (int r = 0; r < 4; ++r) {
            int i = m*16 + lg*4 + r;
            if (i < 77) {
                float mi = fmaxf(fmaxf(rmax[i][0], rmax[i][1]), fmaxf(rmax[i][2], rmax[i][3]));
                float li = rsum[i][0] + rsum[i][1] + rsum[i][2] + rsum[i][3];
                float inv = 1.f / li;
                #pragma unroll
                for (int n = 0; n < 4; ++n)
                    wn[n] += __expf((acc[m][n][r] - mi) * 0.125f) * inv;
            }
        }
    #pragma unroll
    for (int n = 0; n < 4; ++n) {
        wn[n] += __shfl_xor(wn[n], 16);
        wn[n] += __shfl_xor(wn[n], 32);
    }
    if (lane < 16) {
        #pragma unroll
        for (int n = 0; n < 4; ++n) Wj[wave*64 + n*16 + lr] = wn[n];
    }
    __syncthreads();
    int d = t & 63;
    #pragma unroll 4
    for (int it = 0; it < 64; ++it) {
        int j = it*4 + (t >> 6);
        long row = (long)rowblk*256 + j;
        float vh = bf2f(KVHb[row*1536 + 768 + h*64 + d]);
        O[row*768 + h*64 + d] = f2bf(Wj[j] * vh);
    }
}

// ============ streaming final combine (non-temporal img/out) ============
__global__ __launch_bounds__(256) void final_k(const float* __restrict__ img,
                                               const float* __restrict__ Aax,
                                               const float* __restrict__ Asag,
                                               const float* __restrict__ Acor,
                                               float* __restrict__ out) {
    int blk = blockIdx.x;                 // bc*112 + d
    int bc = blk / 112;
    const f4* ip = reinterpret_cast<const f4*>(img + (size_t)blk * 8960);
    const f4* ap = reinterpret_cast<const f4*>(Aax + (size_t)bc * 8960);
    const f4* sp = reinterpret_cast<const f4*>(Asag + (size_t)blk * 80);
    const float* cp = Acor + (size_t)blk * 112;
    f4* op = reinterpret_cast<f4*>(out + (size_t)blk * 8960);
    int t = threadIdx.x;
    #pragma unroll
    for (int k = 0; k < 9; ++k) {
        int q = t + k * 256;
        if (q < 2240) {
            f4 iv = __builtin_nontemporal_load(&ip[q]);
            int h = q / 20, w4 = q % 20;
            float cv = cp[h];
            f4 r = iv + ap[q] + sp[w4] + (f4){cv, cv, cv, cv};
            __builtin_nontemporal_store(r, &op[q]);
        }
    }
}

extern "C" void kernel_launch(void* const* d_in, const int* in_sizes, int n_in,
                              void* d_out, int out_size, void* d_ws, size_t ws_size,
                              hipStream_t stream) {
    (void)in_sizes; (void)n_in; (void)out_size; (void)ws_size;
    const float* img    = (const float*)d_in[0];
    const float* txt    = (const float*)d_in[1];
    const float* pe_w[3] = {(const float*)d_in[2], (const float*)d_in[4], (const float*)d_in[6]};
    const float* pe_b[3] = {(const float*)d_in[3], (const float*)d_in[5], (const float*)d_in[7]};
    const float* pos[3]  = {(const float*)d_in[8], (const float*)d_in[9], (const float*)d_in[10]};
    const float* qw = (const float*)d_in[11];
    const float* kw = (const float*)d_in[12];
    const float* vw_attn = (const float*)d_in[13];
    const float* pw = (const float*)d_in[14];
    const float* pb = (const float*)d_in[15];
    const float* caq_w = (const float*)d_in[16];
    const float* caq_b = (const float*)d_in[17];
    const float* cak_w = (const float*)d_in[18];
    const float* cak_b = (const float*)d_in[19];
    const float* cav_w = (const float*)d_in[20];
    const float* cav_b = (const float*)d_in[21];
    const float* cao_w = (const float*)d_in[22];
    const float* cao_b = (const float*)d_in[23];
    const float* mlp_w1 = (const float*)d_in[24];
    const float* mlp_b1 = (const float*)d_in[25];
    const float* mlp_w2 = (const float*)d_in[26];
    const float* mlp_b2 = (const float*)d_in[27];
    const float* ow[3] = {(const float*)d_in[28], (const float*)d_in[30], (const float*)d_in[32]};
    const float* ob[3] = {(const float*)d_in[29], (const float*)d_in[31], (const float*)d_in[33]};
    const float* view_w = (const float*)d_in[34];
    const float* n_g[3] = {(const float*)d_in[35], (const float*)d_in[36], (const float*)d_in[37]};
    const float* n_b[3] = {(const float*)d_in[38], (const float*)d_in[39], (const float*)d_in[40]};

    typedef unsigned short u16t;
    unsigned char* sb = (unsigned char*)d_out;
    size_t off = 0;
    auto B = [&](size_t bytes) -> void* {
        void* p = sb + off; off += (bytes + 511) & ~(size_t)511; return p;
    };
    u16t* qkvT  = (u16t*)B((size_t)2304*768*2);
    u16t* pwT   = (u16t*)B(768*768*2);
    u16t* caqT  = (u16t*)B(768*768*2);
    u16t* cakvT = (u16t*)B((size_t)1536*768*2);
    u16t* caoT  = (u16t*)B(768*768*2);
    u16t* mlp1T = (u16t*)B((size_t)3072*768*2);
    u16t* mlp2T = (u16t*)B((size_t)768*3072*2);
    u16t* peT[3]; peT[0] = (u16t*)B((size_t)768*1120*2); peT[1] = (u16t*)B((size_t)768*1120*2); peT[2] = (u16t*)B((size_t)768*1568*2);
    u16t* owT[3]; owT[0] = (u16t*)B((size_t)1120*768*2); owT[1] = (u16t*)B((size_t)1120*768*2); owT[2] = (u16t*)B((size_t)1568*768*2);
    float* axp   = (float*)B((size_t)16*573440*4);
    float* m_sag = (float*)B(573440*4);
    float* m_cor = (float*)B(802816*4);
    u16t* P0 = (u16t*)B((size_t)512*1120*2);
    u16t* P1 = (u16t*)B((size_t)512*1120*2);
    u16t* P2 = (u16t*)B((size_t)512*1568*2);
    float* X0  = (float*)B((size_t)1536*768*4);
    float* X1f = (float*)B((size_t)1536*768*4);
    float* X2  = (float*)B((size_t)1536*768*4);
    float* X3f = (float*)B((size_t)1536*768*4);
    float* X4  = (float*)B((size_t)1536*768*4);
    u16t* X1b = (u16t*)B((size_t)1536*768*2);
    u16t* X3b = (u16t*)B((size_t)1536*768*2);
    u16t* X5b = (u16t*)B((size_t)1536*768*2);
    u16t* X6b = (u16t*)B((size_t)1536*768*2);
    u16t* QKVb = (u16t*)B((size_t)1536*2304*2);
    u16t* Obf = (u16t*)B((size_t)1536*768*2);
    u16t* Vt  = (u16t*)B((size_t)72*64*256*2);
    u16t* Hb  = (u16t*)B((size_t)1536*3072*2);
    u16t* KVHb = (u16t*)B((size_t)1536*1536*2);
    u16t* QHb  = (u16t*)B((size_t)154*768*2);

    float* ws = (float*)d_ws;
    float* Aax  = ws;
    float* Asag = ws + 573440;
    float* Acor = ws + 1146880;

    // ---- prep: transposes + means (1 launch) ----
    TT tab;
    {
        const float* ins[16] = {qw, kw, vw_attn, pw, caq_w, cak_w, cav_w, cao_w,
                                mlp_w1, mlp_w2, pe_w[0], pe_w[1], pe_w[2], ow[0], ow[1], ow[2]};
        u16t* outs[16] = {qkvT, qkvT + 768*768, qkvT + 2*768*768, pwT, caqT, cakvT,
                          cakvT + 768*768, caoT, mlp1T, mlp2T, peT[0], peT[1], peT[2],
                          owT[0], owT[1], owT[2]};
        int Ks[16] = {768,768,768,768,768,768,768,768, 768,3072, 1120,1120,1568, 768,768,768};
        int Ns[16] = {768,768,768,768,768,768,768,768, 3072,768, 768,768,768, 1120,1120,1568};
        int st = 0;
        for (int i = 0; i < 16; ++i) {
            tab.in[i] = ins[i]; tab.out[i] = outs[i]; tab.K[i] = Ks[i]; tab.N[i] = Ns[i];
            tab.start[i] = st;
            st += (Ks[i] >> 5) * (Ns[i] >> 5);
        }
        tab.total = st;
        prep_k<<<1024 + st, 256, 0, stream>>>(tab, img, axp, m_sag, m_cor);
    }

    patchify3_k<<<dim3(224,3), 256, 0, stream>>>(axp, m_sag, m_cor, P0, P1, P2);

    auto gemm = [&](const u16t* A, const u16t* Bt, float* Cf, u16t* Cb,
                    int M, int N, int K, const float* bias, const float* bias2,
                    const float* resid, int act, u16t* vt) {
        dim3 g(N/64, M/64, 1);
        gemm_gl<<<g, 256, 0, stream>>>(A, Bt, Cf, Cb, M, N, K, bias, bias2, resid, act, vt);
    };

    // pe (z<3) + QH projection (z=3), one launch
    {
        PeDesc d;
        d.A[0] = P0; d.A[1] = P1; d.A[2] = P2;
        d.Bt[0] = peT[0]; d.Bt[1] = peT[1]; d.Bt[2] = peT[2]; d.Bt[3] = caqT;
        d.bias[0] = pe_b[0]; d.bias[1] = pe_b[1]; d.bias[2] = pe_b[2]; d.bias[3] = caq_b;
        d.pos[0] = pos[0]; d.pos[1] = pos[1]; d.pos[2] = pos[2];
        d.K[0] = 1120; d.K[1] = 1120; d.K[2] = 1568; d.K[3] = 768;
        d.M[0] = 512; d.M[1] = 512; d.M[2] = 512; d.M[3] = 154;
        gemm_pe<<<dim3(12,8,4), 256, 0, stream>>>(d, txt, X0, QHb);
    }

    ln_k<<<1536, 256, 0, stream>>>(X0, X1f, X1b, n_g[0], n_b[0]);
    // QKV projection: 128x128 gload_lds tile + fused Vt scatter
    gemm_gl128<<<dim3(18, 12), 256, 0, stream>>>(X1b, qkvT, QKVb, Vt, 2304, 768,
                                                 nullptr, nullptr, 0);
    attn_k<<<144, 256, 0, stream>>>(QKVb, Vt, Obf);
    gemm(Obf, pwT, X2, nullptr, 1536, 768, 768, pb, nullptr, X1f, 0, nullptr);
    ln_k<<<1536, 256, 0, stream>>>(X2, X3f, X3b, n_g[1], n_b[1]);
    // cak||cav: 128x128 gload_lds tile, split bias
    gemm_gl128<<<dim3(12, 12), 256, 0, stream>>>(X3b, cakvT, KVHb, nullptr, 1536, 768,
                                                 cak_b, cav_b, 0);
    ca_fused<<<72, 256, 0, stream>>>(QHb, KVHb, Obf);
    gemm(Obf, caoT, X4, nullptr, 1536, 768, 768, cao_b, nullptr, X3f, 0, nullptr);
    ln_k<<<1536, 256, 0, stream>>>(X4, nullptr, X5b, n_g[2], n_b[2]);
    // MLP1: 128x128 gload_lds tile, gelu
    gemm_gl128<<<dim3(24, 12), 256, 0, stream>>>(X5b, mlp1T, Hb, nullptr, 3072, 768,
                                                 mlp_b1, nullptr, 1);
    gemm(Hb, mlp2T, nullptr, X6b, 1536, 768, 3072, mlp_b2, nullptr, X4, 0, nullptr);
    {
        OwDesc d;
        d.Bt[0] = owT[0]; d.Bt[1] = owT[1]; d.Bt[2] = owT[2];
        d.plane[0] = Aax; d.plane[1] = Asag; d.plane[2] = Acor;
        d.bias[0] = ob[0]; d.bias[1] = ob[1]; d.bias[2] = ob[2];
        d.N[0] = 1120; d.N[1] = 1120; d.N[2] = 1568;
        d.p2[0] = 5; d.p2[1] = 5; d.p2[2] = 7;
        d.Wd[0] = 80; d.Wd[1] = 80; d.Wd[2] = 112;
        gemm_ow<<<dim3(25,8,3), 256, 0, stream>>>(d, X6b, view_w);
    }

    final_k<<<7168, 256, 0, stream>>>(img, Aax, Asag, Acor, (float*)d_out);
}